// Round 10
// baseline (1089.215 us; speedup 1.0000x reference)
//
#include <hip/hip_runtime.h>
#include <math.h>

#define TPB 256

typedef short s16x8 __attribute__((ext_vector_type(8)));
typedef short s16x4 __attribute__((ext_vector_type(4)));
typedef float f32x4 __attribute__((ext_vector_type(4)));

// split fp32 into bf16 hi + bf16 lo (RNE both), x ~= hi + lo
__device__ inline void bsplit(float x, short& h, short& l){
  union { float f; unsigned u; } a, hf, rf;
  a.f = x;
  unsigned hu = (a.u + 0x7FFFu + ((a.u >> 16) & 1u)) >> 16;
  h = (short)hu;
  hf.u = hu << 16;
  rf.f = x - hf.f;
  l = (short)((rf.u + 0x7FFFu + ((rf.u >> 16) & 1u)) >> 16);
}

// ==== weight split: w[oc][c][tap] -> wh/wl[tap][oc][c] (any tap count) ====
__global__ __launch_bounds__(TPB) void wsplit_k(
    const float* __restrict__ w, short* __restrict__ wh, short* __restrict__ wl,
    int C, int O, int ntap, int total)
{
  int idx = blockIdx.x*TPB + threadIdx.x;
  if (idx >= total) return;
  int c   = idx % C;
  int t2  = idx / C;
  int oc  = t2 % O;
  int tap = t2 / O;
  float x = w[((size_t)oc*C + c)*ntap + tap];
  short h, l; bsplit(x, h, l);
  wh[idx] = h; wl[idx] = l;
}

// ==== conv1 weight prep: c1w[oc][3][11][11] -> wh/wl[oc][576], k=(c*12+kh)*16+kw ====
__global__ __launch_bounds__(TPB) void wsplit1_k(
    const float* __restrict__ w, short* __restrict__ wh, short* __restrict__ wl)
{
  int idx = blockIdx.x*TPB + threadIdx.x;
  if (idx >= 64*576) return;
  int k  = idx % 576;
  int oc = idx / 576;
  int g  = k >> 4, kw = k & 15;
  int c  = g / 12, kh = g % 12;
  float x = 0.f;
  if (kh < 11 && kw < 11)
    x = w[((size_t)oc*3 + c)*121 + kh*11 + kw];
  short h, l; bsplit(x, h, l);
  wh[idx] = h; wl[idx] = l;
}

// ==== transpose w[O][K] -> wT[K][O] (for gw1: gw1[9216][72] -> GT1[72][9216]) ====
__global__ __launch_bounds__(TPB) void wtrans_k(
    const float* __restrict__ w, float* __restrict__ wT, int K, int O)
{
  int idx = blockIdx.x*TPB + threadIdx.x;
  if (idx >= K*O) return;
  int oc = idx % O;
  int k  = idx / O;
  wT[idx] = w[(size_t)oc*K + k];
}

// ============== conv1 MFMA: in-LDS im2col along kw, bf16x3 ==============
// block = (oh, b); 4 waves = 4 n-tiles of 16 ow. Each wave computes all 64 oc.
// LDS: 33 planes (c x kh<=10) x 236 cols (stored col = iw+2) hi/lo.
// B-frag: 8 consecutive kw at col ow*4+(lg&1)*8 -> two ds_read_b64 (8B-aligned).
// kh=11 slice has zero weights; aliased to kh=10 plane (finite garbage x 0).
// Invalid ow (55..63) produce independent garbage columns, discarded at store.
#define CV1_W 236
#define CV1_PL 33
__global__ __launch_bounds__(256, 2) void conv1m_k(
    const float* __restrict__ in, const short* __restrict__ whi,
    const short* __restrict__ wlo, const float* __restrict__ bias,
    float* __restrict__ out)
{
  __shared__ __align__(16) short lds[2][CV1_PL*CV1_W + 84];  // +84 pad: ow>=55 overrun
  const int tid = threadIdx.x;
  const int oh = blockIdx.x % 55;
  const int b  = blockIdx.x / 55;
  const int nt = tid >> 6;
  const int ln = tid & 15;
  const int lg = (tid & 63) >> 4;
  const int ow = nt*16 + ln;             // valid < 55

  const float* ip = in + (size_t)b*3*224*224;
  for (int i = tid; i < CV1_PL*CV1_W; i += 256){
    int plane = i / CV1_W;
    int col   = i % CV1_W;
    int c = plane / 11, kh = plane % 11;
    int ih = oh*4 - 2 + kh;
    int iw = col - 2;
    float v = 0.f;
    if (ih >= 0 && ih < 224 && iw >= 0 && iw < 224)
      v = ip[(size_t)c*50176 + (size_t)ih*224 + iw];
    short h, l; bsplit(v, h, l);
    lds[0][i] = h;
    lds[1][i] = l;
  }
  __syncthreads();

  f32x4 acc[4];
  #pragma unroll
  for (int m=0;m<4;++m){
    const float4 bv = *reinterpret_cast<const float4*>(bias + m*16 + lg*4);
    acc[m] = (f32x4){bv.x, bv.y, bv.z, bv.w};
  }

  // A-frag preload (slice 0), prefetch one slice ahead
  s16x8 ah[4], al[4], ahn[4], aln[4];
  #pragma unroll
  for (int m=0;m<4;++m){
    size_t ao = (size_t)(m*16 + ln)*576 + lg*8;
    ah[m] = *reinterpret_cast<const s16x8*>(whi + ao);
    al[m] = *reinterpret_cast<const s16x8*>(wlo + ao);
  }

  #pragma unroll 1
  for (int s=0; s<18; ++s){
    if (s < 17){
      #pragma unroll
      for (int m=0;m<4;++m){
        size_t ao = (size_t)(m*16 + ln)*576 + (s+1)*32 + lg*8;
        ahn[m] = *reinterpret_cast<const s16x8*>(whi + ao);
        aln[m] = *reinterpret_cast<const s16x8*>(wlo + ao);
      }
    }
    // B frag: group g = 2s + (lg>>1): (c,kh); kw base (lg&1)*8
    int g  = 2*s + (lg >> 1);
    int c  = g / 12, kh = g % 12;
    int plane = c*11 + (kh < 11 ? kh : 10);
    int base  = plane*CV1_W + ow*4 + (lg & 1)*8;
    s16x4 h0 = *reinterpret_cast<const s16x4*>(&lds[0][base]);
    s16x4 h1 = *reinterpret_cast<const s16x4*>(&lds[0][base+4]);
    s16x4 l0 = *reinterpret_cast<const s16x4*>(&lds[1][base]);
    s16x4 l1 = *reinterpret_cast<const s16x4*>(&lds[1][base+4]);
    s16x8 bh, bl;
    #pragma unroll
    for (int j=0;j<4;++j){
      bh[j] = h0[j]; bh[4+j] = h1[j];
      bl[j] = l0[j]; bl[4+j] = l1[j];
    }
    #pragma unroll
    for (int m=0;m<4;++m){
      acc[m] = __builtin_amdgcn_mfma_f32_16x16x32_bf16(al[m], bh, acc[m], 0,0,0);
      acc[m] = __builtin_amdgcn_mfma_f32_16x16x32_bf16(ah[m], bl, acc[m], 0,0,0);
      acc[m] = __builtin_amdgcn_mfma_f32_16x16x32_bf16(ah[m], bh, acc[m], 0,0,0);
    }
    #pragma unroll
    for (int m=0;m<4;++m){ ah[m] = ahn[m]; al[m] = aln[m]; }
  }

  if (ow < 55){
    float* op = out + ((size_t)b*64)*3025 + (size_t)oh*55 + ow;
    #pragma unroll
    for (int m=0;m<4;++m)
      #pragma unroll
      for (int r=0;r<4;++r){
        int oc = m*16 + lg*4 + r;
        op[(size_t)oc*3025] = fmaxf(acc[m][r], 0.f);
      }
  }
}

// ============== conv2 MFMA: tap-decomposed implicit GEMM, bf16x3 ==============
__global__ __launch_bounds__(256, 2) void conv2m_k(
    const float* __restrict__ in, const short* __restrict__ whi,
    const short* __restrict__ wlo, const float* __restrict__ bias,
    float* __restrict__ out)
{
  __shared__ __align__(16) short lds[2][217*72];   // 62496 B
  const int tid = threadIdx.x;
  const int rg  = blockIdx.x;          // 0..8
  const int b   = blockIdx.y;
  const int wid = tid >> 6;
  const int ln  = tid & 15;
  const int lg  = (tid & 63) >> 4;
  const int oc0 = wid*48;
  const int r0  = rg*3;

  int sb[6], nn[6];
  #pragma unroll
  for (int t=0;t<6;++t){
    int n = t*16 + ln;
    nn[t] = n;
    int ohl = n / 27, ow = n % 27;
    sb[t] = (n < 81) ? (ohl*31 + ow) : 0;
  }

  f32x4 acc[3][6];
  #pragma unroll
  for (int m=0;m<3;++m){
    const float4 bv = *reinterpret_cast<const float4*>(bias + oc0 + m*16 + lg*4);
    #pragma unroll
    for (int t=0;t<6;++t) acc[m][t] = (f32x4){bv.x, bv.y, bv.z, bv.w};
  }

  const float* ip = in + (size_t)b*64*729;
  for (int i = tid; i < 217*64; i += 256){
    int c  = i / 217;
    int sp = i % 217;
    int prow = sp / 31, pcol = sp % 31;
    int ih = r0 - 2 + prow;
    int iw = pcol - 2;
    float v = 0.f;
    if (ih >= 0 && ih < 27 && iw >= 0 && iw < 27)
      v = ip[(size_t)c*729 + ih*27 + iw];
    short h, l; bsplit(v, h, l);
    lds[0][sp*72 + c] = h;
    lds[1][sp*72 + c] = l;
  }
  __syncthreads();

  #pragma unroll 1
  for (int tap=0; tap<25; ++tap){
    const int toff = (tap/5)*31 + (tap%5);
    #pragma unroll
    for (int kh2=0; kh2<64; kh2+=32){
      const size_t wo = (size_t)tap*192*64 + (size_t)kh2 + lg*8;
      s16x8 ah0 = *reinterpret_cast<const s16x8*>(whi + wo + (size_t)(oc0      + ln)*64);
      s16x8 ah1 = *reinterpret_cast<const s16x8*>(whi + wo + (size_t)(oc0 + 16 + ln)*64);
      s16x8 ah2 = *reinterpret_cast<const s16x8*>(whi + wo + (size_t)(oc0 + 32 + ln)*64);
      s16x8 al0 = *reinterpret_cast<const s16x8*>(wlo + wo + (size_t)(oc0      + ln)*64);
      s16x8 al1 = *reinterpret_cast<const s16x8*>(wlo + wo + (size_t)(oc0 + 16 + ln)*64);
      s16x8 al2 = *reinterpret_cast<const s16x8*>(wlo + wo + (size_t)(oc0 + 32 + ln)*64);
      #pragma unroll
      for (int t=0;t<6;++t){
        int off = (sb[t] + toff)*72 + kh2 + lg*8;
        s16x8 bh = *reinterpret_cast<const s16x8*>(&lds[0][off]);
        s16x8 bl = *reinterpret_cast<const s16x8*>(&lds[1][off]);
        acc[0][t] = __builtin_amdgcn_mfma_f32_16x16x32_bf16(al0, bh, acc[0][t], 0,0,0);
        acc[0][t] = __builtin_amdgcn_mfma_f32_16x16x32_bf16(ah0, bl, acc[0][t], 0,0,0);
        acc[0][t] = __builtin_amdgcn_mfma_f32_16x16x32_bf16(ah0, bh, acc[0][t], 0,0,0);
        acc[1][t] = __builtin_amdgcn_mfma_f32_16x16x32_bf16(al1, bh, acc[1][t], 0,0,0);
        acc[1][t] = __builtin_amdgcn_mfma_f32_16x16x32_bf16(ah1, bl, acc[1][t], 0,0,0);
        acc[1][t] = __builtin_amdgcn_mfma_f32_16x16x32_bf16(ah1, bh, acc[1][t], 0,0,0);
        acc[2][t] = __builtin_amdgcn_mfma_f32_16x16x32_bf16(al2, bh, acc[2][t], 0,0,0);
        acc[2][t] = __builtin_amdgcn_mfma_f32_16x16x32_bf16(ah2, bl, acc[2][t], 0,0,0);
        acc[2][t] = __builtin_amdgcn_mfma_f32_16x16x32_bf16(ah2, bh, acc[2][t], 0,0,0);
      }
    }
  }

  float* op = out + (size_t)b*192*729 + r0*27;
  #pragma unroll
  for (int m=0;m<3;++m)
    #pragma unroll
    for (int t=0;t<6;++t){
      if (nn[t] < 81){
        #pragma unroll
        for (int r=0;r<4;++r){
          int oc = oc0 + m*16 + lg*4 + r;
          op[(size_t)oc*729 + nn[t]] = fmaxf(acc[m][t][r], 0.f);
        }
      }
    }
}

// ============== conv3/4/5 MFMA: tap-decomposed implicit GEMM, bf16x3 ==========
template<int C,int O>
__global__ __launch_bounds__(256, 2) void conv3m_k(
    const float* __restrict__ in, const short* __restrict__ whi,
    const short* __restrict__ wlo, const float* __restrict__ bias,
    float* __restrict__ out)
{
  __shared__ __align__(16) short lds[2][12000];
  const int tid = threadIdx.x;
  const int b   = blockIdx.y;
  const int wid = tid >> 6;
  const int ln  = tid & 15;
  const int lg  = (tid & 63) >> 4;
  const int oc0 = blockIdx.x*32 + (wid & 1)*16;
  const int ng  = wid >> 1;
  const int tbase  = ng ? 6 : 0;
  const int ntiles = ng ? 5 : 6;

  int sb[6], nn[6];
  #pragma unroll
  for (int t=0;t<6;++t){
    int n = (tbase + t)*16 + ln;
    nn[t] = n;
    int oh = n / 13, ow = n % 13;
    sb[t] = (n < 169) ? (oh*20 + ow) : 0;
  }

  f32x4 acc[6];
  const float4 bv = *reinterpret_cast<const float4*>(bias + oc0 + lg*4);
  #pragma unroll
  for (int t=0;t<6;++t) acc[t] = (f32x4){bv.x, bv.y, bv.z, bv.w};

  const float* ip = in + (size_t)b*C*169;

  #pragma unroll 1
  for (int c0=0; c0<C; c0+=32){
    __syncthreads();
    for (int i = tid; i < 32*300; i += 256){
      int c   = i / 300;
      int sp  = i % 300;
      int row = sp / 20, col = sp % 20;
      float v = 0.f;
      if (row >= 1 && row <= 13 && col >= 1 && col <= 13)
        v = ip[(size_t)(c0 + c)*169 + (row-1)*13 + (col-1)];
      short h, l; bsplit(v, h, l);
      lds[0][sp*40 + c] = h;
      lds[1][sp*40 + c] = l;
    }
    __syncthreads();

    const short* wh = whi + ((size_t)oc0 + ln)*C + c0 + lg*8;
    const short* wl = wlo + ((size_t)oc0 + ln)*C + c0 + lg*8;
    s16x8 ah = *reinterpret_cast<const s16x8*>(wh);
    s16x8 al = *reinterpret_cast<const s16x8*>(wl);
    #pragma unroll 1
    for (int tap=0; tap<9; ++tap){
      s16x8 ahn = ah, aln = al;
      if (tap < 8){
        ahn = *reinterpret_cast<const s16x8*>(wh + (size_t)(tap+1)*O*C);
        aln = *reinterpret_cast<const s16x8*>(wl + (size_t)(tap+1)*O*C);
      }
      const int toff = (tap/3)*20 + (tap%3);
      #pragma unroll
      for (int t=0;t<6;++t){
        if (t < ntiles){
          int off = (sb[t] + toff)*40 + lg*8;
          s16x8 bh = *reinterpret_cast<const s16x8*>(&lds[0][off]);
          s16x8 bl = *reinterpret_cast<const s16x8*>(&lds[1][off]);
          acc[t] = __builtin_amdgcn_mfma_f32_16x16x32_bf16(al, bh, acc[t], 0,0,0);
          acc[t] = __builtin_amdgcn_mfma_f32_16x16x32_bf16(ah, bl, acc[t], 0,0,0);
          acc[t] = __builtin_amdgcn_mfma_f32_16x16x32_bf16(ah, bh, acc[t], 0,0,0);
        }
      }
      ah = ahn; al = aln;
    }
  }

  float* op = out + ((size_t)b*O + oc0)*169;
  #pragma unroll
  for (int t=0;t<6;++t){
    if (t < ntiles && nn[t] < 169){
      #pragma unroll
      for (int r=0;r<4;++r)
        op[(size_t)(lg*4 + r)*169 + nn[t]] = fmaxf(acc[t][r], 0.f);
    }
  }
}

// ---------------- 3x3 stride-2 VALID maxpool ----------------
template<int HIN,int HOUT>
__global__ __launch_bounds__(TPB) void maxpool_k(
    const float* __restrict__ in, float* __restrict__ out, int nTotal)
{
  int idx = blockIdx.x*TPB + threadIdx.x;
  if (idx >= nTotal) return;
  int ow = idx % HOUT;
  int t  = idx / HOUT;
  int oh = t % HOUT;
  int ch = t / HOUT;
  const float* p = in + ((size_t)ch*HIN + oh*2)*HIN + ow*2;
  float m = -INFINITY;
  #pragma unroll
  for (int i=0;i<3;++i)
    #pragma unroll
    for (int j=0;j<3;++j)
      m = fmaxf(m, p[i*HIN + j]);
  out[idx] = m;
}

// ---------------- gate layer 1: one wave per (b,h), shuffle reduce ----------------
__global__ __launch_bounds__(256) void gate1_k(
    const float* __restrict__ feat, const float* __restrict__ gw1T,
    const float* __restrict__ gb1, float* __restrict__ g)
{
  const int b    = blockIdx.x;
  const int h    = blockIdx.y*4 + (threadIdx.x >> 6);
  const int lane = threadIdx.x & 63;
  const float* f = feat + (size_t)b*9216;
  const float* w = gw1T + (size_t)h*9216;
  float s = 0.f;
  #pragma unroll
  for (int it=0; it<36; ++it){
    int d = it*256 + lane*4;
    float4 fv = *reinterpret_cast<const float4*>(f + d);
    float4 wv = *reinterpret_cast<const float4*>(w + d);
    s = fmaf(fv.x, wv.x, s);
    s = fmaf(fv.y, wv.y, s);
    s = fmaf(fv.z, wv.z, s);
    s = fmaf(fv.w, wv.w, s);
  }
  #pragma unroll
  for (int off=32; off; off>>=1) s += __shfl_down(s, off, 64);
  if (lane == 0) g[(size_t)b*72 + h] = fmaxf(s + gb1[h], 0.f);
}

// ---------------- gate layer 2 + top-2 softmax (128 thr: 72-wide load!) ----
__global__ __launch_bounds__(128) void gate2_k(
    const float* __restrict__ g, const float* __restrict__ gw2,
    const float* __restrict__ gb2, float* __restrict__ gates)
{
  const int b = blockIdx.x;
  const int tid = threadIdx.x;
  __shared__ float gs[72];
  __shared__ float logits[8];
  if (tid < 72) gs[tid] = g[(size_t)b*72 + tid];
  __syncthreads();
  if (tid < 8) {
    float acc = gb2[tid];
    for (int j=0;j<72;++j)
      acc = fmaf(gs[j], gw2[(size_t)j*8 + tid], acc);
    logits[tid] = acc;
  }
  __syncthreads();
  if (tid == 0) {
    int i1 = 0; float v1 = logits[0];
    for (int e=1;e<8;++e) if (logits[e] > v1) { v1 = logits[e]; i1 = e; }
    int i2 = -1; float v2 = -INFINITY;
    for (int e=0;e<8;++e) { if (e==i1) continue; if (logits[e] > v2) { v2 = logits[e]; i2 = e; } }
    float z  = expf(v2 - v1);
    float w1 = 1.f / (1.f + z);
    float w2 = z   / (1.f + z);
    float* gr = gates + (size_t)b*8;
    for (int e=0;e<8;++e) gr[e] = 0.f;
    gr[i1] = w1;
    gr[i2] = w2;
  }
}

// ========== expert h1 dense split-K GEMM ==========
__global__ __launch_bounds__(256, 2) void eh1_part_k(
    const float* __restrict__ feat, const float* __restrict__ ew1,
    float* __restrict__ part)
{
  const int e  = blockIdx.x;
  const int ks = blockIdx.y;
  const int nb = blockIdx.z;
  const int h0 = nb*144;
  __shared__ __align__(16) float fs[64*33];
  __shared__ __align__(16) float wsh[32*144];
  const int tid = threadIdx.x;
  const int tx = tid & 15;
  const int ty = tid >> 4;
  float acc[4][9];
  #pragma unroll
  for (int i=0;i<4;++i)
    #pragma unroll
    for (int j=0;j<9;++j) acc[i][j]=0.f;
  const float* wbase = ew1 + (size_t)e*9216*288 + h0;
  for (int d0 = ks*576; d0 < ks*576+576; d0 += 32){
    __syncthreads();
    for (int l = tid; l < 512; l += 256){
      int r = l >> 3, c = l & 7;
      float4 v = *reinterpret_cast<const float4*>(feat + (size_t)r*9216 + d0 + c*4);
      float* dst = &fs[r*33 + c*4];
      dst[0]=v.x; dst[1]=v.y; dst[2]=v.z; dst[3]=v.w;
    }
    for (int l = tid; l < 1152; l += 256){
      int r = l / 36, c = l % 36;
      *reinterpret_cast<float4*>(&wsh[r*144 + c*4]) =
        *reinterpret_cast<const float4*>(wbase + (size_t)(d0 + r)*288 + c*4);
    }
    __syncthreads();
    #pragma unroll
    for (int k=0;k<32;++k){
      float fv[4], wv[9];
      #pragma unroll
      for (int i=0;i<4;++i) fv[i] = fs[(ty*4+i)*33 + k];
      #pragma unroll
      for (int j=0;j<9;++j) wv[j] = wsh[k*144 + tx*9 + j];
      #pragma unroll
      for (int i=0;i<4;++i)
        #pragma unroll
        for (int j=0;j<9;++j)
          acc[i][j] = fmaf(fv[i], wv[j], acc[i][j]);
    }
  }
  float* pp = part + (size_t)(ks*8 + e)*64*288;
  #pragma unroll
  for (int i=0;i<4;++i)
    #pragma unroll
    for (int j=0;j<9;++j)
      pp[(ty*4+i)*288 + h0 + tx*9 + j] = acc[i][j];
}

__global__ __launch_bounds__(TPB) void eh1_reduce_k(
    const float* __restrict__ part, const float* __restrict__ eb1,
    float* __restrict__ h1)
{
  int idx = blockIdx.x*TPB + threadIdx.x;
  if (idx >= 8*64*288) return;
  int h = idx % 288;
  int e = idx / (64*288);
  float a = eb1[(size_t)e*288 + h];
  #pragma unroll
  for (int s=0;s<16;++s)
    a += part[(size_t)s*147456 + idx];
  h1[idx] = fmaxf(a, 0.f);
}

// ---------------- expert h2 / out ----------------
__global__ __launch_bounds__(TPB) void expert_h2_k(
    const float* __restrict__ h1, const float* __restrict__ ew2,
    const float* __restrict__ eb2, const float* __restrict__ gates,
    float* __restrict__ h2)
{
  int idx = blockIdx.x*TPB + threadIdx.x;
  if (idx >= 8*64*144) return;
  int k = idx % 144;
  int t = idx / 144;
  int b = t % 64;
  int e = t / 64;
  if (gates[(size_t)b*8 + e] == 0.f) return;
  float acc = eb2[(size_t)e*144 + k];
  const float* h = h1 + ((size_t)e*64 + b)*288;
  const float* w = ew2 + (size_t)e*288*144 + k;
  for (int d=0; d<288; ++d)
    acc = fmaf(h[d], w[(size_t)d*144], acc);
  h2[idx] = fmaxf(acc, 0.f);
}

__global__ __launch_bounds__(TPB) void expert_out_k(
    const float* __restrict__ h2, const float* __restrict__ ew3,
    const float* __restrict__ eb3, const float* __restrict__ gates,
    float* __restrict__ out)
{
  int idx = blockIdx.x*TPB + threadIdx.x;
  if (idx >= 64*1000) return;
  int o = idx % 1000;
  int b = idx / 1000;
  float acc = 0.f;
  const float* gr = gates + (size_t)b*8;
  for (int e=0;e<8;++e){
    float ge = gr[e];
    if (ge == 0.f) continue;
    float a = eb3[(size_t)e*1000 + o];
    const float* h = h2 + ((size_t)e*64 + b)*144;
    const float* w = ew3 + (size_t)e*144*1000 + o;
    for (int k=0;k<144;++k)
      a = fmaf(h[k], w[(size_t)k*1000], a);
    acc = fmaf(ge, a, acc);
  }
  out[idx] = acc;
}

static inline int nblk(long long n){ return (int)((n + TPB - 1) / TPB); }

extern "C" void kernel_launch(void* const* d_in, const int* in_sizes, int n_in,
                              void* d_out, int out_size, void* d_ws, size_t ws_size,
                              hipStream_t stream)
{
  const float* x   = (const float*)d_in[0];
  const float* c1w = (const float*)d_in[1];  const float* c1b = (const float*)d_in[2];
  const float* c2w = (const float*)d_in[3];  const float* c2b = (const float*)d_in[4];
  const float* c3w = (const float*)d_in[5];  const float* c3b = (const float*)d_in[6];
  const float* c4w = (const float*)d_in[7];  const float* c4b = (const float*)d_in[8];
  const float* c5w = (const float*)d_in[9];  const float* c5b = (const float*)d_in[10];
  const float* gw1 = (const float*)d_in[11]; const float* gb1 = (const float*)d_in[12];
  const float* gw2 = (const float*)d_in[13]; const float* gb2 = (const float*)d_in[14];
  const float* ew1 = (const float*)d_in[15]; const float* eb1 = (const float*)d_in[16];
  const float* ew2 = (const float*)d_in[17]; const float* eb2 = (const float*)d_in[18];
  const float* ew3 = (const float*)d_in[19]; const float* eb3 = (const float*)d_in[20];
  float* out = (float*)d_out;

  const long long A_FLOATS = 12390400LL;
  const long long B_FLOATS = 2985984LL;
  float* A = (float*)d_ws;
  float* B = A + A_FLOATS;
  float* Cg = B + B_FLOATS;
  float* gates = Cg;                         // 512
  float* h1    = Cg + 512;                   // 147456
  float* h2    = h1 + 147456;                // 73728
  float* gbuf  = h2 + 73728;                 // 4608
  // conv1 split weights in B tail: B free until pool1 writes it (conv1m
  // consumes WH1/WL1 before pool1 runs)
  short* WH1 = (short*)(B + 2900000);        // 36,864 sh
  short* WL1 = WH1 + 36864;                  // ends B+2,936,864 < 2,985,984
  // other split weights + gw1 transpose in A tail (dead after pool1)
  short* WH2 = (short*)(A +  9000000);
  short* WL2 = WH2 + 307200;
  short* WH3 = (short*)(A +  9400000);
  short* WL3 = WH3 + 663552;
  short* WH4 = (short*)(A + 10100000);
  short* WL4 = WH4 + 884736;
  short* WH5 = (short*)(A + 11000000);
  short* WL5 = WH5 + 589824;
  float* GT1 = A + 11600000;                 // 663,552 f32, ends 12,263,552
  (void)ws_size; (void)in_sizes; (void)n_in; (void)out_size;

  const int B_ = 64;

  // conv1 weight prep (into B tail), then conv1 (MFMA): x -> A [64,64,55,55]
  wsplit1_k<<<nblk(64LL*576), TPB, 0, stream>>>(c1w, WH1, WL1);
  conv1m_k<<<55*64, 256, 0, stream>>>(x, WH1, WL1, c1b, A);
  // pool1: A -> B [64,64,27,27] (overwrites WH1/WL1 — already consumed)
  {
    long long n = (long long)B_*64*27*27;
    maxpool_k<55,27><<<nblk(n), TPB, 0, stream>>>(A, B, (int)n);
  }
  // weight prep into A tail (A dead now)
  wsplit_k<<<nblk(25LL*192*64),  TPB, 0, stream>>>(c2w, WH2, WL2,  64, 192, 25, 25*192*64);
  wsplit_k<<<nblk(9LL*384*192),  TPB, 0, stream>>>(c3w, WH3, WL3, 192, 384,  9, 9*384*192);
  wsplit_k<<<nblk(9LL*256*384),  TPB, 0, stream>>>(c4w, WH4, WL4, 384, 256,  9, 9*256*384);
  wsplit_k<<<nblk(9LL*256*256),  TPB, 0, stream>>>(c5w, WH5, WL5, 256, 256,  9, 9*256*256);
  wtrans_k<<<nblk(72LL*9216),    TPB, 0, stream>>>(gw1, GT1, 72, 9216);

  // conv2 (MFMA): B -> A [64,192,27,27]
  conv2m_k<<<dim3(9,64), 256, 0, stream>>>(B, WH2, WL2, c2b, A);
  // pool2: A -> B [64,192,13,13]
  {
    long long n = (long long)B_*192*13*13;
    maxpool_k<27,13><<<nblk(n), TPB, 0, stream>>>(A, B, (int)n);
  }
  // conv3 (MFMA): B -> A [64,384,13,13]
  conv3m_k<192,384><<<dim3(12,64), 256, 0, stream>>>(B, WH3, WL3, c3b, A);
  // conv4 (MFMA): A -> B [64,256,13,13]
  conv3m_k<384,256><<<dim3(8,64), 256, 0, stream>>>(A, WH4, WL4, c4b, B);
  // conv5 (MFMA): B -> A [64,256,13,13]
  conv3m_k<256,256><<<dim3(8,64), 256, 0, stream>>>(B, WH5, WL5, c5b, A);
  // pool3: A -> B = feat [64,9216]
  {
    long long n = (long long)B_*256*6*6;
    maxpool_k<13,6><<<nblk(n), TPB, 0, stream>>>(A, B, (int)n);
  }
  const float* feat = B;

  // gate
  gate1_k<<<dim3(64,18), 256, 0, stream>>>(feat, GT1, gb1, gbuf);
  gate2_k<<<64, 128, 0, stream>>>(gbuf, gw2, gb2, gates);

  // experts
  float* part = A;
  eh1_part_k<<<dim3(8,16,2), 256, 0, stream>>>(feat, ew1, part);
  eh1_reduce_k<<<nblk(8LL*64*288), TPB, 0, stream>>>(part, eb1, h1);
  expert_h2_k<<<nblk(8LL*64*144), TPB, 0, stream>>>(h1, ew2, eb2, gates, h2);
  expert_out_k<<<nblk(64LL*1000), TPB, 0, stream>>>(h2, ew3, eb3, gates, out);
}

// Round 11
// 925.443 us; speedup vs baseline: 1.1770x; 1.1770x over previous
//
#include <hip/hip_runtime.h>
#include <math.h>

#define TPB 256

typedef short s16x8 __attribute__((ext_vector_type(8)));
typedef short s16x4 __attribute__((ext_vector_type(4)));
typedef float f32x4 __attribute__((ext_vector_type(4)));

// split fp32 into bf16 hi + bf16 lo (RNE both), x ~= hi + lo
__device__ inline void bsplit(float x, short& h, short& l){
  union { float f; unsigned u; } a, hf, rf;
  a.f = x;
  unsigned hu = (a.u + 0x7FFFu + ((a.u >> 16) & 1u)) >> 16;
  h = (short)hu;
  hf.u = hu << 16;
  rf.f = x - hf.f;
  l = (short)((rf.u + 0x7FFFu + ((rf.u >> 16) & 1u)) >> 16);
}

// ==== weight split + MFMA-native reorder ====
// w[oc][c][tap] -> wh/wl[tile][slice][lane][8], tile=oc/16, slice=tap*(C/32)+c/32,
// lane=lg*16+ln (ln=oc%16, lg=(c%32)/8), j=c%8. A wave's A-frag = 1KB contiguous.
__global__ __launch_bounds__(TPB) void wsplit_k(
    const float* __restrict__ w, short* __restrict__ wh, short* __restrict__ wl,
    int C, int O, int ntap, int total)
{
  int idx = blockIdx.x*TPB + threadIdx.x;
  if (idx >= total) return;
  int c   = idx % C;
  int t2  = idx / C;
  int oc  = t2 % O;
  int tap = t2 / O;
  float x = w[((size_t)oc*C + c)*ntap + tap];
  short h, l; bsplit(x, h, l);
  int tile = oc >> 4, ln = oc & 15;
  int S    = ntap*(C >> 5);
  int sl   = tap*(C >> 5) + (c >> 5);
  int lg   = (c >> 3) & 3, j = c & 7;
  size_t dst = (((size_t)tile*S + sl)*64 + lg*16 + ln)*8 + j;
  wh[dst] = h; wl[dst] = l;
}

// ==== conv1 weight prep: c1w[oc][3][11][11] -> [m][s][lane][8] ====
// k=(c*12+kh)*16+kw (kh,kw zero-padded to 12,16), m=oc/16, s=k/32.
__global__ __launch_bounds__(TPB) void wsplit1_k(
    const float* __restrict__ w, short* __restrict__ wh, short* __restrict__ wl)
{
  int idx = blockIdx.x*TPB + threadIdx.x;
  if (idx >= 64*576) return;
  int k  = idx % 576;
  int oc = idx / 576;
  int g  = k >> 4, kw = k & 15;
  int c  = g / 12, kh = g % 12;
  float x = 0.f;
  if (kh < 11 && kw < 11)
    x = w[((size_t)oc*3 + c)*121 + kh*11 + kw];
  short h, l; bsplit(x, h, l);
  int m = oc >> 4, ln = oc & 15;
  int s = k >> 5, r = k & 31;
  int lg = r >> 3, j = r & 7;
  size_t dst = (((size_t)m*18 + s)*64 + lg*16 + ln)*8 + j;
  wh[dst] = h; wl[dst] = l;
}

// ==== transpose gw1[9216][72] -> GT1[72][9216] ====
__global__ __launch_bounds__(TPB) void wtrans_k(
    const float* __restrict__ w, float* __restrict__ wT, int K, int O)
{
  int idx = blockIdx.x*TPB + threadIdx.x;
  if (idx >= K*O) return;
  int oc = idx % O;
  int k  = idx / O;
  wT[idx] = w[(size_t)oc*K + k];
}

// ============== conv1 MFMA: in-LDS im2col along kw, bf16x3 ==============
// block = (oh, b); 4 waves = 4 n-tiles of 16 ow; each wave computes 64 oc.
// LDS: 33 planes (c x kh) x 240 cols (col = iw+2, 480B row = 16B-aligned) hi/lo.
// A-frag: one 16B coalesced load/lane from the [m][s][lane][8] layout.
#define C1W 240
#define CV1_PL 33
__global__ __launch_bounds__(256, 2) void conv1m_k(
    const float* __restrict__ in, const short* __restrict__ whi,
    const short* __restrict__ wlo, const float* __restrict__ bias,
    float* __restrict__ out)
{
  __shared__ __align__(16) short lds[2][CV1_PL*C1W + 84];  // +84: ow>=55 garbage overrun
  const int tid = threadIdx.x;
  const int oh = blockIdx.x % 55;
  const int b  = blockIdx.x / 55;
  const int nt = tid >> 6;
  const int ln = tid & 15;
  const int lg = (tid & 63) >> 4;
  const int lane = tid & 63;
  const int ow = nt*16 + ln;             // valid < 55

  const float* ip = in + (size_t)b*3*224*224;
  for (int i = tid; i < CV1_PL*59; i += 256){
    int plane = i / 59;
    int p     = i % 59;
    int c = plane / 11, kh = plane % 11;
    int ih = oh*4 - 2 + kh;
    int col0 = p*4;
    const float* rowp = (ih >= 0 && ih < 224) ? ip + (size_t)c*50176 + (size_t)ih*224 : nullptr;
    short h[4], l[4];
    #pragma unroll
    for (int j=0;j<4;++j){
      int iw = col0 + j - 2;
      float v = (rowp && iw >= 0 && iw < 224) ? rowp[iw] : 0.f;
      bsplit(v, h[j], l[j]);
    }
    s16x4 hv = {h[0],h[1],h[2],h[3]}, lv = {l[0],l[1],l[2],l[3]};
    *reinterpret_cast<s16x4*>(&lds[0][plane*C1W + col0]) = hv;
    *reinterpret_cast<s16x4*>(&lds[1][plane*C1W + col0]) = lv;
  }
  __syncthreads();

  f32x4 acc[4];
  #pragma unroll
  for (int m=0;m<4;++m){
    const float4 bv = *reinterpret_cast<const float4*>(bias + m*16 + lg*4);
    acc[m] = (f32x4){bv.x, bv.y, bv.z, bv.w};
  }

  s16x8 ah[4], al[4], ahn[4], aln[4];
  #pragma unroll
  for (int m=0;m<4;++m){
    size_t ao = (((size_t)m*18 + 0)*64 + lane)*8;
    ah[m] = *reinterpret_cast<const s16x8*>(whi + ao);
    al[m] = *reinterpret_cast<const s16x8*>(wlo + ao);
  }

  #pragma unroll 1
  for (int s=0; s<18; ++s){
    if (s < 17){
      #pragma unroll
      for (int m=0;m<4;++m){
        size_t ao = (((size_t)m*18 + s + 1)*64 + lane)*8;
        ahn[m] = *reinterpret_cast<const s16x8*>(whi + ao);
        aln[m] = *reinterpret_cast<const s16x8*>(wlo + ao);
      }
    }
    int g  = 2*s + (lg >> 1);            // (c,kh) group
    int c  = g / 12, kh = g % 12;
    int plane = c*11 + (kh < 11 ? kh : 10);   // kh=11: zero weights, alias row
    int base  = plane*C1W + ow*4 + (lg & 1)*8;
    s16x4 h0 = *reinterpret_cast<const s16x4*>(&lds[0][base]);
    s16x4 h1 = *reinterpret_cast<const s16x4*>(&lds[0][base+4]);
    s16x4 l0 = *reinterpret_cast<const s16x4*>(&lds[1][base]);
    s16x4 l1 = *reinterpret_cast<const s16x4*>(&lds[1][base+4]);
    s16x8 bh = __builtin_shufflevector(h0, h1, 0,1,2,3,4,5,6,7);
    s16x8 bl = __builtin_shufflevector(l0, l1, 0,1,2,3,4,5,6,7);
    #pragma unroll
    for (int m=0;m<4;++m){
      acc[m] = __builtin_amdgcn_mfma_f32_16x16x32_bf16(al[m], bh, acc[m], 0,0,0);
      acc[m] = __builtin_amdgcn_mfma_f32_16x16x32_bf16(ah[m], bl, acc[m], 0,0,0);
      acc[m] = __builtin_amdgcn_mfma_f32_16x16x32_bf16(ah[m], bh, acc[m], 0,0,0);
    }
    #pragma unroll
    for (int m=0;m<4;++m){ ah[m] = ahn[m]; al[m] = aln[m]; }
  }

  if (ow < 55){
    float* op = out + ((size_t)b*64)*3025 + (size_t)oh*55 + ow;
    #pragma unroll
    for (int m=0;m<4;++m)
      #pragma unroll
      for (int r=0;r<4;++r){
        int oc = m*16 + lg*4 + r;
        op[(size_t)oc*3025] = fmaxf(acc[m][r], 0.f);
      }
  }
}

// ============== conv2 MFMA: tap-decomposed implicit GEMM, bf16x3 ==============
// A layout: [12 tiles][50 slices][64 lanes][8] — coalesced 1KB wave loads.
__global__ __launch_bounds__(256, 2) void conv2m_k(
    const float* __restrict__ in, const short* __restrict__ whi,
    const short* __restrict__ wlo, const float* __restrict__ bias,
    float* __restrict__ out)
{
  __shared__ __align__(16) short lds[2][217*72];   // 62496 B
  const int tid = threadIdx.x;
  const int rg  = blockIdx.x;          // 0..8
  const int b   = blockIdx.y;
  const int wid = tid >> 6;
  const int ln  = tid & 15;
  const int lg  = (tid & 63) >> 4;
  const int lane = tid & 63;
  const int oc0 = wid*48;
  const int r0  = rg*3;

  int sb[6], nn[6];
  #pragma unroll
  for (int t=0;t<6;++t){
    int n = t*16 + ln;
    nn[t] = n;
    int ohl = n / 27, ow = n % 27;
    sb[t] = (n < 81) ? (ohl*31 + ow) : 0;
  }

  f32x4 acc[3][6];
  #pragma unroll
  for (int m=0;m<3;++m){
    const float4 bv = *reinterpret_cast<const float4*>(bias + oc0 + m*16 + lg*4);
    #pragma unroll
    for (int t=0;t<6;++t) acc[m][t] = (f32x4){bv.x, bv.y, bv.z, bv.w};
  }

  const float* ip = in + (size_t)b*64*729;
  for (int i = tid; i < 217*64; i += 256){
    int c  = i / 217;
    int sp = i % 217;
    int prow = sp / 31, pcol = sp % 31;
    int ih = r0 - 2 + prow;
    int iw = pcol - 2;
    float v = 0.f;
    if (ih >= 0 && ih < 27 && iw >= 0 && iw < 27)
      v = ip[(size_t)c*729 + ih*27 + iw];
    short h, l; bsplit(v, h, l);
    lds[0][sp*72 + c] = h;
    lds[1][sp*72 + c] = l;
  }
  __syncthreads();

  #pragma unroll 1
  for (int tap=0; tap<25; ++tap){
    const int toff = (tap/5)*31 + (tap%5);
    #pragma unroll
    for (int h2=0; h2<2; ++h2){
      const size_t wo = (((size_t)(wid*3)*50 + tap*2 + h2)*64 + lane)*8;
      s16x8 ah0 = *reinterpret_cast<const s16x8*>(whi + wo);
      s16x8 ah1 = *reinterpret_cast<const s16x8*>(whi + wo + 25600);   // +1 tile = 50*512
      s16x8 ah2 = *reinterpret_cast<const s16x8*>(whi + wo + 51200);
      s16x8 al0 = *reinterpret_cast<const s16x8*>(wlo + wo);
      s16x8 al1 = *reinterpret_cast<const s16x8*>(wlo + wo + 25600);
      s16x8 al2 = *reinterpret_cast<const s16x8*>(wlo + wo + 51200);
      #pragma unroll
      for (int t=0;t<6;++t){
        int off = (sb[t] + toff)*72 + h2*32 + lg*8;
        s16x8 bh = *reinterpret_cast<const s16x8*>(&lds[0][off]);
        s16x8 bl = *reinterpret_cast<const s16x8*>(&lds[1][off]);
        acc[0][t] = __builtin_amdgcn_mfma_f32_16x16x32_bf16(al0, bh, acc[0][t], 0,0,0);
        acc[0][t] = __builtin_amdgcn_mfma_f32_16x16x32_bf16(ah0, bl, acc[0][t], 0,0,0);
        acc[0][t] = __builtin_amdgcn_mfma_f32_16x16x32_bf16(ah0, bh, acc[0][t], 0,0,0);
        acc[1][t] = __builtin_amdgcn_mfma_f32_16x16x32_bf16(al1, bh, acc[1][t], 0,0,0);
        acc[1][t] = __builtin_amdgcn_mfma_f32_16x16x32_bf16(ah1, bl, acc[1][t], 0,0,0);
        acc[1][t] = __builtin_amdgcn_mfma_f32_16x16x32_bf16(ah1, bh, acc[1][t], 0,0,0);
        acc[2][t] = __builtin_amdgcn_mfma_f32_16x16x32_bf16(al2, bh, acc[2][t], 0,0,0);
        acc[2][t] = __builtin_amdgcn_mfma_f32_16x16x32_bf16(ah2, bl, acc[2][t], 0,0,0);
        acc[2][t] = __builtin_amdgcn_mfma_f32_16x16x32_bf16(ah2, bh, acc[2][t], 0,0,0);
      }
    }
  }

  float* op = out + (size_t)b*192*729 + r0*27;
  #pragma unroll
  for (int m=0;m<3;++m)
    #pragma unroll
    for (int t=0;t<6;++t){
      if (nn[t] < 81){
        #pragma unroll
        for (int r=0;r<4;++r){
          int oc = oc0 + m*16 + lg*4 + r;
          op[(size_t)oc*729 + nn[t]] = fmaxf(acc[m][t][r], 0.f);
        }
      }
    }
}

// ============== conv3/4/5 MFMA: tap-decomposed implicit GEMM, bf16x3 ==========
// A layout: [O/16 tiles][9*(C/32) slices][64 lanes][8].
template<int C,int O>
__global__ __launch_bounds__(256, 2) void conv3m_k(
    const float* __restrict__ in, const short* __restrict__ whi,
    const short* __restrict__ wlo, const float* __restrict__ bias,
    float* __restrict__ out)
{
  __shared__ __align__(16) short lds[2][12000];
  const int tid = threadIdx.x;
  const int b   = blockIdx.y;
  const int wid = tid >> 6;
  const int ln  = tid & 15;
  const int lg  = (tid & 63) >> 4;
  const int lane = tid & 63;
  const int tileIdx = blockIdx.x*2 + (wid & 1);
  const int oc0 = tileIdx*16;
  const int ng  = wid >> 1;
  const int tbase  = ng ? 6 : 0;
  const int ntiles = ng ? 5 : 6;
  const int S3 = 9*(C/32);

  int sb[6], nn[6];
  #pragma unroll
  for (int t=0;t<6;++t){
    int n = (tbase + t)*16 + ln;
    nn[t] = n;
    int oh = n / 13, ow = n % 13;
    sb[t] = (n < 169) ? (oh*20 + ow) : 0;
  }

  f32x4 acc[6];
  const float4 bv = *reinterpret_cast<const float4*>(bias + oc0 + lg*4);
  #pragma unroll
  for (int t=0;t<6;++t) acc[t] = (f32x4){bv.x, bv.y, bv.z, bv.w};

  const float* ip = in + (size_t)b*C*169;

  #pragma unroll 1
  for (int c0=0; c0<C; c0+=32){
    __syncthreads();
    for (int i = tid; i < 32*300; i += 256){
      int c   = i / 300;
      int sp  = i % 300;
      int row = sp / 20, col = sp % 20;
      float v = 0.f;
      if (row >= 1 && row <= 13 && col >= 1 && col <= 13)
        v = ip[(size_t)(c0 + c)*169 + (row-1)*13 + (col-1)];
      short h, l; bsplit(v, h, l);
      lds[0][sp*40 + c] = h;
      lds[1][sp*40 + c] = l;
    }
    __syncthreads();

    const size_t tb = (size_t)tileIdx*S3 + (c0 >> 5);
    s16x8 ah = *reinterpret_cast<const s16x8*>(whi + (tb*64 + lane)*8);
    s16x8 al = *reinterpret_cast<const s16x8*>(wlo + (tb*64 + lane)*8);
    #pragma unroll 1
    for (int tap=0; tap<9; ++tap){
      s16x8 ahn = ah, aln = al;
      if (tap < 8){
        size_t ao = ((tb + (size_t)(tap+1)*(C/32))*64 + lane)*8;
        ahn = *reinterpret_cast<const s16x8*>(whi + ao);
        aln = *reinterpret_cast<const s16x8*>(wlo + ao);
      }
      const int toff = (tap/3)*20 + (tap%3);
      #pragma unroll
      for (int t=0;t<6;++t){
        if (t < ntiles){
          int off = (sb[t] + toff)*40 + lg*8;
          s16x8 bh = *reinterpret_cast<const s16x8*>(&lds[0][off]);
          s16x8 bl = *reinterpret_cast<const s16x8*>(&lds[1][off]);
          acc[t] = __builtin_amdgcn_mfma_f32_16x16x32_bf16(al, bh, acc[t], 0,0,0);
          acc[t] = __builtin_amdgcn_mfma_f32_16x16x32_bf16(ah, bl, acc[t], 0,0,0);
          acc[t] = __builtin_amdgcn_mfma_f32_16x16x32_bf16(ah, bh, acc[t], 0,0,0);
        }
      }
      ah = ahn; al = aln;
    }
  }

  float* op = out + ((size_t)b*O + oc0)*169;
  #pragma unroll
  for (int t=0;t<6;++t){
    if (t < ntiles && nn[t] < 169){
      #pragma unroll
      for (int r=0;r<4;++r)
        op[(size_t)(lg*4 + r)*169 + nn[t]] = fmaxf(acc[t][r], 0.f);
    }
  }
}

// ---------------- 3x3 stride-2 VALID maxpool ----------------
template<int HIN,int HOUT>
__global__ __launch_bounds__(TPB) void maxpool_k(
    const float* __restrict__ in, float* __restrict__ out, int nTotal)
{
  int idx = blockIdx.x*TPB + threadIdx.x;
  if (idx >= nTotal) return;
  int ow = idx % HOUT;
  int t  = idx / HOUT;
  int oh = t % HOUT;
  int ch = t / HOUT;
  const float* p = in + ((size_t)ch*HIN + oh*2)*HIN + ow*2;
  float m = -INFINITY;
  #pragma unroll
  for (int i=0;i<3;++i)
    #pragma unroll
    for (int j=0;j<3;++j)
      m = fmaxf(m, p[i*HIN + j]);
  out[idx] = m;
}

// ---------------- gate layer 1: one wave per (b,h), shuffle reduce ----------------
__global__ __launch_bounds__(256) void gate1_k(
    const float* __restrict__ feat, const float* __restrict__ gw1T,
    const float* __restrict__ gb1, float* __restrict__ g)
{
  const int b    = blockIdx.x;
  const int h    = blockIdx.y*4 + (threadIdx.x >> 6);
  const int lane = threadIdx.x & 63;
  const float* f = feat + (size_t)b*9216;
  const float* w = gw1T + (size_t)h*9216;
  float s = 0.f;
  #pragma unroll
  for (int it=0; it<36; ++it){
    int d = it*256 + lane*4;
    float4 fv = *reinterpret_cast<const float4*>(f + d);
    float4 wv = *reinterpret_cast<const float4*>(w + d);
    s = fmaf(fv.x, wv.x, s);
    s = fmaf(fv.y, wv.y, s);
    s = fmaf(fv.z, wv.z, s);
    s = fmaf(fv.w, wv.w, s);
  }
  #pragma unroll
  for (int off=32; off; off>>=1) s += __shfl_down(s, off, 64);
  if (lane == 0) g[(size_t)b*72 + h] = fmaxf(s + gb1[h], 0.f);
}

// ---------------- gate layer 2 + top-2 softmax (128 thr: 72-wide load!) ----
__global__ __launch_bounds__(128) void gate2_k(
    const float* __restrict__ g, const float* __restrict__ gw2,
    const float* __restrict__ gb2, float* __restrict__ gates)
{
  const int b = blockIdx.x;
  const int tid = threadIdx.x;
  __shared__ float gs[72];
  __shared__ float logits[8];
  if (tid < 72) gs[tid] = g[(size_t)b*72 + tid];
  __syncthreads();
  if (tid < 8) {
    float acc = gb2[tid];
    for (int j=0;j<72;++j)
      acc = fmaf(gs[j], gw2[(size_t)j*8 + tid], acc);
    logits[tid] = acc;
  }
  __syncthreads();
  if (tid == 0) {
    int i1 = 0; float v1 = logits[0];
    for (int e=1;e<8;++e) if (logits[e] > v1) { v1 = logits[e]; i1 = e; }
    int i2 = -1; float v2 = -INFINITY;
    for (int e=0;e<8;++e) { if (e==i1) continue; if (logits[e] > v2) { v2 = logits[e]; i2 = e; } }
    float z  = expf(v2 - v1);
    float w1 = 1.f / (1.f + z);
    float w2 = z   / (1.f + z);
    float* gr = gates + (size_t)b*8;
    for (int e=0;e<8;++e) gr[e] = 0.f;
    gr[i1] = w1;
    gr[i2] = w2;
  }
}

// ========== expert h1 dense split-K GEMM ==========
__global__ __launch_bounds__(256, 2) void eh1_part_k(
    const float* __restrict__ feat, const float* __restrict__ ew1,
    float* __restrict__ part)
{
  const int e  = blockIdx.x;
  const int ks = blockIdx.y;
  const int nb = blockIdx.z;
  const int h0 = nb*144;
  __shared__ __align__(16) float fs[64*33];
  __shared__ __align__(16) float wsh[32*144];
  const int tid = threadIdx.x;
  const int tx = tid & 15;
  const int ty = tid >> 4;
  float acc[4][9];
  #pragma unroll
  for (int i=0;i<4;++i)
    #pragma unroll
    for (int j=0;j<9;++j) acc[i][j]=0.f;
  const float* wbase = ew1 + (size_t)e*9216*288 + h0;
  for (int d0 = ks*576; d0 < ks*576+576; d0 += 32){
    __syncthreads();
    for (int l = tid; l < 512; l += 256){
      int r = l >> 3, c = l & 7;
      float4 v = *reinterpret_cast<const float4*>(feat + (size_t)r*9216 + d0 + c*4);
      float* dst = &fs[r*33 + c*4];
      dst[0]=v.x; dst[1]=v.y; dst[2]=v.z; dst[3]=v.w;
    }
    for (int l = tid; l < 1152; l += 256){
      int r = l / 36, c = l % 36;
      *reinterpret_cast<float4*>(&wsh[r*144 + c*4]) =
        *reinterpret_cast<const float4*>(wbase + (size_t)(d0 + r)*288 + c*4);
    }
    __syncthreads();
    #pragma unroll
    for (int k=0;k<32;++k){
      float fv[4], wv[9];
      #pragma unroll
      for (int i=0;i<4;++i) fv[i] = fs[(ty*4+i)*33 + k];
      #pragma unroll
      for (int j=0;j<9;++j) wv[j] = wsh[k*144 + tx*9 + j];
      #pragma unroll
      for (int i=0;i<4;++i)
        #pragma unroll
        for (int j=0;j<9;++j)
          acc[i][j] = fmaf(fv[i], wv[j], acc[i][j]);
    }
  }
  float* pp = part + (size_t)(ks*8 + e)*64*288;
  #pragma unroll
  for (int i=0;i<4;++i)
    #pragma unroll
    for (int j=0;j<9;++j)
      pp[(ty*4+i)*288 + h0 + tx*9 + j] = acc[i][j];
}

__global__ __launch_bounds__(TPB) void eh1_reduce_k(
    const float* __restrict__ part, const float* __restrict__ eb1,
    float* __restrict__ h1)
{
  int idx = blockIdx.x*TPB + threadIdx.x;
  if (idx >= 8*64*288) return;
  int h = idx % 288;
  int e = idx / (64*288);
  float a = eb1[(size_t)e*288 + h];
  #pragma unroll
  for (int s=0;s<16;++s)
    a += part[(size_t)s*147456 + idx];
  h1[idx] = fmaxf(a, 0.f);
}

// ---------------- expert h2 / out ----------------
__global__ __launch_bounds__(TPB) void expert_h2_k(
    const float* __restrict__ h1, const float* __restrict__ ew2,
    const float* __restrict__ eb2, const float* __restrict__ gates,
    float* __restrict__ h2)
{
  int idx = blockIdx.x*TPB + threadIdx.x;
  if (idx >= 8*64*144) return;
  int k = idx % 144;
  int t = idx / 144;
  int b = t % 64;
  int e = t / 64;
  if (gates[(size_t)b*8 + e] == 0.f) return;
  float acc = eb2[(size_t)e*144 + k];
  const float* h = h1 + ((size_t)e*64 + b)*288;
  const float* w = ew2 + (size_t)e*288*144 + k;
  for (int d=0; d<288; ++d)
    acc = fmaf(h[d], w[(size_t)d*144], acc);
  h2[idx] = fmaxf(acc, 0.f);
}

__global__ __launch_bounds__(TPB) void expert_out_k(
    const float* __restrict__ h2, const float* __restrict__ ew3,
    const float* __restrict__ eb3, const float* __restrict__ gates,
    float* __restrict__ out)
{
  int idx = blockIdx.x*TPB + threadIdx.x;
  if (idx >= 64*1000) return;
  int o = idx % 1000;
  int b = idx / 1000;
  float acc = 0.f;
  const float* gr = gates + (size_t)b*8;
  for (int e=0;e<8;++e){
    float ge = gr[e];
    if (ge == 0.f) continue;
    float a = eb3[(size_t)e*1000 + o];
    const float* h = h2 + ((size_t)e*64 + b)*144;
    const float* w = ew3 + (size_t)e*144*1000 + o;
    for (int k=0;k<144;++k)
      a = fmaf(h[k], w[(size_t)k*1000], a);
    acc = fmaf(ge, a, acc);
  }
  out[idx] = acc;
}

static inline int nblk(long long n){ return (int)((n + TPB - 1) / TPB); }

extern "C" void kernel_launch(void* const* d_in, const int* in_sizes, int n_in,
                              void* d_out, int out_size, void* d_ws, size_t ws_size,
                              hipStream_t stream)
{
  const float* x   = (const float*)d_in[0];
  const float* c1w = (const float*)d_in[1];  const float* c1b = (const float*)d_in[2];
  const float* c2w = (const float*)d_in[3];  const float* c2b = (const float*)d_in[4];
  const float* c3w = (const float*)d_in[5];  const float* c3b = (const float*)d_in[6];
  const float* c4w = (const float*)d_in[7];  const float* c4b = (const float*)d_in[8];
  const float* c5w = (const float*)d_in[9];  const float* c5b = (const float*)d_in[10];
  const float* gw1 = (const float*)d_in[11]; const float* gb1 = (const float*)d_in[12];
  const float* gw2 = (const float*)d_in[13]; const float* gb2 = (const float*)d_in[14];
  const float* ew1 = (const float*)d_in[15]; const float* eb1 = (const float*)d_in[16];
  const float* ew2 = (const float*)d_in[17]; const float* eb2 = (const float*)d_in[18];
  const float* ew3 = (const float*)d_in[19]; const float* eb3 = (const float*)d_in[20];
  float* out = (float*)d_out;

  const long long A_FLOATS = 12390400LL;
  const long long B_FLOATS = 2985984LL;
  float* A = (float*)d_ws;
  float* B = A + A_FLOATS;
  float* Cg = B + B_FLOATS;
  float* gates = Cg;                         // 512
  float* h1    = Cg + 512;                   // 147456
  float* h2    = h1 + 147456;                // 73728
  float* gbuf  = h2 + 73728;                 // 4608
  // conv1 split weights in B tail (B free until pool1; conv1m consumes first)
  short* WH1 = (short*)(B + 2900000);        // 36,864 sh
  short* WL1 = WH1 + 36864;
  // other split weights + gw1 transpose in A tail (dead after pool1)
  short* WH2 = (short*)(A +  9000000);
  short* WL2 = WH2 + 307200;
  short* WH3 = (short*)(A +  9400000);
  short* WL3 = WH3 + 663552;
  short* WH4 = (short*)(A + 10100000);
  short* WL4 = WH4 + 884736;
  short* WH5 = (short*)(A + 11000000);
  short* WL5 = WH5 + 589824;
  float* GT1 = A + 11600000;
  (void)ws_size; (void)in_sizes; (void)n_in; (void)out_size;

  const int B_ = 64;

  // conv1 weight prep (into B tail), then conv1 (MFMA): x -> A [64,64,55,55]
  wsplit1_k<<<nblk(64LL*576), TPB, 0, stream>>>(c1w, WH1, WL1);
  conv1m_k<<<55*64, 256, 0, stream>>>(x, WH1, WL1, c1b, A);
  // pool1: A -> B [64,64,27,27] (overwrites WH1/WL1 — already consumed)
  {
    long long n = (long long)B_*64*27*27;
    maxpool_k<55,27><<<nblk(n), TPB, 0, stream>>>(A, B, (int)n);
  }
  // weight prep into A tail (A dead now)
  wsplit_k<<<nblk(25LL*192*64),  TPB, 0, stream>>>(c2w, WH2, WL2,  64, 192, 25, 25*192*64);
  wsplit_k<<<nblk(9LL*384*192),  TPB, 0, stream>>>(c3w, WH3, WL3, 192, 384,  9, 9*384*192);
  wsplit_k<<<nblk(9LL*256*384),  TPB, 0, stream>>>(c4w, WH4, WL4, 384, 256,  9, 9*256*384);
  wsplit_k<<<nblk(9LL*256*256),  TPB, 0, stream>>>(c5w, WH5, WL5, 256, 256,  9, 9*256*256);
  wtrans_k<<<nblk(72LL*9216),    TPB, 0, stream>>>(gw1, GT1, 72, 9216);

  // conv2 (MFMA): B -> A [64,192,27,27]
  conv2m_k<<<dim3(9,64), 256, 0, stream>>>(B, WH2, WL2, c2b, A);
  // pool2: A -> B [64,192,13,13]
  {
    long long n = (long long)B_*192*13*13;
    maxpool_k<27,13><<<nblk(n), TPB, 0, stream>>>(A, B, (int)n);
  }
  // conv3 (MFMA): B -> A [64,384,13,13]
  conv3m_k<192,384><<<dim3(12,64), 256, 0, stream>>>(B, WH3, WL3, c3b, A);
  // conv4 (MFMA): A -> B [64,256,13,13]
  conv3m_k<384,256><<<dim3(8,64), 256, 0, stream>>>(A, WH4, WL4, c4b, B);
  // conv5 (MFMA): B -> A [64,256,13,13]
  conv3m_k<256,256><<<dim3(8,64), 256, 0, stream>>>(B, WH5, WL5, c5b, A);
  // pool3: A -> B = feat [64,9216]
  {
    long long n = (long long)B_*256*6*6;
    maxpool_k<13,6><<<nblk(n), TPB, 0, stream>>>(A, B, (int)n);
  }
  const float* feat = B;

  // gate
  gate1_k<<<dim3(64,18), 256, 0, stream>>>(feat, GT1, gb1, gbuf);
  gate2_k<<<64, 128, 0, stream>>>(gbuf, gw2, gb2, gates);

  // experts
  float* part = A;
  eh1_part_k<<<dim3(8,16,2), 256, 0, stream>>>(feat, ew1, part);
  eh1_reduce_k<<<nblk(8LL*64*288), TPB, 0, stream>>>(part, eb1, h1);
  expert_h2_k<<<nblk(8LL*64*144), TPB, 0, stream>>>(h1, ew2, eb2, gates, h2);
  expert_out_k<<<nblk(64LL*1000), TPB, 0, stream>>>(h2, ew3, eb3, gates, out);
}

// Round 12
// 633.030 us; speedup vs baseline: 1.7206x; 1.4619x over previous
//
#include <hip/hip_runtime.h>
#include <math.h>

#define TPB 256

typedef short s16x8 __attribute__((ext_vector_type(8)));
typedef short s16x4 __attribute__((ext_vector_type(4)));
typedef float f32x4 __attribute__((ext_vector_type(4)));

__device__ inline void bsplit(float x, short& h, short& l){
  union { float f; unsigned u; } a, hf, rf;
  a.f = x;
  unsigned hu = (a.u + 0x7FFFu + ((a.u >> 16) & 1u)) >> 16;
  h = (short)hu;
  hf.u = hu << 16;
  rf.f = x - hf.f;
  l = (short)((rf.u + 0x7FFFu + ((rf.u >> 16) & 1u)) >> 16);
}
__device__ inline float b2f(short s){
  union { unsigned u; float f; } x;
  x.u = ((unsigned)(unsigned short)s) << 16;
  return x.f;
}

// ==== weight split + MFMA-native reorder (as round 11) ====
__global__ __launch_bounds__(TPB) void wsplit_k(
    const float* __restrict__ w, short* __restrict__ wh, short* __restrict__ wl,
    int C, int O, int ntap, int total)
{
  int idx = blockIdx.x*TPB + threadIdx.x;
  if (idx >= total) return;
  int c   = idx % C;
  int t2  = idx / C;
  int oc  = t2 % O;
  int tap = t2 / O;
  float x = w[((size_t)oc*C + c)*ntap + tap];
  short h, l; bsplit(x, h, l);
  int tile = oc >> 4, ln = oc & 15;
  int S    = ntap*(C >> 5);
  int sl   = tap*(C >> 5) + (c >> 5);
  int lg   = (c >> 3) & 3, j = c & 7;
  size_t dst = (((size_t)tile*S + sl)*64 + lg*16 + ln)*8 + j;
  wh[dst] = h; wl[dst] = l;
}

__global__ __launch_bounds__(TPB) void wsplit1_k(
    const float* __restrict__ w, short* __restrict__ wh, short* __restrict__ wl)
{
  int idx = blockIdx.x*TPB + threadIdx.x;
  if (idx >= 64*576) return;
  int k  = idx % 576;
  int oc = idx / 576;
  int g  = k >> 4, kw = k & 15;
  int c  = g / 12, kh = g % 12;
  float x = 0.f;
  if (kh < 11 && kw < 11)
    x = w[((size_t)oc*3 + c)*121 + kh*11 + kw];
  short h, l; bsplit(x, h, l);
  int m = oc >> 4, ln = oc & 15;
  int s = k >> 5, r = k & 31;
  int lg = r >> 3, j = r & 7;
  size_t dst = (((size_t)m*18 + s)*64 + lg*16 + ln)*8 + j;
  wh[dst] = h; wl[dst] = l;
}

__global__ __launch_bounds__(TPB) void wtrans_k(
    const float* __restrict__ w, float* __restrict__ wT, int K, int O)
{
  int idx = blockIdx.x*TPB + threadIdx.x;
  if (idx >= K*O) return;
  int oc = idx % O;
  int k  = idx / O;
  wT[idx] = w[(size_t)oc*K + k];
}

// ============== conv1 MFMA (im2col along kw); out: split ch-minor [3025][64] ====
#define C1W 240
#define CV1_PL 33
__global__ __launch_bounds__(256, 2) void conv1m_k(
    const float* __restrict__ in, const short* __restrict__ whi,
    const short* __restrict__ wlo, const float* __restrict__ bias,
    short* __restrict__ yh, short* __restrict__ yl)
{
  __shared__ __align__(16) short lds[2][CV1_PL*C1W + 84];
  const int tid = threadIdx.x;
  const int oh = blockIdx.x % 55;
  const int b  = blockIdx.x / 55;
  const int nt = tid >> 6;
  const int ln = tid & 15;
  const int lg = (tid & 63) >> 4;
  const int lane = tid & 63;
  const int ow = nt*16 + ln;

  const float* ip = in + (size_t)b*3*224*224;
  for (int i = tid; i < CV1_PL*59; i += 256){
    int plane = i / 59;
    int p     = i % 59;
    int c = plane / 11, kh = plane % 11;
    int ih = oh*4 - 2 + kh;
    int col0 = p*4;
    const float* rowp = (ih >= 0 && ih < 224) ? ip + (size_t)c*50176 + (size_t)ih*224 : nullptr;
    short h[4], l[4];
    #pragma unroll
    for (int j=0;j<4;++j){
      int iw = col0 + j - 2;
      float v = (rowp && iw >= 0 && iw < 224) ? rowp[iw] : 0.f;
      bsplit(v, h[j], l[j]);
    }
    s16x4 hv = {h[0],h[1],h[2],h[3]}, lv = {l[0],l[1],l[2],l[3]};
    *reinterpret_cast<s16x4*>(&lds[0][plane*C1W + col0]) = hv;
    *reinterpret_cast<s16x4*>(&lds[1][plane*C1W + col0]) = lv;
  }
  __syncthreads();

  f32x4 acc[4];
  #pragma unroll
  for (int m=0;m<4;++m){
    const float4 bv = *reinterpret_cast<const float4*>(bias + m*16 + lg*4);
    acc[m] = (f32x4){bv.x, bv.y, bv.z, bv.w};
  }

  s16x8 ah[4], al[4], ahn[4], aln[4];
  #pragma unroll
  for (int m=0;m<4;++m){
    size_t ao = (((size_t)m*18 + 0)*64 + lane)*8;
    ah[m] = *reinterpret_cast<const s16x8*>(whi + ao);
    al[m] = *reinterpret_cast<const s16x8*>(wlo + ao);
  }

  #pragma unroll 1
  for (int s=0; s<18; ++s){
    if (s < 17){
      #pragma unroll
      for (int m=0;m<4;++m){
        size_t ao = (((size_t)m*18 + s + 1)*64 + lane)*8;
        ahn[m] = *reinterpret_cast<const s16x8*>(whi + ao);
        aln[m] = *reinterpret_cast<const s16x8*>(wlo + ao);
      }
    }
    int g  = 2*s + (lg >> 1);
    int c  = g / 12, kh = g % 12;
    int plane = c*11 + (kh < 11 ? kh : 10);
    int base  = plane*C1W + ow*4 + (lg & 1)*8;
    s16x4 h0 = *reinterpret_cast<const s16x4*>(&lds[0][base]);
    s16x4 h1 = *reinterpret_cast<const s16x4*>(&lds[0][base+4]);
    s16x4 l0 = *reinterpret_cast<const s16x4*>(&lds[1][base]);
    s16x4 l1 = *reinterpret_cast<const s16x4*>(&lds[1][base+4]);
    s16x8 bh = __builtin_shufflevector(h0, h1, 0,1,2,3,4,5,6,7);
    s16x8 bl = __builtin_shufflevector(l0, l1, 0,1,2,3,4,5,6,7);
    #pragma unroll
    for (int m=0;m<4;++m){
      acc[m] = __builtin_amdgcn_mfma_f32_16x16x32_bf16(al[m], bh, acc[m], 0,0,0);
      acc[m] = __builtin_amdgcn_mfma_f32_16x16x32_bf16(ah[m], bl, acc[m], 0,0,0);
      acc[m] = __builtin_amdgcn_mfma_f32_16x16x32_bf16(ah[m], bh, acc[m], 0,0,0);
    }
    #pragma unroll
    for (int m=0;m<4;++m){ ah[m] = ahn[m]; al[m] = aln[m]; }
  }

  if (ow < 55){
    size_t base = ((size_t)b*3025 + (size_t)oh*55 + ow)*64;
    #pragma unroll
    for (int m=0;m<4;++m){
      short h[4], l[4];
      #pragma unroll
      for (int r=0;r<4;++r) bsplit(fmaxf(acc[m][r], 0.f), h[r], l[r]);
      s16x4 hv = {h[0],h[1],h[2],h[3]}, lv = {l[0],l[1],l[2],l[3]};
      *reinterpret_cast<s16x4*>(yh + base + m*16 + lg*4) = hv;
      *reinterpret_cast<s16x4*>(yl + base + m*16 + lg*4) = lv;
    }
  }
}

// ---- pool1: X1[3025][64] split -> X2[729][64] split (ch-minor, coalesced) ----
__global__ __launch_bounds__(TPB) void pool1_k(
    const short* __restrict__ xh, const short* __restrict__ xl,
    short* __restrict__ yh, short* __restrict__ yl)
{
  int i = blockIdx.x*TPB + threadIdx.x;
  if (i >= 64*729*64) return;
  int c = i & 63;
  int t = i >> 6;
  int sp = t % 729;
  int b = t / 729;
  int r = sp/27, cc = sp%27;
  const short* ph = xh + (size_t)b*3025*64 + c;
  const short* pl = xl + (size_t)b*3025*64 + c;
  float m = -INFINITY;
  #pragma unroll
  for (int di=0;di<3;++di)
    #pragma unroll
    for (int dj=0;dj<3;++dj){
      size_t s = (size_t)((2*r+di)*55 + 2*cc+dj)*64;
      m = fmaxf(m, b2f(ph[s]) + b2f(pl[s]));
    }
  short h, l; bsplit(m, h, l);
  yh[i] = h; yl[i] = l;
}

// ============== conv2 MFMA; in: X2 split [729][64]; out: X3 split [729][192] ====
__global__ __launch_bounds__(256, 2) void conv2m_k(
    const short* __restrict__ xh, const short* __restrict__ xl,
    const short* __restrict__ whi, const short* __restrict__ wlo,
    const float* __restrict__ bias, short* __restrict__ yh, short* __restrict__ yl)
{
  __shared__ __align__(16) short lds[2][217*72];
  const int tid = threadIdx.x;
  const int rg  = blockIdx.x;
  const int b   = blockIdx.y;
  const int wid = tid >> 6;
  const int ln  = tid & 15;
  const int lg  = (tid & 63) >> 4;
  const int lane = tid & 63;
  const int oc0 = wid*48;
  const int r0  = rg*3;

  int sb[6], nn[6];
  #pragma unroll
  for (int t=0;t<6;++t){
    int n = t*16 + ln;
    nn[t] = n;
    int ohl = n / 27, ow = n % 27;
    sb[t] = (n < 81) ? (ohl*31 + ow) : 0;
  }

  f32x4 acc[3][6];
  #pragma unroll
  for (int m=0;m<3;++m){
    const float4 bv = *reinterpret_cast<const float4*>(bias + oc0 + m*16 + lg*4);
    #pragma unroll
    for (int t=0;t<6;++t) acc[m][t] = (f32x4){bv.x, bv.y, bv.z, bv.w};
  }

  // stage: pure vector copy from split ch-minor global
  for (int i = tid; i < 217*8; i += 256){
    int sp = i >> 3, v = i & 7;
    int pr = sp/31, pc = sp%31;
    int ih = r0 - 2 + pr, iw = pc - 2;
    s16x8 hv = {0,0,0,0,0,0,0,0}, lv = {0,0,0,0,0,0,0,0};
    if (ih >= 0 && ih < 27 && iw >= 0 && iw < 27){
      size_t o = ((size_t)b*729 + ih*27 + iw)*64 + v*8;
      hv = *reinterpret_cast<const s16x8*>(xh + o);
      lv = *reinterpret_cast<const s16x8*>(xl + o);
    }
    *reinterpret_cast<s16x8*>(&lds[0][sp*72 + v*8]) = hv;
    *reinterpret_cast<s16x8*>(&lds[1][sp*72 + v*8]) = lv;
  }
  __syncthreads();

  #pragma unroll 1
  for (int tap=0; tap<25; ++tap){
    const int toff = (tap/5)*31 + (tap%5);
    #pragma unroll
    for (int h2=0; h2<2; ++h2){
      const size_t wo = (((size_t)(wid*3)*50 + tap*2 + h2)*64 + lane)*8;
      s16x8 ah0 = *reinterpret_cast<const s16x8*>(whi + wo);
      s16x8 ah1 = *reinterpret_cast<const s16x8*>(whi + wo + 25600);
      s16x8 ah2 = *reinterpret_cast<const s16x8*>(whi + wo + 51200);
      s16x8 al0 = *reinterpret_cast<const s16x8*>(wlo + wo);
      s16x8 al1 = *reinterpret_cast<const s16x8*>(wlo + wo + 25600);
      s16x8 al2 = *reinterpret_cast<const s16x8*>(wlo + wo + 51200);
      #pragma unroll
      for (int t=0;t<6;++t){
        int off = (sb[t] + toff)*72 + h2*32 + lg*8;
        s16x8 bh = *reinterpret_cast<const s16x8*>(&lds[0][off]);
        s16x8 bl = *reinterpret_cast<const s16x8*>(&lds[1][off]);
        acc[0][t] = __builtin_amdgcn_mfma_f32_16x16x32_bf16(al0, bh, acc[0][t], 0,0,0);
        acc[0][t] = __builtin_amdgcn_mfma_f32_16x16x32_bf16(ah0, bl, acc[0][t], 0,0,0);
        acc[0][t] = __builtin_amdgcn_mfma_f32_16x16x32_bf16(ah0, bh, acc[0][t], 0,0,0);
        acc[1][t] = __builtin_amdgcn_mfma_f32_16x16x32_bf16(al1, bh, acc[1][t], 0,0,0);
        acc[1][t] = __builtin_amdgcn_mfma_f32_16x16x32_bf16(ah1, bl, acc[1][t], 0,0,0);
        acc[1][t] = __builtin_amdgcn_mfma_f32_16x16x32_bf16(ah1, bh, acc[1][t], 0,0,0);
        acc[2][t] = __builtin_amdgcn_mfma_f32_16x16x32_bf16(al2, bh, acc[2][t], 0,0,0);
        acc[2][t] = __builtin_amdgcn_mfma_f32_16x16x32_bf16(ah2, bl, acc[2][t], 0,0,0);
        acc[2][t] = __builtin_amdgcn_mfma_f32_16x16x32_bf16(ah2, bh, acc[2][t], 0,0,0);
      }
    }
  }

  #pragma unroll
  for (int m=0;m<3;++m)
    #pragma unroll
    for (int t=0;t<6;++t){
      if (nn[t] < 81){
        int gsp = r0*27 + nn[t];
        size_t base = ((size_t)b*729 + gsp)*192 + oc0 + m*16 + lg*4;
        short h[4], l[4];
        #pragma unroll
        for (int r=0;r<4;++r) bsplit(fmaxf(acc[m][t][r], 0.f), h[r], l[r]);
        s16x4 hv = {h[0],h[1],h[2],h[3]}, lv = {l[0],l[1],l[2],l[3]};
        *reinterpret_cast<s16x4*>(yh + base) = hv;
        *reinterpret_cast<s16x4*>(yl + base) = lv;
      }
    }
}

// ---- pool2: X3[729][192] split -> X4[169][192] split ----
__global__ __launch_bounds__(TPB) void pool2_k(
    const short* __restrict__ xh, const short* __restrict__ xl,
    short* __restrict__ yh, short* __restrict__ yl)
{
  int i = blockIdx.x*TPB + threadIdx.x;
  if (i >= 64*169*192) return;
  int c = i % 192;
  int t = i / 192;
  int sp = t % 169;
  int b = t / 169;
  int r = sp/13, cc = sp%13;
  const short* ph = xh + (size_t)b*729*192 + c;
  const short* pl = xl + (size_t)b*729*192 + c;
  float m = -INFINITY;
  #pragma unroll
  for (int di=0;di<3;++di)
    #pragma unroll
    for (int dj=0;dj<3;++dj){
      size_t s = (size_t)((2*r+di)*27 + 2*cc+dj)*192;
      m = fmaxf(m, b2f(ph[s]) + b2f(pl[s]));
    }
  short h, l; bsplit(m, h, l);
  yh[i] = h; yl[i] = l;
}

// ============== conv3/4/5 MFMA; in: split ch-minor [169][C]; out: [169][O] =====
template<int C,int O>
__global__ __launch_bounds__(256, 3) void conv3m_k(
    const short* __restrict__ xh, const short* __restrict__ xl,
    const short* __restrict__ whi, const short* __restrict__ wlo,
    const float* __restrict__ bias, short* __restrict__ yh, short* __restrict__ yl)
{
  __shared__ __align__(16) short lds[2][225*40];   // 36 KB total
  const int tid = threadIdx.x;
  const int b   = blockIdx.y;
  const int wid = tid >> 6;
  const int ln  = tid & 15;
  const int lg  = (tid & 63) >> 4;
  const int lane = tid & 63;
  const int tileIdx = blockIdx.x*2 + (wid & 1);
  const int oc0 = tileIdx*16;
  const int ng  = wid >> 1;
  const int tbase  = ng ? 6 : 0;
  const int ntiles = ng ? 5 : 6;
  const int S3 = 9*(C/32);

  int sb[6], nn[6];
  #pragma unroll
  for (int t=0;t<6;++t){
    int n = (tbase + t)*16 + ln;
    nn[t] = n;
    int oh = n / 13, ow = n % 13;
    sb[t] = (n < 169) ? (oh*15 + ow) : 0;
  }

  f32x4 acc[6];
  const float4 bv = *reinterpret_cast<const float4*>(bias + oc0 + lg*4);
  #pragma unroll
  for (int t=0;t<6;++t) acc[t] = (f32x4){bv.x, bv.y, bv.z, bv.w};

  #pragma unroll 1
  for (int c0=0; c0<C; c0+=32){
    __syncthreads();
    // stage 32 channels: vector copy, padded [15][15] plane
    for (int i = tid; i < 225*4; i += 256){
      int sp = i >> 2, v = i & 3;
      int r = sp/15, cc = sp%15;
      s16x8 hv = {0,0,0,0,0,0,0,0}, lv = {0,0,0,0,0,0,0,0};
      if (r >= 1 && r <= 13 && cc >= 1 && cc <= 13){
        size_t o = ((size_t)b*169 + (r-1)*13 + (cc-1))*C + c0 + v*8;
        hv = *reinterpret_cast<const s16x8*>(xh + o);
        lv = *reinterpret_cast<const s16x8*>(xl + o);
      }
      *reinterpret_cast<s16x8*>(&lds[0][sp*40 + v*8]) = hv;
      *reinterpret_cast<s16x8*>(&lds[1][sp*40 + v*8]) = lv;
    }
    __syncthreads();

    const size_t tb = (size_t)tileIdx*S3 + (c0 >> 5);
    s16x8 ah = *reinterpret_cast<const s16x8*>(whi + (tb*64 + lane)*8);
    s16x8 al = *reinterpret_cast<const s16x8*>(wlo + (tb*64 + lane)*8);
    #pragma unroll 1
    for (int tap=0; tap<9; ++tap){
      s16x8 ahn = ah, aln = al;
      if (tap < 8){
        size_t ao = ((tb + (size_t)(tap+1)*(C/32))*64 + lane)*8;
        ahn = *reinterpret_cast<const s16x8*>(whi + ao);
        aln = *reinterpret_cast<const s16x8*>(wlo + ao);
      }
      const int toff = (tap/3)*15 + (tap%3);
      #pragma unroll
      for (int t=0;t<6;++t){
        if (t < ntiles){
          int off = (sb[t] + toff)*40 + lg*8;
          s16x8 bh = *reinterpret_cast<const s16x8*>(&lds[0][off]);
          s16x8 bl = *reinterpret_cast<const s16x8*>(&lds[1][off]);
          acc[t] = __builtin_amdgcn_mfma_f32_16x16x32_bf16(al, bh, acc[t], 0,0,0);
          acc[t] = __builtin_amdgcn_mfma_f32_16x16x32_bf16(ah, bl, acc[t], 0,0,0);
          acc[t] = __builtin_amdgcn_mfma_f32_16x16x32_bf16(ah, bh, acc[t], 0,0,0);
        }
      }
      ah = ahn; al = aln;
    }
  }

  #pragma unroll
  for (int t=0;t<6;++t){
    if (t < ntiles && nn[t] < 169){
      size_t base = ((size_t)b*169 + nn[t])*O + oc0 + lg*4;
      short h[4], l[4];
      #pragma unroll
      for (int r=0;r<4;++r) bsplit(fmaxf(acc[t][r], 0.f), h[r], l[r]);
      s16x4 hv = {h[0],h[1],h[2],h[3]}, lv = {l[0],l[1],l[2],l[3]};
      *reinterpret_cast<s16x4*>(yh + base) = hv;
      *reinterpret_cast<s16x4*>(yl + base) = lv;
    }
  }
}

// ---- pool3: X7[169][256] split -> feat[b][9216] f32 (d = c*36 + sp) ----
__global__ __launch_bounds__(TPB) void pool3_k(
    const short* __restrict__ xh, const short* __restrict__ xl,
    float* __restrict__ feat)
{
  int i = blockIdx.x*TPB + threadIdx.x;
  if (i >= 64*9216) return;
  int d = i % 9216;
  int b = i / 9216;
  int c = d / 36;
  int sp = d % 36;
  int r = sp/6, cc = sp%6;
  const short* ph = xh + (size_t)b*169*256 + c;
  const short* pl = xl + (size_t)b*169*256 + c;
  float m = -INFINITY;
  #pragma unroll
  for (int di=0;di<3;++di)
    #pragma unroll
    for (int dj=0;dj<3;++dj){
      size_t s = (size_t)((2*r+di)*13 + 2*cc+dj)*256;
      m = fmaxf(m, b2f(ph[s]) + b2f(pl[s]));
    }
  feat[i] = m;
}

// ---------------- gate ----------------
__global__ __launch_bounds__(256) void gate1_k(
    const float* __restrict__ feat, const float* __restrict__ gw1T,
    const float* __restrict__ gb1, float* __restrict__ g)
{
  const int b    = blockIdx.x;
  const int h    = blockIdx.y*4 + (threadIdx.x >> 6);
  const int lane = threadIdx.x & 63;
  const float* f = feat + (size_t)b*9216;
  const float* w = gw1T + (size_t)h*9216;
  float s = 0.f;
  #pragma unroll
  for (int it=0; it<36; ++it){
    int d = it*256 + lane*4;
    float4 fv = *reinterpret_cast<const float4*>(f + d);
    float4 wv = *reinterpret_cast<const float4*>(w + d);
    s = fmaf(fv.x, wv.x, s);
    s = fmaf(fv.y, wv.y, s);
    s = fmaf(fv.z, wv.z, s);
    s = fmaf(fv.w, wv.w, s);
  }
  #pragma unroll
  for (int off=32; off; off>>=1) s += __shfl_down(s, off, 64);
  if (lane == 0) g[(size_t)b*72 + h] = fmaxf(s + gb1[h], 0.f);
}

__global__ __launch_bounds__(128) void gate2_k(
    const float* __restrict__ g, const float* __restrict__ gw2,
    const float* __restrict__ gb2, float* __restrict__ gates)
{
  const int b = blockIdx.x;
  const int tid = threadIdx.x;
  __shared__ float gs[72];
  __shared__ float logits[8];
  if (tid < 72) gs[tid] = g[(size_t)b*72 + tid];
  __syncthreads();
  if (tid < 8) {
    float acc = gb2[tid];
    for (int j=0;j<72;++j)
      acc = fmaf(gs[j], gw2[(size_t)j*8 + tid], acc);
    logits[tid] = acc;
  }
  __syncthreads();
  if (tid == 0) {
    int i1 = 0; float v1 = logits[0];
    for (int e=1;e<8;++e) if (logits[e] > v1) { v1 = logits[e]; i1 = e; }
    int i2 = -1; float v2 = -INFINITY;
    for (int e=0;e<8;++e) { if (e==i1) continue; if (logits[e] > v2) { v2 = logits[e]; i2 = e; } }
    float z  = expf(v2 - v1);
    float w1 = 1.f / (1.f + z);
    float w2 = z   / (1.f + z);
    float* gr = gates + (size_t)b*8;
    for (int e=0;e<8;++e) gr[e] = 0.f;
    gr[i1] = w1;
    gr[i2] = w2;
  }
}

// ========== expert h1 dense split-K GEMM ==========
__global__ __launch_bounds__(256, 2) void eh1_part_k(
    const float* __restrict__ feat, const float* __restrict__ ew1,
    float* __restrict__ part)
{
  const int e  = blockIdx.x;
  const int ks = blockIdx.y;
  const int nb = blockIdx.z;
  const int h0 = nb*144;
  __shared__ __align__(16) float fs[64*33];
  __shared__ __align__(16) float wsh[32*144];
  const int tid = threadIdx.x;
  const int tx = tid & 15;
  const int ty = tid >> 4;
  float acc[4][9];
  #pragma unroll
  for (int i=0;i<4;++i)
    #pragma unroll
    for (int j=0;j<9;++j) acc[i][j]=0.f;
  const float* wbase = ew1 + (size_t)e*9216*288 + h0;
  for (int d0 = ks*576; d0 < ks*576+576; d0 += 32){
    __syncthreads();
    for (int l = tid; l < 512; l += 256){
      int r = l >> 3, c = l & 7;
      float4 v = *reinterpret_cast<const float4*>(feat + (size_t)r*9216 + d0 + c*4);
      float* dst = &fs[r*33 + c*4];
      dst[0]=v.x; dst[1]=v.y; dst[2]=v.z; dst[3]=v.w;
    }
    for (int l = tid; l < 1152; l += 256){
      int r = l / 36, c = l % 36;
      *reinterpret_cast<float4*>(&wsh[r*144 + c*4]) =
        *reinterpret_cast<const float4*>(wbase + (size_t)(d0 + r)*288 + c*4);
    }
    __syncthreads();
    #pragma unroll
    for (int k=0;k<32;++k){
      float fv[4], wv[9];
      #pragma unroll
      for (int i=0;i<4;++i) fv[i] = fs[(ty*4+i)*33 + k];
      #pragma unroll
      for (int j=0;j<9;++j) wv[j] = wsh[k*144 + tx*9 + j];
      #pragma unroll
      for (int i=0;i<4;++i)
        #pragma unroll
        for (int j=0;j<9;++j)
          acc[i][j] = fmaf(fv[i], wv[j], acc[i][j]);
    }
  }
  float* pp = part + (size_t)(ks*8 + e)*64*288;
  #pragma unroll
  for (int i=0;i<4;++i)
    #pragma unroll
    for (int j=0;j<9;++j)
      pp[(ty*4+i)*288 + h0 + tx*9 + j] = acc[i][j];
}

__global__ __launch_bounds__(TPB) void eh1_reduce_k(
    const float* __restrict__ part, const float* __restrict__ eb1,
    float* __restrict__ h1)
{
  int idx = blockIdx.x*TPB + threadIdx.x;
  if (idx >= 8*64*288) return;
  int h = idx % 288;
  int e = idx / (64*288);
  float a = eb1[(size_t)e*288 + h];
  #pragma unroll
  for (int s=0;s<16;++s)
    a += part[(size_t)s*147456 + idx];
  h1[idx] = fmaxf(a, 0.f);
}

__global__ __launch_bounds__(TPB) void expert_h2_k(
    const float* __restrict__ h1, const float* __restrict__ ew2,
    const float* __restrict__ eb2, const float* __restrict__ gates,
    float* __restrict__ h2)
{
  int idx = blockIdx.x*TPB + threadIdx.x;
  if (idx >= 8*64*144) return;
  int k = idx % 144;
  int t = idx / 144;
  int b = t % 64;
  int e = t / 64;
  if (gates[(size_t)b*8 + e] == 0.f) return;
  float acc = eb2[(size_t)e*144 + k];
  const float* h = h1 + ((size_t)e*64 + b)*288;
  const float* w = ew2 + (size_t)e*288*144 + k;
  for (int d=0; d<288; ++d)
    acc = fmaf(h[d], w[(size_t)d*144], acc);
  h2[idx] = fmaxf(acc, 0.f);
}

__global__ __launch_bounds__(TPB) void expert_out_k(
    const float* __restrict__ h2, const float* __restrict__ ew3,
    const float* __restrict__ eb3, const float* __restrict__ gates,
    float* __restrict__ out)
{
  int idx = blockIdx.x*TPB + threadIdx.x;
  if (idx >= 64*1000) return;
  int o = idx % 1000;
  int b = idx / 1000;
  float acc = 0.f;
  const float* gr = gates + (size_t)b*8;
  for (int e=0;e<8;++e){
    float ge = gr[e];
    if (ge == 0.f) continue;
    float a = eb3[(size_t)e*1000 + o];
    const float* h = h2 + ((size_t)e*64 + b)*144;
    const float* w = ew3 + (size_t)e*144*1000 + o;
    for (int k=0;k<144;++k)
      a = fmaf(h[k], w[(size_t)k*1000], a);
    acc = fmaf(ge, a, acc);
  }
  out[idx] = acc;
}

static inline int nblk(long long n){ return (int)((n + TPB - 1) / TPB); }

extern "C" void kernel_launch(void* const* d_in, const int* in_sizes, int n_in,
                              void* d_out, int out_size, void* d_ws, size_t ws_size,
                              hipStream_t stream)
{
  const float* x   = (const float*)d_in[0];
  const float* c1w = (const float*)d_in[1];  const float* c1b = (const float*)d_in[2];
  const float* c2w = (const float*)d_in[3];  const float* c2b = (const float*)d_in[4];
  const float* c3w = (const float*)d_in[5];  const float* c3b = (const float*)d_in[6];
  const float* c4w = (const float*)d_in[7];  const float* c4b = (const float*)d_in[8];
  const float* c5w = (const float*)d_in[9];  const float* c5b = (const float*)d_in[10];
  const float* gw1 = (const float*)d_in[11]; const float* gb1 = (const float*)d_in[12];
  const float* gw2 = (const float*)d_in[13]; const float* gb2 = (const float*)d_in[14];
  const float* ew1 = (const float*)d_in[15]; const float* eb1 = (const float*)d_in[16];
  const float* ew2 = (const float*)d_in[17]; const float* eb2 = (const float*)d_in[18];
  const float* ew3 = (const float*)d_in[19]; const float* eb3 = (const float*)d_in[20];
  float* out = (float*)d_out;

  float* W = (float*)d_ws;
  // activations (split bf16 hi/lo, channel-minor); region reuse by lifetime
  short* X1H = (short*)W;                  // [64][3025][64]  (conv1 out)
  short* X1L = X1H + 12390400;
  short* X3H = (short*)W;                  // [64][729][192]  (conv2 out; X1 dead)
  short* X3L = X3H + 8957952;
  short* X5H = (short*)W;                  // [64][169][384]  (conv3 out; X3 dead)
  short* X5L = X5H + 4153344;
  short* X7H = (short*)W;                  // [64][169][256]  (conv5 out; X5 dead)
  short* X7L = X7H + 2768896;
  float* feat  = W + 5000000;              // 589,824
  float* part  = W + 6000000;              // 2,359,296
  float* gates = W + 8400000;              // 512
  float* h1    = gates + 512;              // 147,456
  float* h2    = h1 + 147456;              // 73,728
  float* gbuf  = h2 + 73728;               // 4,608
  // weight zone (written after pool1; X1 tail dead by then)
  short* WH2 = (short*)(W +  9000000);     // 307,200
  short* WL2 = WH2 + 307200;
  short* WH3 = (short*)(W +  9320000);     // 663,552
  short* WL3 = WH3 + 663552;
  short* WH4 = (short*)(W + 10000000);     // 884,736
  short* WL4 = WH4 + 884736;
  short* WH5 = (short*)(W + 10900000);     // 589,824
  short* WL5 = WH5 + 589824;
  float* GT1 = W + 11500000;               // 663,552
  // B zone (after X1): X2/X4/X6 alternate
  short* X2H = (short*)(W + 12390400);     // [64][729][64]
  short* X2L = X2H + 2985984;
  short* X4H = (short*)(W + 12390400);     // [64][169][192]
  short* X4L = X4H + 2076672;
  short* X6H = (short*)(W + 12390400);     // [64][169][256]
  short* X6L = X6H + 2768896;
  short* WH1 = (short*)(W + 15400000);     // 36,864
  short* WL1 = WH1 + 36864;
  (void)ws_size; (void)in_sizes; (void)n_in; (void)out_size;

  // conv1 (MFMA) -> X1 split
  wsplit1_k<<<nblk(64LL*576), TPB, 0, stream>>>(c1w, WH1, WL1);
  conv1m_k<<<55*64, 256, 0, stream>>>(x, WH1, WL1, c1b, X1H, X1L);
  // pool1 -> X2 split
  pool1_k<<<nblk(64LL*729*64), TPB, 0, stream>>>(X1H, X1L, X2H, X2L);
  // weight prep (X1 dead)
  wsplit_k<<<nblk(25LL*192*64),  TPB, 0, stream>>>(c2w, WH2, WL2,  64, 192, 25, 25*192*64);
  wsplit_k<<<nblk(9LL*384*192),  TPB, 0, stream>>>(c3w, WH3, WL3, 192, 384,  9, 9*384*192);
  wsplit_k<<<nblk(9LL*256*384),  TPB, 0, stream>>>(c4w, WH4, WL4, 384, 256,  9, 9*256*384);
  wsplit_k<<<nblk(9LL*256*256),  TPB, 0, stream>>>(c5w, WH5, WL5, 256, 256,  9, 9*256*256);
  wtrans_k<<<nblk(72LL*9216),    TPB, 0, stream>>>(gw1, GT1, 72, 9216);

  // conv2 -> X3 split
  conv2m_k<<<dim3(9,64), 256, 0, stream>>>(X2H, X2L, WH2, WL2, c2b, X3H, X3L);
  // pool2 -> X4 split
  pool2_k<<<nblk(64LL*169*192), TPB, 0, stream>>>(X3H, X3L, X4H, X4L);
  // conv3 -> X5, conv4 -> X6, conv5 -> X7
  conv3m_k<192,384><<<dim3(12,64), 256, 0, stream>>>(X4H, X4L, WH3, WL3, c3b, X5H, X5L);
  conv3m_k<384,256><<<dim3(8,64),  256, 0, stream>>>(X5H, X5L, WH4, WL4, c4b, X6H, X6L);
  conv3m_k<256,256><<<dim3(8,64),  256, 0, stream>>>(X6H, X6L, WH5, WL5, c5b, X7H, X7L);
  // pool3 -> feat f32
  pool3_k<<<nblk(64LL*9216), TPB, 0, stream>>>(X7H, X7L, feat);

  // gate
  gate1_k<<<dim3(64,18), 256, 0, stream>>>(feat, GT1, gb1, gbuf);
  gate2_k<<<64, 128, 0, stream>>>(gbuf, gw2, gb2, gates);

  // experts
  eh1_part_k<<<dim3(8,16,2), 256, 0, stream>>>(feat, ew1, part);
  eh1_reduce_k<<<nblk(8LL*64*288), TPB, 0, stream>>>(part, eb1, h1);
  expert_h2_k<<<nblk(8LL*64*144), TPB, 0, stream>>>(h1, ew2, eb2, gates, h2);
  expert_out_k<<<nblk(64LL*1000), TPB, 0, stream>>>(h2, ew3, eb3, gates, out);
}

// Round 13
// 610.281 us; speedup vs baseline: 1.7848x; 1.0373x over previous
//
#include <hip/hip_runtime.h>
#include <math.h>

#define TPB 256

typedef short s16x8 __attribute__((ext_vector_type(8)));
typedef short s16x4 __attribute__((ext_vector_type(4)));
typedef float f32x4 __attribute__((ext_vector_type(4)));

__device__ inline void bsplit(float x, short& h, short& l){
  union { float f; unsigned u; } a, hf, rf;
  a.f = x;
  unsigned hu = (a.u + 0x7FFFu + ((a.u >> 16) & 1u)) >> 16;
  h = (short)hu;
  hf.u = hu << 16;
  rf.f = x - hf.f;
  l = (short)((rf.u + 0x7FFFu + ((rf.u >> 16) & 1u)) >> 16);
}
__device__ inline float b2f(short s){
  union { unsigned u; float f; } x;
  x.u = ((unsigned)(unsigned short)s) << 16;
  return x.f;
}

// ==== weight split + MFMA-native reorder ====
__global__ __launch_bounds__(TPB) void wsplit_k(
    const float* __restrict__ w, short* __restrict__ wh, short* __restrict__ wl,
    int C, int O, int ntap, int total)
{
  int idx = blockIdx.x*TPB + threadIdx.x;
  if (idx >= total) return;
  int c   = idx % C;
  int t2  = idx / C;
  int oc  = t2 % O;
  int tap = t2 / O;
  float x = w[((size_t)oc*C + c)*ntap + tap];
  short h, l; bsplit(x, h, l);
  int tile = oc >> 4, ln = oc & 15;
  int S    = ntap*(C >> 5);
  int sl   = tap*(C >> 5) + (c >> 5);
  int lg   = (c >> 3) & 3, j = c & 7;
  size_t dst = (((size_t)tile*S + sl)*64 + lg*16 + ln)*8 + j;
  wh[dst] = h; wl[dst] = l;
}

__global__ __launch_bounds__(TPB) void wsplit1_k(
    const float* __restrict__ w, short* __restrict__ wh, short* __restrict__ wl)
{
  int idx = blockIdx.x*TPB + threadIdx.x;
  if (idx >= 64*576) return;
  int k  = idx % 576;
  int oc = idx / 576;
  int g  = k >> 4, kw = k & 15;
  int c  = g / 12, kh = g % 12;
  float x = 0.f;
  if (kh < 11 && kw < 11)
    x = w[((size_t)oc*3 + c)*121 + kh*11 + kw];
  short h, l; bsplit(x, h, l);
  int m = oc >> 4, ln = oc & 15;
  int s = k >> 5, r = k & 31;
  int lg = r >> 3, j = r & 7;
  size_t dst = (((size_t)m*18 + s)*64 + lg*16 + ln)*8 + j;
  wh[dst] = h; wl[dst] = l;
}

__global__ __launch_bounds__(TPB) void wtrans_k(
    const float* __restrict__ w, float* __restrict__ wT, int K, int O)
{
  int idx = blockIdx.x*TPB + threadIdx.x;
  if (idx >= K*O) return;
  int oc = idx % O;
  int k  = idx / O;
  wT[idx] = w[(size_t)oc*K + k];
}

// ============== conv1 MFMA (im2col along kw); out: split ch-minor [3025][64] ====
#define C1W 240
#define CV1_PL 33
__global__ __launch_bounds__(256, 2) void conv1m_k(
    const float* __restrict__ in, const short* __restrict__ whi,
    const short* __restrict__ wlo, const float* __restrict__ bias,
    short* __restrict__ yh, short* __restrict__ yl)
{
  __shared__ __align__(16) short lds[2][CV1_PL*C1W + 84];
  const int tid = threadIdx.x;
  const int oh = blockIdx.x % 55;
  const int b  = blockIdx.x / 55;
  const int nt = tid >> 6;
  const int ln = tid & 15;
  const int lg = (tid & 63) >> 4;
  const int lane = tid & 63;
  const int ow = nt*16 + ln;

  const float* ip = in + (size_t)b*3*224*224;
  for (int i = tid; i < CV1_PL*59; i += 256){
    int plane = i / 59;
    int p     = i % 59;
    int c = plane / 11, kh = plane % 11;
    int ih = oh*4 - 2 + kh;
    int col0 = p*4;
    const float* rowp = (ih >= 0 && ih < 224) ? ip + (size_t)c*50176 + (size_t)ih*224 : nullptr;
    short h[4], l[4];
    #pragma unroll
    for (int j=0;j<4;++j){
      int iw = col0 + j - 2;
      float v = (rowp && iw >= 0 && iw < 224) ? rowp[iw] : 0.f;
      bsplit(v, h[j], l[j]);
    }
    s16x4 hv = {h[0],h[1],h[2],h[3]}, lv = {l[0],l[1],l[2],l[3]};
    *reinterpret_cast<s16x4*>(&lds[0][plane*C1W + col0]) = hv;
    *reinterpret_cast<s16x4*>(&lds[1][plane*C1W + col0]) = lv;
  }
  __syncthreads();

  f32x4 acc[4];
  #pragma unroll
  for (int m=0;m<4;++m){
    const float4 bv = *reinterpret_cast<const float4*>(bias + m*16 + lg*4);
    acc[m] = (f32x4){bv.x, bv.y, bv.z, bv.w};
  }

  s16x8 ah[4], al[4], ahn[4], aln[4];
  #pragma unroll
  for (int m=0;m<4;++m){
    size_t ao = (((size_t)m*18 + 0)*64 + lane)*8;
    ah[m] = *reinterpret_cast<const s16x8*>(whi + ao);
    al[m] = *reinterpret_cast<const s16x8*>(wlo + ao);
  }

  #pragma unroll 1
  for (int s=0; s<18; ++s){
    if (s < 17){
      #pragma unroll
      for (int m=0;m<4;++m){
        size_t ao = (((size_t)m*18 + s + 1)*64 + lane)*8;
        ahn[m] = *reinterpret_cast<const s16x8*>(whi + ao);
        aln[m] = *reinterpret_cast<const s16x8*>(wlo + ao);
      }
    }
    int g  = 2*s + (lg >> 1);
    int c  = g / 12, kh = g % 12;
    int plane = c*11 + (kh < 11 ? kh : 10);
    int base  = plane*C1W + ow*4 + (lg & 1)*8;
    s16x4 h0 = *reinterpret_cast<const s16x4*>(&lds[0][base]);
    s16x4 h1 = *reinterpret_cast<const s16x4*>(&lds[0][base+4]);
    s16x4 l0 = *reinterpret_cast<const s16x4*>(&lds[1][base]);
    s16x4 l1 = *reinterpret_cast<const s16x4*>(&lds[1][base+4]);
    s16x8 bh = __builtin_shufflevector(h0, h1, 0,1,2,3,4,5,6,7);
    s16x8 bl = __builtin_shufflevector(l0, l1, 0,1,2,3,4,5,6,7);
    #pragma unroll
    for (int m=0;m<4;++m){
      acc[m] = __builtin_amdgcn_mfma_f32_16x16x32_bf16(al[m], bh, acc[m], 0,0,0);
      acc[m] = __builtin_amdgcn_mfma_f32_16x16x32_bf16(ah[m], bl, acc[m], 0,0,0);
      acc[m] = __builtin_amdgcn_mfma_f32_16x16x32_bf16(ah[m], bh, acc[m], 0,0,0);
    }
    #pragma unroll
    for (int m=0;m<4;++m){ ah[m] = ahn[m]; al[m] = aln[m]; }
  }

  if (ow < 55){
    size_t base = ((size_t)b*3025 + (size_t)oh*55 + ow)*64;
    #pragma unroll
    for (int m=0;m<4;++m){
      short h[4], l[4];
      #pragma unroll
      for (int r=0;r<4;++r) bsplit(fmaxf(acc[m][r], 0.f), h[r], l[r]);
      s16x4 hv = {h[0],h[1],h[2],h[3]}, lv = {l[0],l[1],l[2],l[3]};
      *reinterpret_cast<s16x4*>(yh + base + m*16 + lg*4) = hv;
      *reinterpret_cast<s16x4*>(yl + base + m*16 + lg*4) = lv;
    }
  }
}

// ---- pool1: X1[3025][64] split -> X2[729][64] split ----
__global__ __launch_bounds__(TPB) void pool1_k(
    const short* __restrict__ xh, const short* __restrict__ xl,
    short* __restrict__ yh, short* __restrict__ yl)
{
  int i = blockIdx.x*TPB + threadIdx.x;
  if (i >= 64*729*64) return;
  int c = i & 63;
  int t = i >> 6;
  int sp = t % 729;
  int b = t / 729;
  int r = sp/27, cc = sp%27;
  const short* ph = xh + (size_t)b*3025*64 + c;
  const short* pl = xl + (size_t)b*3025*64 + c;
  float m = -INFINITY;
  #pragma unroll
  for (int di=0;di<3;++di)
    #pragma unroll
    for (int dj=0;dj<3;++dj){
      size_t s = (size_t)((2*r+di)*55 + 2*cc+dj)*64;
      m = fmaxf(m, b2f(ph[s]) + b2f(pl[s]));
    }
  short h, l; bsplit(m, h, l);
  yh[i] = h; yl[i] = l;
}

// ============== conv2 MFMA; in: X2 split [729][64]; out: X3 split [729][192] ====
__global__ __launch_bounds__(256, 2) void conv2m_k(
    const short* __restrict__ xh, const short* __restrict__ xl,
    const short* __restrict__ whi, const short* __restrict__ wlo,
    const float* __restrict__ bias, short* __restrict__ yh, short* __restrict__ yl)
{
  __shared__ __align__(16) short lds[2][217*72];
  const int tid = threadIdx.x;
  const int rg  = blockIdx.x;
  const int b   = blockIdx.y;
  const int wid = tid >> 6;
  const int ln  = tid & 15;
  const int lg  = (tid & 63) >> 4;
  const int lane = tid & 63;
  const int oc0 = wid*48;
  const int r0  = rg*3;

  int sb[6], nn[6];
  #pragma unroll
  for (int t=0;t<6;++t){
    int n = t*16 + ln;
    nn[t] = n;
    int ohl = n / 27, ow = n % 27;
    sb[t] = (n < 81) ? (ohl*31 + ow) : 0;
  }

  f32x4 acc[3][6];
  #pragma unroll
  for (int m=0;m<3;++m){
    const float4 bv = *reinterpret_cast<const float4*>(bias + oc0 + m*16 + lg*4);
    #pragma unroll
    for (int t=0;t<6;++t) acc[m][t] = (f32x4){bv.x, bv.y, bv.z, bv.w};
  }

  for (int i = tid; i < 217*8; i += 256){
    int sp = i >> 3, v = i & 7;
    int pr = sp/31, pc = sp%31;
    int ih = r0 - 2 + pr, iw = pc - 2;
    s16x8 hv = {0,0,0,0,0,0,0,0}, lv = {0,0,0,0,0,0,0,0};
    if (ih >= 0 && ih < 27 && iw >= 0 && iw < 27){
      size_t o = ((size_t)b*729 + ih*27 + iw)*64 + v*8;
      hv = *reinterpret_cast<const s16x8*>(xh + o);
      lv = *reinterpret_cast<const s16x8*>(xl + o);
    }
    *reinterpret_cast<s16x8*>(&lds[0][sp*72 + v*8]) = hv;
    *reinterpret_cast<s16x8*>(&lds[1][sp*72 + v*8]) = lv;
  }
  __syncthreads();

  #pragma unroll 1
  for (int tap=0; tap<25; ++tap){
    const int toff = (tap/5)*31 + (tap%5);
    #pragma unroll
    for (int h2=0; h2<2; ++h2){
      const size_t wo = (((size_t)(wid*3)*50 + tap*2 + h2)*64 + lane)*8;
      s16x8 ah0 = *reinterpret_cast<const s16x8*>(whi + wo);
      s16x8 ah1 = *reinterpret_cast<const s16x8*>(whi + wo + 25600);
      s16x8 ah2 = *reinterpret_cast<const s16x8*>(whi + wo + 51200);
      s16x8 al0 = *reinterpret_cast<const s16x8*>(wlo + wo);
      s16x8 al1 = *reinterpret_cast<const s16x8*>(wlo + wo + 25600);
      s16x8 al2 = *reinterpret_cast<const s16x8*>(wlo + wo + 51200);
      #pragma unroll
      for (int t=0;t<6;++t){
        int off = (sb[t] + toff)*72 + h2*32 + lg*8;
        s16x8 bh = *reinterpret_cast<const s16x8*>(&lds[0][off]);
        s16x8 bl = *reinterpret_cast<const s16x8*>(&lds[1][off]);
        acc[0][t] = __builtin_amdgcn_mfma_f32_16x16x32_bf16(al0, bh, acc[0][t], 0,0,0);
        acc[0][t] = __builtin_amdgcn_mfma_f32_16x16x32_bf16(ah0, bl, acc[0][t], 0,0,0);
        acc[0][t] = __builtin_amdgcn_mfma_f32_16x16x32_bf16(ah0, bh, acc[0][t], 0,0,0);
        acc[1][t] = __builtin_amdgcn_mfma_f32_16x16x32_bf16(al1, bh, acc[1][t], 0,0,0);
        acc[1][t] = __builtin_amdgcn_mfma_f32_16x16x32_bf16(ah1, bl, acc[1][t], 0,0,0);
        acc[1][t] = __builtin_amdgcn_mfma_f32_16x16x32_bf16(ah1, bh, acc[1][t], 0,0,0);
        acc[2][t] = __builtin_amdgcn_mfma_f32_16x16x32_bf16(al2, bh, acc[2][t], 0,0,0);
        acc[2][t] = __builtin_amdgcn_mfma_f32_16x16x32_bf16(ah2, bl, acc[2][t], 0,0,0);
        acc[2][t] = __builtin_amdgcn_mfma_f32_16x16x32_bf16(ah2, bh, acc[2][t], 0,0,0);
      }
    }
  }

  #pragma unroll
  for (int m=0;m<3;++m)
    #pragma unroll
    for (int t=0;t<6;++t){
      if (nn[t] < 81){
        int gsp = r0*27 + nn[t];
        size_t base = ((size_t)b*729 + gsp)*192 + oc0 + m*16 + lg*4;
        short h[4], l[4];
        #pragma unroll
        for (int r=0;r<4;++r) bsplit(fmaxf(acc[m][t][r], 0.f), h[r], l[r]);
        s16x4 hv = {h[0],h[1],h[2],h[3]}, lv = {l[0],l[1],l[2],l[3]};
        *reinterpret_cast<s16x4*>(yh + base) = hv;
        *reinterpret_cast<s16x4*>(yl + base) = lv;
      }
    }
}

// ---- pool2: X3[729][192] split -> X4[169][192] split ----
__global__ __launch_bounds__(TPB) void pool2_k(
    const short* __restrict__ xh, const short* __restrict__ xl,
    short* __restrict__ yh, short* __restrict__ yl)
{
  int i = blockIdx.x*TPB + threadIdx.x;
  if (i >= 64*169*192) return;
  int c = i % 192;
  int t = i / 192;
  int sp = t % 169;
  int b = t / 169;
  int r = sp/13, cc = sp%13;
  const short* ph = xh + (size_t)b*729*192 + c;
  const short* pl = xl + (size_t)b*729*192 + c;
  float m = -INFINITY;
  #pragma unroll
  for (int di=0;di<3;++di)
    #pragma unroll
    for (int dj=0;dj<3;++dj){
      size_t s = (size_t)((2*r+di)*27 + 2*cc+dj)*192;
      m = fmaxf(m, b2f(ph[s]) + b2f(pl[s]));
    }
  short h, l; bsplit(m, h, l);
  yh[i] = h; yl[i] = l;
}

// ============== conv3/4/5 MFMA; in: split ch-minor [169][C]; out: [169][O] =====
template<int C,int O>
__global__ __launch_bounds__(256, 3) void conv3m_k(
    const short* __restrict__ xh, const short* __restrict__ xl,
    const short* __restrict__ whi, const short* __restrict__ wlo,
    const float* __restrict__ bias, short* __restrict__ yh, short* __restrict__ yl)
{
  __shared__ __align__(16) short lds[2][225*40];
  const int tid = threadIdx.x;
  const int b   = blockIdx.y;
  const int wid = tid >> 6;
  const int ln  = tid & 15;
  const int lg  = (tid & 63) >> 4;
  const int lane = tid & 63;
  const int tileIdx = blockIdx.x*2 + (wid & 1);
  const int oc0 = tileIdx*16;
  const int ng  = wid >> 1;
  const int tbase  = ng ? 6 : 0;
  const int ntiles = ng ? 5 : 6;
  const int S3 = 9*(C/32);

  int sb[6], nn[6];
  #pragma unroll
  for (int t=0;t<6;++t){
    int n = (tbase + t)*16 + ln;
    nn[t] = n;
    int oh = n / 13, ow = n % 13;
    sb[t] = (n < 169) ? (oh*15 + ow) : 0;
  }

  f32x4 acc[6];
  const float4 bv = *reinterpret_cast<const float4*>(bias + oc0 + lg*4);
  #pragma unroll
  for (int t=0;t<6;++t) acc[t] = (f32x4){bv.x, bv.y, bv.z, bv.w};

  #pragma unroll 1
  for (int c0=0; c0<C; c0+=32){
    __syncthreads();
    for (int i = tid; i < 225*4; i += 256){
      int sp = i >> 2, v = i & 3;
      int r = sp/15, cc = sp%15;
      s16x8 hv = {0,0,0,0,0,0,0,0}, lv = {0,0,0,0,0,0,0,0};
      if (r >= 1 && r <= 13 && cc >= 1 && cc <= 13){
        size_t o = ((size_t)b*169 + (r-1)*13 + (cc-1))*C + c0 + v*8;
        hv = *reinterpret_cast<const s16x8*>(xh + o);
        lv = *reinterpret_cast<const s16x8*>(xl + o);
      }
      *reinterpret_cast<s16x8*>(&lds[0][sp*40 + v*8]) = hv;
      *reinterpret_cast<s16x8*>(&lds[1][sp*40 + v*8]) = lv;
    }
    __syncthreads();

    const size_t tb = (size_t)tileIdx*S3 + (c0 >> 5);
    s16x8 ah = *reinterpret_cast<const s16x8*>(whi + (tb*64 + lane)*8);
    s16x8 al = *reinterpret_cast<const s16x8*>(wlo + (tb*64 + lane)*8);
    #pragma unroll 1
    for (int tap=0; tap<9; ++tap){
      s16x8 ahn = ah, aln = al;
      if (tap < 8){
        size_t ao = ((tb + (size_t)(tap+1)*(C/32))*64 + lane)*8;
        ahn = *reinterpret_cast<const s16x8*>(whi + ao);
        aln = *reinterpret_cast<const s16x8*>(wlo + ao);
      }
      const int toff = (tap/3)*15 + (tap%3);
      #pragma unroll
      for (int t=0;t<6;++t){
        if (t < ntiles){
          int off = (sb[t] + toff)*40 + lg*8;
          s16x8 bh = *reinterpret_cast<const s16x8*>(&lds[0][off]);
          s16x8 bl = *reinterpret_cast<const s16x8*>(&lds[1][off]);
          acc[t] = __builtin_amdgcn_mfma_f32_16x16x32_bf16(al, bh, acc[t], 0,0,0);
          acc[t] = __builtin_amdgcn_mfma_f32_16x16x32_bf16(ah, bl, acc[t], 0,0,0);
          acc[t] = __builtin_amdgcn_mfma_f32_16x16x32_bf16(ah, bh, acc[t], 0,0,0);
        }
      }
      ah = ahn; al = aln;
    }
  }

  #pragma unroll
  for (int t=0;t<6;++t){
    if (t < ntiles && nn[t] < 169){
      size_t base = ((size_t)b*169 + nn[t])*O + oc0 + lg*4;
      short h[4], l[4];
      #pragma unroll
      for (int r=0;r<4;++r) bsplit(fmaxf(acc[t][r], 0.f), h[r], l[r]);
      s16x4 hv = {h[0],h[1],h[2],h[3]}, lv = {l[0],l[1],l[2],l[3]};
      *reinterpret_cast<s16x4*>(yh + base) = hv;
      *reinterpret_cast<s16x4*>(yl + base) = lv;
    }
  }
}

// ---- pool3: X7[169][256] split -> feat[b][9216] f32 (d = c*36 + sp) ----
__global__ __launch_bounds__(TPB) void pool3_k(
    const short* __restrict__ xh, const short* __restrict__ xl,
    float* __restrict__ feat)
{
  int i = blockIdx.x*TPB + threadIdx.x;
  if (i >= 64*9216) return;
  int d = i % 9216;
  int b = i / 9216;
  int c = d / 36;
  int sp = d % 36;
  int r = sp/6, cc = sp%6;
  const short* ph = xh + (size_t)b*169*256 + c;
  const short* pl = xl + (size_t)b*169*256 + c;
  float m = -INFINITY;
  #pragma unroll
  for (int di=0;di<3;++di)
    #pragma unroll
    for (int dj=0;dj<3;++dj){
      size_t s = (size_t)((2*r+di)*13 + 2*cc+dj)*256;
      m = fmaxf(m, b2f(ph[s]) + b2f(pl[s]));
    }
  feat[i] = m;
}

// ---------------- gate ----------------
__global__ __launch_bounds__(256) void gate1_k(
    const float* __restrict__ feat, const float* __restrict__ gw1T,
    const float* __restrict__ gb1, float* __restrict__ g)
{
  const int b    = blockIdx.x;
  const int h    = blockIdx.y*4 + (threadIdx.x >> 6);
  const int lane = threadIdx.x & 63;
  const float* f = feat + (size_t)b*9216;
  const float* w = gw1T + (size_t)h*9216;
  float s = 0.f;
  #pragma unroll
  for (int it=0; it<36; ++it){
    int d = it*256 + lane*4;
    float4 fv = *reinterpret_cast<const float4*>(f + d);
    float4 wv = *reinterpret_cast<const float4*>(w + d);
    s = fmaf(fv.x, wv.x, s);
    s = fmaf(fv.y, wv.y, s);
    s = fmaf(fv.z, wv.z, s);
    s = fmaf(fv.w, wv.w, s);
  }
  #pragma unroll
  for (int off=32; off; off>>=1) s += __shfl_down(s, off, 64);
  if (lane == 0) g[(size_t)b*72 + h] = fmaxf(s + gb1[h], 0.f);
}

__global__ __launch_bounds__(128) void gate2_k(
    const float* __restrict__ g, const float* __restrict__ gw2,
    const float* __restrict__ gb2, float* __restrict__ gates)
{
  const int b = blockIdx.x;
  const int tid = threadIdx.x;
  __shared__ float gs[72];
  __shared__ float logits[8];
  if (tid < 72) gs[tid] = g[(size_t)b*72 + tid];
  __syncthreads();
  if (tid < 8) {
    float acc = gb2[tid];
    for (int j=0;j<72;++j)
      acc = fmaf(gs[j], gw2[(size_t)j*8 + tid], acc);
    logits[tid] = acc;
  }
  __syncthreads();
  if (tid == 0) {
    int i1 = 0; float v1 = logits[0];
    for (int e=1;e<8;++e) if (logits[e] > v1) { v1 = logits[e]; i1 = e; }
    int i2 = -1; float v2 = -INFINITY;
    for (int e=0;e<8;++e) { if (e==i1) continue; if (logits[e] > v2) { v2 = logits[e]; i2 = e; } }
    float z  = expf(v2 - v1);
    float w1 = 1.f / (1.f + z);
    float w2 = z   / (1.f + z);
    float* gr = gates + (size_t)b*8;
    for (int e=0;e<8;++e) gr[e] = 0.f;
    gr[i1] = w1;
    gr[i2] = w2;
  }
}

// ========== expert h1 dense split-K GEMM (48-way split for occupancy) ==========
__global__ __launch_bounds__(256, 2) void eh1_part_k(
    const float* __restrict__ feat, const float* __restrict__ ew1,
    float* __restrict__ part)
{
  const int e  = blockIdx.x;
  const int ks = blockIdx.y;      // 0..47, chunk = 192
  const int nb = blockIdx.z;
  const int h0 = nb*144;
  __shared__ __align__(16) float fs[64*33];
  __shared__ __align__(16) float wsh[32*144];
  const int tid = threadIdx.x;
  const int tx = tid & 15;
  const int ty = tid >> 4;
  float acc[4][9];
  #pragma unroll
  for (int i=0;i<4;++i)
    #pragma unroll
    for (int j=0;j<9;++j) acc[i][j]=0.f;
  const float* wbase = ew1 + (size_t)e*9216*288 + h0;
  for (int d0 = ks*192; d0 < ks*192+192; d0 += 32){
    __syncthreads();
    for (int l = tid; l < 512; l += 256){
      int r = l >> 3, c = l & 7;
      float4 v = *reinterpret_cast<const float4*>(feat + (size_t)r*9216 + d0 + c*4);
      float* dst = &fs[r*33 + c*4];
      dst[0]=v.x; dst[1]=v.y; dst[2]=v.z; dst[3]=v.w;
    }
    for (int l = tid; l < 1152; l += 256){
      int r = l / 36, c = l % 36;
      *reinterpret_cast<float4*>(&wsh[r*144 + c*4]) =
        *reinterpret_cast<const float4*>(wbase + (size_t)(d0 + r)*288 + c*4);
    }
    __syncthreads();
    #pragma unroll
    for (int k=0;k<32;++k){
      float fv[4], wv[9];
      #pragma unroll
      for (int i=0;i<4;++i) fv[i] = fs[(ty*4+i)*33 + k];
      #pragma unroll
      for (int j=0;j<9;++j) wv[j] = wsh[k*144 + tx*9 + j];
      #pragma unroll
      for (int i=0;i<4;++i)
        #pragma unroll
        for (int j=0;j<9;++j)
          acc[i][j] = fmaf(fv[i], wv[j], acc[i][j]);
    }
  }
  float* pp = part + (size_t)(ks*8 + e)*64*288;
  #pragma unroll
  for (int i=0;i<4;++i)
    #pragma unroll
    for (int j=0;j<9;++j)
      pp[(ty*4+i)*288 + h0 + tx*9 + j] = acc[i][j];
}

__global__ __launch_bounds__(TPB) void eh1_reduce_k(
    const float* __restrict__ part, const float* __restrict__ eb1,
    float* __restrict__ h1)
{
  int idx = blockIdx.x*TPB + threadIdx.x;
  if (idx >= 8*64*288) return;
  int h = idx % 288;
  int e = idx / (64*288);
  float a = eb1[(size_t)e*288 + h];
  #pragma unroll
  for (int s=0;s<48;++s)
    a += part[(size_t)s*147456 + idx];
  h1[idx] = fmaxf(a, 0.f);
}

__global__ __launch_bounds__(TPB) void expert_h2_k(
    const float* __restrict__ h1, const float* __restrict__ ew2,
    const float* __restrict__ eb2, const float* __restrict__ gates,
    float* __restrict__ h2)
{
  int idx = blockIdx.x*TPB + threadIdx.x;
  if (idx >= 8*64*144) return;
  int k = idx % 144;
  int t = idx / 144;
  int b = t % 64;
  int e = t / 64;
  if (gates[(size_t)b*8 + e] == 0.f) return;
  float acc = eb2[(size_t)e*144 + k];
  const float* h = h1 + ((size_t)e*64 + b)*288;
  const float* w = ew2 + (size_t)e*288*144 + k;
  for (int d=0; d<288; ++d)
    acc = fmaf(h[d], w[(size_t)d*144], acc);
  h2[idx] = fmaxf(acc, 0.f);
}

__global__ __launch_bounds__(TPB) void expert_out_k(
    const float* __restrict__ h2, const float* __restrict__ ew3,
    const float* __restrict__ eb3, const float* __restrict__ gates,
    float* __restrict__ out)
{
  int idx = blockIdx.x*TPB + threadIdx.x;
  if (idx >= 64*1000) return;
  int o = idx % 1000;
  int b = idx / 1000;
  float acc = 0.f;
  const float* gr = gates + (size_t)b*8;
  for (int e=0;e<8;++e){
    float ge = gr[e];
    if (ge == 0.f) continue;
    float a = eb3[(size_t)e*1000 + o];
    const float* h = h2 + ((size_t)e*64 + b)*144;
    const float* w = ew3 + (size_t)e*144*1000 + o;
    for (int k=0;k<144;++k)
      a = fmaf(h[k], w[(size_t)k*1000], a);
    acc = fmaf(ge, a, acc);
  }
  out[idx] = acc;
}

static inline int nblk(long long n){ return (int)((n + TPB - 1) / TPB); }

extern "C" void kernel_launch(void* const* d_in, const int* in_sizes, int n_in,
                              void* d_out, int out_size, void* d_ws, size_t ws_size,
                              hipStream_t stream)
{
  const float* x   = (const float*)d_in[0];
  const float* c1w = (const float*)d_in[1];  const float* c1b = (const float*)d_in[2];
  const float* c2w = (const float*)d_in[3];  const float* c2b = (const float*)d_in[4];
  const float* c3w = (const float*)d_in[5];  const float* c3b = (const float*)d_in[6];
  const float* c4w = (const float*)d_in[7];  const float* c4b = (const float*)d_in[8];
  const float* c5w = (const float*)d_in[9];  const float* c5b = (const float*)d_in[10];
  const float* gw1 = (const float*)d_in[11]; const float* gb1 = (const float*)d_in[12];
  const float* gw2 = (const float*)d_in[13]; const float* gb2 = (const float*)d_in[14];
  const float* ew1 = (const float*)d_in[15]; const float* eb1 = (const float*)d_in[16];
  const float* ew2 = (const float*)d_in[17]; const float* eb2 = (const float*)d_in[18];
  const float* ew3 = (const float*)d_in[19]; const float* eb3 = (const float*)d_in[20];
  float* out = (float*)d_out;

  float* W = (float*)d_ws;
  // activations (split bf16 hi/lo, channel-minor); region reuse by lifetime
  short* X1H = (short*)W;                  // [64][3025][64]  (conv1 out)
  short* X1L = X1H + 12390400;
  short* X3H = (short*)W;                  // [64][729][192]  (conv2 out; X1 dead)
  short* X3L = X3H + 8957952;
  short* X5H = (short*)W;                  // [64][169][384]  (conv3 out; X3 dead)
  short* X5L = X5H + 4153344;
  short* X7H = (short*)W;                  // [64][169][256]  (conv5 out; X5 dead)
  short* X7L = X7H + 2768896;
  float* feat  = W + 5000000;              // 589,824 (ends 5,589,824)
  float* part  = W + 6000000;              // 48×147,456 = 7,077,888 (ends 13,077,888;
                                           //  overlays weight zone + X2/X4/X6 — all dead by expert phase)
  // weight zone (written after pool1; X1 tail dead by then; dead before experts)
  short* WH2 = (short*)(W +  9000000);     // 307,200
  short* WL2 = WH2 + 307200;
  short* WH3 = (short*)(W +  9320000);     // 663,552
  short* WL3 = WH3 + 663552;
  short* WH4 = (short*)(W + 10000000);     // 884,736
  short* WL4 = WH4 + 884736;
  short* WH5 = (short*)(W + 10900000);     // 589,824
  short* WL5 = WH5 + 589824;
  float* GT1 = W + 11500000;               // 663,552 (dead after gate1)
  // B zone (after X1): X2/X4/X6 alternate (dead before expert phase)
  short* X2H = (short*)(W + 12390400);     // [64][729][64]
  short* X2L = X2H + 2985984;
  short* X4H = (short*)(W + 12390400);     // [64][169][192]
  short* X4L = X4H + 2076672;
  short* X6H = (short*)(W + 12390400);     // [64][169][256]
  short* X6L = X6H + 2768896;
  // gate/expert small buffers — above part (alive through expert phase)
  float* gates = W + 14000000;             // 512
  float* h1    = gates + 512;              // 147,456
  float* h2    = h1 + 147456;              // 73,728
  float* gbuf  = h2 + 73728;               // 4,608 (ends 14,226,304)
  short* WH1 = (short*)(W + 15400000);     // 36,864 sh (dead after conv1m)
  short* WL1 = WH1 + 36864;
  (void)ws_size; (void)in_sizes; (void)n_in; (void)out_size;

  // conv1 (MFMA) -> X1 split
  wsplit1_k<<<nblk(64LL*576), TPB, 0, stream>>>(c1w, WH1, WL1);
  conv1m_k<<<55*64, 256, 0, stream>>>(x, WH1, WL1, c1b, X1H, X1L);
  // pool1 -> X2 split
  pool1_k<<<nblk(64LL*729*64), TPB, 0, stream>>>(X1H, X1L, X2H, X2L);
  // weight prep (X1 dead)
  wsplit_k<<<nblk(25LL*192*64),  TPB, 0, stream>>>(c2w, WH2, WL2,  64, 192, 25, 25*192*64);
  wsplit_k<<<nblk(9LL*384*192),  TPB, 0, stream>>>(c3w, WH3, WL3, 192, 384,  9, 9*384*192);
  wsplit_k<<<nblk(9LL*256*384),  TPB, 0, stream>>>(c4w, WH4, WL4, 384, 256,  9, 9*256*384);
  wsplit_k<<<nblk(9LL*256*256),  TPB, 0, stream>>>(c5w, WH5, WL5, 256, 256,  9, 9*256*256);
  wtrans_k<<<nblk(72LL*9216),    TPB, 0, stream>>>(gw1, GT1, 72, 9216);

  // conv2 -> X3 split
  conv2m_k<<<dim3(9,64), 256, 0, stream>>>(X2H, X2L, WH2, WL2, c2b, X3H, X3L);
  // pool2 -> X4 split
  pool2_k<<<nblk(64LL*169*192), TPB, 0, stream>>>(X3H, X3L, X4H, X4L);
  // conv3 -> X5, conv4 -> X6, conv5 -> X7
  conv3m_k<192,384><<<dim3(12,64), 256, 0, stream>>>(X4H, X4L, WH3, WL3, c3b, X5H, X5L);
  conv3m_k<384,256><<<dim3(8,64),  256, 0, stream>>>(X5H, X5L, WH4, WL4, c4b, X6H, X6L);
  conv3m_k<256,256><<<dim3(8,64),  256, 0, stream>>>(X6H, X6L, WH5, WL5, c5b, X7H, X7L);
  // pool3 -> feat f32
  pool3_k<<<nblk(64LL*9216), TPB, 0, stream>>>(X7H, X7L, feat);

  // gate
  gate1_k<<<dim3(64,18), 256, 0, stream>>>(feat, GT1, gb1, gbuf);
  gate2_k<<<64, 128, 0, stream>>>(gbuf, gw2, gb2, gates);

  // experts
  eh1_part_k<<<dim3(8,48,2), 256, 0, stream>>>(feat, ew1, part);
  eh1_reduce_k<<<nblk(8LL*64*288), TPB, 0, stream>>>(part, eb1, h1);
  expert_h2_k<<<nblk(8LL*64*144), TPB, 0, stream>>>(h1, ew2, eb2, gates, h2);
  expert_out_k<<<nblk(64LL*1000), TPB, 0, stream>>>(h2, ew3, eb3, gates, out);
}

// Round 14
// 585.081 us; speedup vs baseline: 1.8616x; 1.0431x over previous
//
#include <hip/hip_runtime.h>
#include <math.h>

#define TPB 256

typedef short s16x8 __attribute__((ext_vector_type(8)));
typedef short s16x4 __attribute__((ext_vector_type(4)));
typedef float f32x4 __attribute__((ext_vector_type(4)));

__device__ inline void bsplit(float x, short& h, short& l){
  union { float f; unsigned u; } a, hf, rf;
  a.f = x;
  unsigned hu = (a.u + 0x7FFFu + ((a.u >> 16) & 1u)) >> 16;
  h = (short)hu;
  hf.u = hu << 16;
  rf.f = x - hf.f;
  l = (short)((rf.u + 0x7FFFu + ((rf.u >> 16) & 1u)) >> 16);
}
__device__ inline float b2f(short s){
  union { unsigned u; float f; } x;
  x.u = ((unsigned)(unsigned short)s) << 16;
  return x.f;
}

// ==== weight split + MFMA-native reorder ====
__global__ __launch_bounds__(TPB) void wsplit_k(
    const float* __restrict__ w, short* __restrict__ wh, short* __restrict__ wl,
    int C, int O, int ntap, int total)
{
  int idx = blockIdx.x*TPB + threadIdx.x;
  if (idx >= total) return;
  int c   = idx % C;
  int t2  = idx / C;
  int oc  = t2 % O;
  int tap = t2 / O;
  float x = w[((size_t)oc*C + c)*ntap + tap];
  short h, l; bsplit(x, h, l);
  int tile = oc >> 4, ln = oc & 15;
  int S    = ntap*(C >> 5);
  int sl   = tap*(C >> 5) + (c >> 5);
  int lg   = (c >> 3) & 3, j = c & 7;
  size_t dst = (((size_t)tile*S + sl)*64 + lg*16 + ln)*8 + j;
  wh[dst] = h; wl[dst] = l;
}

__global__ __launch_bounds__(TPB) void wsplit1_k(
    const float* __restrict__ w, short* __restrict__ wh, short* __restrict__ wl)
{
  int idx = blockIdx.x*TPB + threadIdx.x;
  if (idx >= 64*576) return;
  int k  = idx % 576;
  int oc = idx / 576;
  int g  = k >> 4, kw = k & 15;
  int c  = g / 12, kh = g % 12;
  float x = 0.f;
  if (kh < 11 && kw < 11)
    x = w[((size_t)oc*3 + c)*121 + kh*11 + kw];
  short h, l; bsplit(x, h, l);
  int m = oc >> 4, ln = oc & 15;
  int s = k >> 5, r = k & 31;
  int lg = r >> 3, j = r & 7;
  size_t dst = (((size_t)m*18 + s)*64 + lg*16 + ln)*8 + j;
  wh[dst] = h; wl[dst] = l;
}

__global__ __launch_bounds__(TPB) void wtrans_k(
    const float* __restrict__ w, float* __restrict__ wT, int K, int O)
{
  int idx = blockIdx.x*TPB + threadIdx.x;
  if (idx >= K*O) return;
  int oc = idx % O;
  int k  = idx / O;
  wT[idx] = w[(size_t)oc*K + k];
}

// ============== conv1 MFMA (im2col along kw); out: split ch-minor [3025][64] ====
#define C1W 240
#define CV1_PL 33
__global__ __launch_bounds__(256, 2) void conv1m_k(
    const float* __restrict__ in, const short* __restrict__ whi,
    const short* __restrict__ wlo, const float* __restrict__ bias,
    short* __restrict__ yh, short* __restrict__ yl)
{
  __shared__ __align__(16) short lds[2][CV1_PL*C1W + 84];
  const int tid = threadIdx.x;
  const int oh = blockIdx.x % 55;
  const int b  = blockIdx.x / 55;
  const int nt = tid >> 6;
  const int ln = tid & 15;
  const int lg = (tid & 63) >> 4;
  const int lane = tid & 63;
  const int ow = nt*16 + ln;

  const float* ip = in + (size_t)b*3*224*224;
  for (int i = tid; i < CV1_PL*59; i += 256){
    int plane = i / 59;
    int p     = i % 59;
    int c = plane / 11, kh = plane % 11;
    int ih = oh*4 - 2 + kh;
    int col0 = p*4;
    const float* rowp = (ih >= 0 && ih < 224) ? ip + (size_t)c*50176 + (size_t)ih*224 : nullptr;
    short h[4], l[4];
    #pragma unroll
    for (int j=0;j<4;++j){
      int iw = col0 + j - 2;
      float v = (rowp && iw >= 0 && iw < 224) ? rowp[iw] : 0.f;
      bsplit(v, h[j], l[j]);
    }
    s16x4 hv = {h[0],h[1],h[2],h[3]}, lv = {l[0],l[1],l[2],l[3]};
    *reinterpret_cast<s16x4*>(&lds[0][plane*C1W + col0]) = hv;
    *reinterpret_cast<s16x4*>(&lds[1][plane*C1W + col0]) = lv;
  }
  __syncthreads();

  f32x4 acc[4];
  #pragma unroll
  for (int m=0;m<4;++m){
    const float4 bv = *reinterpret_cast<const float4*>(bias + m*16 + lg*4);
    acc[m] = (f32x4){bv.x, bv.y, bv.z, bv.w};
  }

  s16x8 ah[4], al[4], ahn[4], aln[4];
  #pragma unroll
  for (int m=0;m<4;++m){
    size_t ao = (((size_t)m*18 + 0)*64 + lane)*8;
    ah[m] = *reinterpret_cast<const s16x8*>(whi + ao);
    al[m] = *reinterpret_cast<const s16x8*>(wlo + ao);
  }

  #pragma unroll 1
  for (int s=0; s<18; ++s){
    if (s < 17){
      #pragma unroll
      for (int m=0;m<4;++m){
        size_t ao = (((size_t)m*18 + s + 1)*64 + lane)*8;
        ahn[m] = *reinterpret_cast<const s16x8*>(whi + ao);
        aln[m] = *reinterpret_cast<const s16x8*>(wlo + ao);
      }
    }
    int g  = 2*s + (lg >> 1);
    int c  = g / 12, kh = g % 12;
    int plane = c*11 + (kh < 11 ? kh : 10);
    int base  = plane*C1W + ow*4 + (lg & 1)*8;
    s16x4 h0 = *reinterpret_cast<const s16x4*>(&lds[0][base]);
    s16x4 h1 = *reinterpret_cast<const s16x4*>(&lds[0][base+4]);
    s16x4 l0 = *reinterpret_cast<const s16x4*>(&lds[1][base]);
    s16x4 l1 = *reinterpret_cast<const s16x4*>(&lds[1][base+4]);
    s16x8 bh = __builtin_shufflevector(h0, h1, 0,1,2,3,4,5,6,7);
    s16x8 bl = __builtin_shufflevector(l0, l1, 0,1,2,3,4,5,6,7);
    #pragma unroll
    for (int m=0;m<4;++m){
      acc[m] = __builtin_amdgcn_mfma_f32_16x16x32_bf16(al[m], bh, acc[m], 0,0,0);
      acc[m] = __builtin_amdgcn_mfma_f32_16x16x32_bf16(ah[m], bl, acc[m], 0,0,0);
      acc[m] = __builtin_amdgcn_mfma_f32_16x16x32_bf16(ah[m], bh, acc[m], 0,0,0);
    }
    #pragma unroll
    for (int m=0;m<4;++m){ ah[m] = ahn[m]; al[m] = aln[m]; }
  }

  if (ow < 55){
    size_t base = ((size_t)b*3025 + (size_t)oh*55 + ow)*64;
    #pragma unroll
    for (int m=0;m<4;++m){
      short h[4], l[4];
      #pragma unroll
      for (int r=0;r<4;++r) bsplit(fmaxf(acc[m][r], 0.f), h[r], l[r]);
      s16x4 hv = {h[0],h[1],h[2],h[3]}, lv = {l[0],l[1],l[2],l[3]};
      *reinterpret_cast<s16x4*>(yh + base + m*16 + lg*4) = hv;
      *reinterpret_cast<s16x4*>(yl + base + m*16 + lg*4) = lv;
    }
  }
}

// ---- pool1: X1[3025][64] split -> X2[729][64] split ----
__global__ __launch_bounds__(TPB) void pool1_k(
    const short* __restrict__ xh, const short* __restrict__ xl,
    short* __restrict__ yh, short* __restrict__ yl)
{
  int i = blockIdx.x*TPB + threadIdx.x;
  if (i >= 64*729*64) return;
  int c = i & 63;
  int t = i >> 6;
  int sp = t % 729;
  int b = t / 729;
  int r = sp/27, cc = sp%27;
  const short* ph = xh + (size_t)b*3025*64 + c;
  const short* pl = xl + (size_t)b*3025*64 + c;
  float m = -INFINITY;
  #pragma unroll
  for (int di=0;di<3;++di)
    #pragma unroll
    for (int dj=0;dj<3;++dj){
      size_t s = (size_t)((2*r+di)*55 + 2*cc+dj)*64;
      m = fmaxf(m, b2f(ph[s]) + b2f(pl[s]));
    }
  short h, l; bsplit(m, h, l);
  yh[i] = h; yl[i] = l;
}

// ============== conv2 MFMA v3: 32-ch chunks + A-prefetch ==============
// block = (rg of 3 rows, b); 4 waves, wave = 48 ocs (3 M-tiles x 6 N-tiles).
// LDS: [217 sp][40 ch] hi/lo = 34.7 KB -> 3 blocks/CU. c0 chunks {0,32}.
// A prefetched one tap ahead (conv3m pattern).
__global__ __launch_bounds__(256, 3) void conv2m_k(
    const short* __restrict__ xh, const short* __restrict__ xl,
    const short* __restrict__ whi, const short* __restrict__ wlo,
    const float* __restrict__ bias, short* __restrict__ yh, short* __restrict__ yl)
{
  __shared__ __align__(16) short lds[2][217*40];
  const int tid = threadIdx.x;
  const int rg  = blockIdx.x;
  const int b   = blockIdx.y;
  const int wid = tid >> 6;
  const int ln  = tid & 15;
  const int lg  = (tid & 63) >> 4;
  const int lane = tid & 63;
  const int oc0 = wid*48;
  const int r0  = rg*3;

  int sb[6], nn[6];
  #pragma unroll
  for (int t=0;t<6;++t){
    int n = t*16 + ln;
    nn[t] = n;
    int ohl = n / 27, ow = n % 27;
    sb[t] = (n < 81) ? (ohl*31 + ow) : 0;
  }

  f32x4 acc[3][6];
  #pragma unroll
  for (int m=0;m<3;++m){
    const float4 bv = *reinterpret_cast<const float4*>(bias + oc0 + m*16 + lg*4);
    #pragma unroll
    for (int t=0;t<6;++t) acc[m][t] = (f32x4){bv.x, bv.y, bv.z, bv.w};
  }

  #pragma unroll 1
  for (int c0=0; c0<64; c0+=32){
    __syncthreads();
    // stage 32 channels of padded 7x31 tile: pure vector copy
    for (int i = tid; i < 217*4; i += 256){
      int sp = i >> 2, v = i & 3;
      int pr = sp/31, pc = sp%31;
      int ih = r0 - 2 + pr, iw = pc - 2;
      s16x8 hv = {0,0,0,0,0,0,0,0}, lv = {0,0,0,0,0,0,0,0};
      if (ih >= 0 && ih < 27 && iw >= 0 && iw < 27){
        size_t o = ((size_t)b*729 + ih*27 + iw)*64 + c0 + v*8;
        hv = *reinterpret_cast<const s16x8*>(xh + o);
        lv = *reinterpret_cast<const s16x8*>(xl + o);
      }
      *reinterpret_cast<s16x8*>(&lds[0][sp*40 + v*8]) = hv;
      *reinterpret_cast<s16x8*>(&lds[1][sp*40 + v*8]) = lv;
    }
    __syncthreads();

    // A slices: sl = tap*2 + (c0>>5); tile stride = 50 slices
    const size_t tstr = 50*512;            // shorts per tile
    const size_t abase = ((size_t)(wid*3)*50 + (c0 >> 5))*512 + (size_t)lane*8;
    s16x8 ah0 = *reinterpret_cast<const s16x8*>(whi + abase);
    s16x8 ah1 = *reinterpret_cast<const s16x8*>(whi + abase + tstr);
    s16x8 ah2 = *reinterpret_cast<const s16x8*>(whi + abase + 2*tstr);
    s16x8 al0 = *reinterpret_cast<const s16x8*>(wlo + abase);
    s16x8 al1 = *reinterpret_cast<const s16x8*>(wlo + abase + tstr);
    s16x8 al2 = *reinterpret_cast<const s16x8*>(wlo + abase + 2*tstr);

    #pragma unroll 1
    for (int tap=0; tap<25; ++tap){
      s16x8 nh0=ah0, nh1=ah1, nh2=ah2, nl0=al0, nl1=al1, nl2=al2;
      if (tap < 24){
        size_t ao = abase + (size_t)(tap+1)*2*512;
        nh0 = *reinterpret_cast<const s16x8*>(whi + ao);
        nh1 = *reinterpret_cast<const s16x8*>(whi + ao + tstr);
        nh2 = *reinterpret_cast<const s16x8*>(whi + ao + 2*tstr);
        nl0 = *reinterpret_cast<const s16x8*>(wlo + ao);
        nl1 = *reinterpret_cast<const s16x8*>(wlo + ao + tstr);
        nl2 = *reinterpret_cast<const s16x8*>(wlo + ao + 2*tstr);
      }
      const int toff = (tap/5)*31 + (tap%5);
      #pragma unroll
      for (int t=0;t<6;++t){
        int off = (sb[t] + toff)*40 + lg*8;
        s16x8 bh = *reinterpret_cast<const s16x8*>(&lds[0][off]);
        s16x8 bl = *reinterpret_cast<const s16x8*>(&lds[1][off]);
        acc[0][t] = __builtin_amdgcn_mfma_f32_16x16x32_bf16(al0, bh, acc[0][t], 0,0,0);
        acc[0][t] = __builtin_amdgcn_mfma_f32_16x16x32_bf16(ah0, bl, acc[0][t], 0,0,0);
        acc[0][t] = __builtin_amdgcn_mfma_f32_16x16x32_bf16(ah0, bh, acc[0][t], 0,0,0);
        acc[1][t] = __builtin_amdgcn_mfma_f32_16x16x32_bf16(al1, bh, acc[1][t], 0,0,0);
        acc[1][t] = __builtin_amdgcn_mfma_f32_16x16x32_bf16(ah1, bl, acc[1][t], 0,0,0);
        acc[1][t] = __builtin_amdgcn_mfma_f32_16x16x32_bf16(ah1, bh, acc[1][t], 0,0,0);
        acc[2][t] = __builtin_amdgcn_mfma_f32_16x16x32_bf16(al2, bh, acc[2][t], 0,0,0);
        acc[2][t] = __builtin_amdgcn_mfma_f32_16x16x32_bf16(ah2, bl, acc[2][t], 0,0,0);
        acc[2][t] = __builtin_amdgcn_mfma_f32_16x16x32_bf16(ah2, bh, acc[2][t], 0,0,0);
      }
      ah0=nh0; ah1=nh1; ah2=nh2; al0=nl0; al1=nl1; al2=nl2;
    }
  }

  #pragma unroll
  for (int m=0;m<3;++m)
    #pragma unroll
    for (int t=0;t<6;++t){
      if (nn[t] < 81){
        int gsp = r0*27 + nn[t];
        size_t base = ((size_t)b*729 + gsp)*192 + oc0 + m*16 + lg*4;
        short h[4], l[4];
        #pragma unroll
        for (int r=0;r<4;++r) bsplit(fmaxf(acc[m][t][r], 0.f), h[r], l[r]);
        s16x4 hv = {h[0],h[1],h[2],h[3]}, lv = {l[0],l[1],l[2],l[3]};
        *reinterpret_cast<s16x4*>(yh + base) = hv;
        *reinterpret_cast<s16x4*>(yl + base) = lv;
      }
    }
}

// ---- pool2: X3[729][192] split -> X4[169][192] split ----
__global__ __launch_bounds__(TPB) void pool2_k(
    const short* __restrict__ xh, const short* __restrict__ xl,
    short* __restrict__ yh, short* __restrict__ yl)
{
  int i = blockIdx.x*TPB + threadIdx.x;
  if (i >= 64*169*192) return;
  int c = i % 192;
  int t = i / 192;
  int sp = t % 169;
  int b = t / 169;
  int r = sp/13, cc = sp%13;
  const short* ph = xh + (size_t)b*729*192 + c;
  const short* pl = xl + (size_t)b*729*192 + c;
  float m = -INFINITY;
  #pragma unroll
  for (int di=0;di<3;++di)
    #pragma unroll
    for (int dj=0;dj<3;++dj){
      size_t s = (size_t)((2*r+di)*27 + 2*cc+dj)*192;
      m = fmaxf(m, b2f(ph[s]) + b2f(pl[s]));
    }
  short h, l; bsplit(m, h, l);
  yh[i] = h; yl[i] = l;
}

// ============== conv3/4/5 MFMA; in: split ch-minor [169][C]; out: [169][O] =====
template<int C,int O>
__global__ __launch_bounds__(256, 3) void conv3m_k(
    const short* __restrict__ xh, const short* __restrict__ xl,
    const short* __restrict__ whi, const short* __restrict__ wlo,
    const float* __restrict__ bias, short* __restrict__ yh, short* __restrict__ yl)
{
  __shared__ __align__(16) short lds[2][225*40];
  const int tid = threadIdx.x;
  const int b   = blockIdx.y;
  const int wid = tid >> 6;
  const int ln  = tid & 15;
  const int lg  = (tid & 63) >> 4;
  const int lane = tid & 63;
  const int tileIdx = blockIdx.x*2 + (wid & 1);
  const int oc0 = tileIdx*16;
  const int ng  = wid >> 1;
  const int tbase  = ng ? 6 : 0;
  const int ntiles = ng ? 5 : 6;
  const int S3 = 9*(C/32);

  int sb[6], nn[6];
  #pragma unroll
  for (int t=0;t<6;++t){
    int n = (tbase + t)*16 + ln;
    nn[t] = n;
    int oh = n / 13, ow = n % 13;
    sb[t] = (n < 169) ? (oh*15 + ow) : 0;
  }

  f32x4 acc[6];
  const float4 bv = *reinterpret_cast<const float4*>(bias + oc0 + lg*4);
  #pragma unroll
  for (int t=0;t<6;++t) acc[t] = (f32x4){bv.x, bv.y, bv.z, bv.w};

  #pragma unroll 1
  for (int c0=0; c0<C; c0+=32){
    __syncthreads();
    for (int i = tid; i < 225*4; i += 256){
      int sp = i >> 2, v = i & 3;
      int r = sp/15, cc = sp%15;
      s16x8 hv = {0,0,0,0,0,0,0,0}, lv = {0,0,0,0,0,0,0,0};
      if (r >= 1 && r <= 13 && cc >= 1 && cc <= 13){
        size_t o = ((size_t)b*169 + (r-1)*13 + (cc-1))*C + c0 + v*8;
        hv = *reinterpret_cast<const s16x8*>(xh + o);
        lv = *reinterpret_cast<const s16x8*>(xl + o);
      }
      *reinterpret_cast<s16x8*>(&lds[0][sp*40 + v*8]) = hv;
      *reinterpret_cast<s16x8*>(&lds[1][sp*40 + v*8]) = lv;
    }
    __syncthreads();

    const size_t tb = (size_t)tileIdx*S3 + (c0 >> 5);
    s16x8 ah = *reinterpret_cast<const s16x8*>(whi + (tb*64 + lane)*8);
    s16x8 al = *reinterpret_cast<const s16x8*>(wlo + (tb*64 + lane)*8);
    #pragma unroll 1
    for (int tap=0; tap<9; ++tap){
      s16x8 ahn = ah, aln = al;
      if (tap < 8){
        size_t ao = ((tb + (size_t)(tap+1)*(C/32))*64 + lane)*8;
        ahn = *reinterpret_cast<const s16x8*>(whi + ao);
        aln = *reinterpret_cast<const s16x8*>(wlo + ao);
      }
      const int toff = (tap/3)*15 + (tap%3);
      #pragma unroll
      for (int t=0;t<6;++t){
        if (t < ntiles){
          int off = (sb[t] + toff)*40 + lg*8;
          s16x8 bh = *reinterpret_cast<const s16x8*>(&lds[0][off]);
          s16x8 bl = *reinterpret_cast<const s16x8*>(&lds[1][off]);
          acc[t] = __builtin_amdgcn_mfma_f32_16x16x32_bf16(al, bh, acc[t], 0,0,0);
          acc[t] = __builtin_amdgcn_mfma_f32_16x16x32_bf16(ah, bl, acc[t], 0,0,0);
          acc[t] = __builtin_amdgcn_mfma_f32_16x16x32_bf16(ah, bh, acc[t], 0,0,0);
        }
      }
      ah = ahn; al = aln;
    }
  }

  #pragma unroll
  for (int t=0;t<6;++t){
    if (t < ntiles && nn[t] < 169){
      size_t base = ((size_t)b*169 + nn[t])*O + oc0 + lg*4;
      short h[4], l[4];
      #pragma unroll
      for (int r=0;r<4;++r) bsplit(fmaxf(acc[t][r], 0.f), h[r], l[r]);
      s16x4 hv = {h[0],h[1],h[2],h[3]}, lv = {l[0],l[1],l[2],l[3]};
      *reinterpret_cast<s16x4*>(yh + base) = hv;
      *reinterpret_cast<s16x4*>(yl + base) = lv;
    }
  }
}

// ---- pool3: X7[169][256] split -> feat[b][9216] f32 (d = c*36 + sp) ----
__global__ __launch_bounds__(TPB) void pool3_k(
    const short* __restrict__ xh, const short* __restrict__ xl,
    float* __restrict__ feat)
{
  int i = blockIdx.x*TPB + threadIdx.x;
  if (i >= 64*9216) return;
  int d = i % 9216;
  int b = i / 9216;
  int c = d / 36;
  int sp = d % 36;
  int r = sp/6, cc = sp%6;
  const short* ph = xh + (size_t)b*169*256 + c;
  const short* pl = xl + (size_t)b*169*256 + c;
  float m = -INFINITY;
  #pragma unroll
  for (int di=0;di<3;++di)
    #pragma unroll
    for (int dj=0;dj<3;++dj){
      size_t s = (size_t)((2*r+di)*13 + 2*cc+dj)*256;
      m = fmaxf(m, b2f(ph[s]) + b2f(pl[s]));
    }
  feat[i] = m;
}

// ---------------- gate ----------------
__global__ __launch_bounds__(256) void gate1_k(
    const float* __restrict__ feat, const float* __restrict__ gw1T,
    const float* __restrict__ gb1, float* __restrict__ g)
{
  const int b    = blockIdx.x;
  const int h    = blockIdx.y*4 + (threadIdx.x >> 6);
  const int lane = threadIdx.x & 63;
  const float* f = feat + (size_t)b*9216;
  const float* w = gw1T + (size_t)h*9216;
  float s = 0.f;
  #pragma unroll
  for (int it=0; it<36; ++it){
    int d = it*256 + lane*4;
    float4 fv = *reinterpret_cast<const float4*>(f + d);
    float4 wv = *reinterpret_cast<const float4*>(w + d);
    s = fmaf(fv.x, wv.x, s);
    s = fmaf(fv.y, wv.y, s);
    s = fmaf(fv.z, wv.z, s);
    s = fmaf(fv.w, wv.w, s);
  }
  #pragma unroll
  for (int off=32; off; off>>=1) s += __shfl_down(s, off, 64);
  if (lane == 0) g[(size_t)b*72 + h] = fmaxf(s + gb1[h], 0.f);
}

__global__ __launch_bounds__(128) void gate2_k(
    const float* __restrict__ g, const float* __restrict__ gw2,
    const float* __restrict__ gb2, float* __restrict__ gates)
{
  const int b = blockIdx.x;
  const int tid = threadIdx.x;
  __shared__ float gs[72];
  __shared__ float logits[8];
  if (tid < 72) gs[tid] = g[(size_t)b*72 + tid];
  __syncthreads();
  if (tid < 8) {
    float acc = gb2[tid];
    for (int j=0;j<72;++j)
      acc = fmaf(gs[j], gw2[(size_t)j*8 + tid], acc);
    logits[tid] = acc;
  }
  __syncthreads();
  if (tid == 0) {
    int i1 = 0; float v1 = logits[0];
    for (int e=1;e<8;++e) if (logits[e] > v1) { v1 = logits[e]; i1 = e; }
    int i2 = -1; float v2 = -INFINITY;
    for (int e=0;e<8;++e) { if (e==i1) continue; if (logits[e] > v2) { v2 = logits[e]; i2 = e; } }
    float z  = expf(v2 - v1);
    float w1 = 1.f / (1.f + z);
    float w2 = z   / (1.f + z);
    float* gr = gates + (size_t)b*8;
    for (int e=0;e<8;++e) gr[e] = 0.f;
    gr[i1] = w1;
    gr[i2] = w2;
  }
}

// ========== expert h1 dense split-K GEMM (48-way split) ==========
__global__ __launch_bounds__(256, 2) void eh1_part_k(
    const float* __restrict__ feat, const float* __restrict__ ew1,
    float* __restrict__ part)
{
  const int e  = blockIdx.x;
  const int ks = blockIdx.y;
  const int nb = blockIdx.z;
  const int h0 = nb*144;
  __shared__ __align__(16) float fs[64*33];
  __shared__ __align__(16) float wsh[32*144];
  const int tid = threadIdx.x;
  const int tx = tid & 15;
  const int ty = tid >> 4;
  float acc[4][9];
  #pragma unroll
  for (int i=0;i<4;++i)
    #pragma unroll
    for (int j=0;j<9;++j) acc[i][j]=0.f;
  const float* wbase = ew1 + (size_t)e*9216*288 + h0;
  for (int d0 = ks*192; d0 < ks*192+192; d0 += 32){
    __syncthreads();
    for (int l = tid; l < 512; l += 256){
      int r = l >> 3, c = l & 7;
      float4 v = *reinterpret_cast<const float4*>(feat + (size_t)r*9216 + d0 + c*4);
      float* dst = &fs[r*33 + c*4];
      dst[0]=v.x; dst[1]=v.y; dst[2]=v.z; dst[3]=v.w;
    }
    for (int l = tid; l < 1152; l += 256){
      int r = l / 36, c = l % 36;
      *reinterpret_cast<float4*>(&wsh[r*144 + c*4]) =
        *reinterpret_cast<const float4*>(wbase + (size_t)(d0 + r)*288 + c*4);
    }
    __syncthreads();
    #pragma unroll
    for (int k=0;k<32;++k){
      float fv[4], wv[9];
      #pragma unroll
      for (int i=0;i<4;++i) fv[i] = fs[(ty*4+i)*33 + k];
      #pragma unroll
      for (int j=0;j<9;++j) wv[j] = wsh[k*144 + tx*9 + j];
      #pragma unroll
      for (int i=0;i<4;++i)
        #pragma unroll
        for (int j=0;j<9;++j)
          acc[i][j] = fmaf(fv[i], wv[j], acc[i][j]);
    }
  }
  float* pp = part + (size_t)(ks*8 + e)*64*288;
  #pragma unroll
  for (int i=0;i<4;++i)
    #pragma unroll
    for (int j=0;j<9;++j)
      pp[(ty*4+i)*288 + h0 + tx*9 + j] = acc[i][j];
}

__global__ __launch_bounds__(TPB) void eh1_reduce_k(
    const float* __restrict__ part, const float* __restrict__ eb1,
    float* __restrict__ h1)
{
  int idx = blockIdx.x*TPB + threadIdx.x;
  if (idx >= 8*64*288) return;
  int h = idx % 288;
  int e = idx / (64*288);
  float a = eb1[(size_t)e*288 + h];
  #pragma unroll
  for (int s=0;s<48;++s)
    a += part[(size_t)s*147456 + idx];
  h1[idx] = fmaxf(a, 0.f);
}

__global__ __launch_bounds__(TPB) void expert_h2_k(
    const float* __restrict__ h1, const float* __restrict__ ew2,
    const float* __restrict__ eb2, const float* __restrict__ gates,
    float* __restrict__ h2)
{
  int idx = blockIdx.x*TPB + threadIdx.x;
  if (idx >= 8*64*144) return;
  int k = idx % 144;
  int t = idx / 144;
  int b = t % 64;
  int e = t / 64;
  if (gates[(size_t)b*8 + e] == 0.f) return;
  float acc = eb2[(size_t)e*144 + k];
  const float* h = h1 + ((size_t)e*64 + b)*288;
  const float* w = ew2 + (size_t)e*288*144 + k;
  for (int d=0; d<288; ++d)
    acc = fmaf(h[d], w[(size_t)d*144], acc);
  h2[idx] = fmaxf(acc, 0.f);
}

__global__ __launch_bounds__(TPB) void expert_out_k(
    const float* __restrict__ h2, const float* __restrict__ ew3,
    const float* __restrict__ eb3, const float* __restrict__ gates,
    float* __restrict__ out)
{
  int idx = blockIdx.x*TPB + threadIdx.x;
  if (idx >= 64*1000) return;
  int o = idx % 1000;
  int b = idx / 1000;
  float acc = 0.f;
  const float* gr = gates + (size_t)b*8;
  for (int e=0;e<8;++e){
    float ge = gr[e];
    if (ge == 0.f) continue;
    float a = eb3[(size_t)e*1000 + o];
    const float* h = h2 + ((size_t)e*64 + b)*144;
    const float* w = ew3 + (size_t)e*144*1000 + o;
    for (int k=0;k<144;++k)
      a = fmaf(h[k], w[(size_t)k*1000], a);
    acc = fmaf(ge, a, acc);
  }
  out[idx] = acc;
}

static inline int nblk(long long n){ return (int)((n + TPB - 1) / TPB); }

extern "C" void kernel_launch(void* const* d_in, const int* in_sizes, int n_in,
                              void* d_out, int out_size, void* d_ws, size_t ws_size,
                              hipStream_t stream)
{
  const float* x   = (const float*)d_in[0];
  const float* c1w = (const float*)d_in[1];  const float* c1b = (const float*)d_in[2];
  const float* c2w = (const float*)d_in[3];  const float* c2b = (const float*)d_in[4];
  const float* c3w = (const float*)d_in[5];  const float* c3b = (const float*)d_in[6];
  const float* c4w = (const float*)d_in[7];  const float* c4b = (const float*)d_in[8];
  const float* c5w = (const float*)d_in[9];  const float* c5b = (const float*)d_in[10];
  const float* gw1 = (const float*)d_in[11]; const float* gb1 = (const float*)d_in[12];
  const float* gw2 = (const float*)d_in[13]; const float* gb2 = (const float*)d_in[14];
  const float* ew1 = (const float*)d_in[15]; const float* eb1 = (const float*)d_in[16];
  const float* ew2 = (const float*)d_in[17]; const float* eb2 = (const float*)d_in[18];
  const float* ew3 = (const float*)d_in[19]; const float* eb3 = (const float*)d_in[20];
  float* out = (float*)d_out;

  float* W = (float*)d_ws;
  short* X1H = (short*)W;
  short* X1L = X1H + 12390400;
  short* X3H = (short*)W;
  short* X3L = X3H + 8957952;
  short* X5H = (short*)W;
  short* X5L = X5H + 4153344;
  short* X7H = (short*)W;
  short* X7L = X7H + 2768896;
  float* feat  = W + 5000000;
  float* part  = W + 6000000;
  short* WH2 = (short*)(W +  9000000);
  short* WL2 = WH2 + 307200;
  short* WH3 = (short*)(W +  9320000);
  short* WL3 = WH3 + 663552;
  short* WH4 = (short*)(W + 10000000);
  short* WL4 = WH4 + 884736;
  short* WH5 = (short*)(W + 10900000);
  short* WL5 = WH5 + 589824;
  float* GT1 = W + 11500000;
  short* X2H = (short*)(W + 12390400);
  short* X2L = X2H + 2985984;
  short* X4H = (short*)(W + 12390400);
  short* X4L = X4H + 2076672;
  short* X6H = (short*)(W + 12390400);
  short* X6L = X6H + 2768896;
  float* gates = W + 14000000;
  float* h1    = gates + 512;
  float* h2    = h1 + 147456;
  float* gbuf  = h2 + 73728;
  short* WH1 = (short*)(W + 15400000);
  short* WL1 = WH1 + 36864;
  (void)ws_size; (void)in_sizes; (void)n_in; (void)out_size;

  wsplit1_k<<<nblk(64LL*576), TPB, 0, stream>>>(c1w, WH1, WL1);
  conv1m_k<<<55*64, 256, 0, stream>>>(x, WH1, WL1, c1b, X1H, X1L);
  pool1_k<<<nblk(64LL*729*64), TPB, 0, stream>>>(X1H, X1L, X2H, X2L);
  wsplit_k<<<nblk(25LL*192*64),  TPB, 0, stream>>>(c2w, WH2, WL2,  64, 192, 25, 25*192*64);
  wsplit_k<<<nblk(9LL*384*192),  TPB, 0, stream>>>(c3w, WH3, WL3, 192, 384,  9, 9*384*192);
  wsplit_k<<<nblk(9LL*256*384),  TPB, 0, stream>>>(c4w, WH4, WL4, 384, 256,  9, 9*256*384);
  wsplit_k<<<nblk(9LL*256*256),  TPB, 0, stream>>>(c5w, WH5, WL5, 256, 256,  9, 9*256*256);
  wtrans_k<<<nblk(72LL*9216),    TPB, 0, stream>>>(gw1, GT1, 72, 9216);

  conv2m_k<<<dim3(9,64), 256, 0, stream>>>(X2H, X2L, WH2, WL2, c2b, X3H, X3L);
  pool2_k<<<nblk(64LL*169*192), TPB, 0, stream>>>(X3H, X3L, X4H, X4L);
  conv3m_k<192,384><<<dim3(12,64), 256, 0, stream>>>(X4H, X4L, WH3, WL3, c3b, X5H, X5L);
  conv3m_k<384,256><<<dim3(8,64),  256, 0, stream>>>(X5H, X5L, WH4, WL4, c4b, X6H, X6L);
  conv3m_k<256,256><<<dim3(8,64),  256, 0, stream>>>(X6H, X6L, WH5, WL5, c5b, X7H, X7L);
  pool3_k<<<nblk(64LL*9216), TPB, 0, stream>>>(X7H, X7L, feat);

  gate1_k<<<dim3(64,18), 256, 0, stream>>>(feat, GT1, gb1, gbuf);
  gate2_k<<<64, 128, 0, stream>>>(gbuf, gw2, gb2, gates);

  eh1_part_k<<<dim3(8,48,2), 256, 0, stream>>>(feat, ew1, part);
  eh1_reduce_k<<<nblk(8LL*64*288), TPB, 0, stream>>>(part, eb1, h1);
  expert_h2_k<<<nblk(8LL*64*144), TPB, 0, stream>>>(h1, ew2, eb2, gates, h2);
  expert_out_k<<<nblk(64LL*1000), TPB, 0, stream>>>(h2, ew3, eb3, gates, out);
}

// Round 15
// 576.258 us; speedup vs baseline: 1.8902x; 1.0153x over previous
//
#include <hip/hip_runtime.h>
#include <math.h>

#define TPB 256

typedef short s16x8 __attribute__((ext_vector_type(8)));
typedef short s16x4 __attribute__((ext_vector_type(4)));
typedef float f32x4 __attribute__((ext_vector_type(4)));

__device__ inline void bsplit(float x, short& h, short& l){
  union { float f; unsigned u; } a, hf, rf;
  a.f = x;
  unsigned hu = (a.u + 0x7FFFu + ((a.u >> 16) & 1u)) >> 16;
  h = (short)hu;
  hf.u = hu << 16;
  rf.f = x - hf.f;
  l = (short)((rf.u + 0x7FFFu + ((rf.u >> 16) & 1u)) >> 16);
}
__device__ inline float b2f(short s){
  union { unsigned u; float f; } x;
  x.u = ((unsigned)(unsigned short)s) << 16;
  return x.f;
}

// ==== weight split + MFMA-native reorder ====
__global__ __launch_bounds__(TPB) void wsplit_k(
    const float* __restrict__ w, short* __restrict__ wh, short* __restrict__ wl,
    int C, int O, int ntap, int total)
{
  int idx = blockIdx.x*TPB + threadIdx.x;
  if (idx >= total) return;
  int c   = idx % C;
  int t2  = idx / C;
  int oc  = t2 % O;
  int tap = t2 / O;
  float x = w[((size_t)oc*C + c)*ntap + tap];
  short h, l; bsplit(x, h, l);
  int tile = oc >> 4, ln = oc & 15;
  int S    = ntap*(C >> 5);
  int sl   = tap*(C >> 5) + (c >> 5);
  int lg   = (c >> 3) & 3, j = c & 7;
  size_t dst = (((size_t)tile*S + sl)*64 + lg*16 + ln)*8 + j;
  wh[dst] = h; wl[dst] = l;
}

__global__ __launch_bounds__(TPB) void wsplit1_k(
    const float* __restrict__ w, short* __restrict__ wh, short* __restrict__ wl)
{
  int idx = blockIdx.x*TPB + threadIdx.x;
  if (idx >= 64*576) return;
  int k  = idx % 576;
  int oc = idx / 576;
  int g  = k >> 4, kw = k & 15;
  int c  = g / 12, kh = g % 12;
  float x = 0.f;
  if (kh < 11 && kw < 11)
    x = w[((size_t)oc*3 + c)*121 + kh*11 + kw];
  short h, l; bsplit(x, h, l);
  int m = oc >> 4, ln = oc & 15;
  int s = k >> 5, r = k & 31;
  int lg = r >> 3, j = r & 7;
  size_t dst = (((size_t)m*18 + s)*64 + lg*16 + ln)*8 + j;
  wh[dst] = h; wl[dst] = l;
}

__global__ __launch_bounds__(TPB) void wtrans_k(
    const float* __restrict__ w, float* __restrict__ wT, int K, int O)
{
  int idx = blockIdx.x*TPB + threadIdx.x;
  if (idx >= K*O) return;
  int oc = idx % O;
  int k  = idx / O;
  wT[idx] = w[(size_t)oc*K + k];
}

// ============== conv1 MFMA (im2col along kw); out: split ch-minor [3025][64] ====
#define C1W 240
#define CV1_PL 33
__global__ __launch_bounds__(256, 4) void conv1m_k(
    const float* __restrict__ in, const short* __restrict__ whi,
    const short* __restrict__ wlo, const float* __restrict__ bias,
    short* __restrict__ yh, short* __restrict__ yl)
{
  __shared__ __align__(16) short lds[2][CV1_PL*C1W + 84];
  const int tid = threadIdx.x;
  const int oh = blockIdx.x % 55;
  const int b  = blockIdx.x / 55;
  const int nt = tid >> 6;
  const int ln = tid & 15;
  const int lg = (tid & 63) >> 4;
  const int lane = tid & 63;
  const int ow = nt*16 + ln;

  const float* ip = in + (size_t)b*3*224*224;
  for (int i = tid; i < CV1_PL*59; i += 256){
    int plane = i / 59;
    int p     = i % 59;
    int c = plane / 11, kh = plane % 11;
    int ih = oh*4 - 2 + kh;
    int col0 = p*4;
    const float* rowp = (ih >= 0 && ih < 224) ? ip + (size_t)c*50176 + (size_t)ih*224 : nullptr;
    short h[4], l[4];
    #pragma unroll
    for (int j=0;j<4;++j){
      int iw = col0 + j - 2;
      float v = (rowp && iw >= 0 && iw < 224) ? rowp[iw] : 0.f;
      bsplit(v, h[j], l[j]);
    }
    s16x4 hv = {h[0],h[1],h[2],h[3]}, lv = {l[0],l[1],l[2],l[3]};
    *reinterpret_cast<s16x4*>(&lds[0][plane*C1W + col0]) = hv;
    *reinterpret_cast<s16x4*>(&lds[1][plane*C1W + col0]) = lv;
  }
  __syncthreads();

  f32x4 acc[4];
  #pragma unroll
  for (int m=0;m<4;++m){
    const float4 bv = *reinterpret_cast<const float4*>(bias + m*16 + lg*4);
    acc[m] = (f32x4){bv.x, bv.y, bv.z, bv.w};
  }

  s16x8 ah[4], al[4], ahn[4], aln[4];
  #pragma unroll
  for (int m=0;m<4;++m){
    size_t ao = (((size_t)m*18 + 0)*64 + lane)*8;
    ah[m] = *reinterpret_cast<const s16x8*>(whi + ao);
    al[m] = *reinterpret_cast<const s16x8*>(wlo + ao);
  }

  #pragma unroll 1
  for (int s=0; s<18; ++s){
    if (s < 17){
      #pragma unroll
      for (int m=0;m<4;++m){
        size_t ao = (((size_t)m*18 + s + 1)*64 + lane)*8;
        ahn[m] = *reinterpret_cast<const s16x8*>(whi + ao);
        aln[m] = *reinterpret_cast<const s16x8*>(wlo + ao);
      }
    }
    int g  = 2*s + (lg >> 1);
    int c  = g / 12, kh = g % 12;
    int plane = c*11 + (kh < 11 ? kh : 10);
    int base  = plane*C1W + ow*4 + (lg & 1)*8;
    s16x4 h0 = *reinterpret_cast<const s16x4*>(&lds[0][base]);
    s16x4 h1 = *reinterpret_cast<const s16x4*>(&lds[0][base+4]);
    s16x4 l0 = *reinterpret_cast<const s16x4*>(&lds[1][base]);
    s16x4 l1 = *reinterpret_cast<const s16x4*>(&lds[1][base+4]);
    s16x8 bh = __builtin_shufflevector(h0, h1, 0,1,2,3,4,5,6,7);
    s16x8 bl = __builtin_shufflevector(l0, l1, 0,1,2,3,4,5,6,7);
    #pragma unroll
    for (int m=0;m<4;++m){
      acc[m] = __builtin_amdgcn_mfma_f32_16x16x32_bf16(al[m], bh, acc[m], 0,0,0);
      acc[m] = __builtin_amdgcn_mfma_f32_16x16x32_bf16(ah[m], bl, acc[m], 0,0,0);
      acc[m] = __builtin_amdgcn_mfma_f32_16x16x32_bf16(ah[m], bh, acc[m], 0,0,0);
    }
    #pragma unroll
    for (int m=0;m<4;++m){ ah[m] = ahn[m]; al[m] = aln[m]; }
  }

  if (ow < 55){
    size_t base = ((size_t)b*3025 + (size_t)oh*55 + ow)*64;
    #pragma unroll
    for (int m=0;m<4;++m){
      short h[4], l[4];
      #pragma unroll
      for (int r=0;r<4;++r) bsplit(fmaxf(acc[m][r], 0.f), h[r], l[r]);
      s16x4 hv = {h[0],h[1],h[2],h[3]}, lv = {l[0],l[1],l[2],l[3]};
      *reinterpret_cast<s16x4*>(yh + base + m*16 + lg*4) = hv;
      *reinterpret_cast<s16x4*>(yl + base + m*16 + lg*4) = lv;
    }
  }
}

// ---- pool1: X1[3025][64] split -> X2[729][64] split ----
__global__ __launch_bounds__(TPB) void pool1_k(
    const short* __restrict__ xh, const short* __restrict__ xl,
    short* __restrict__ yh, short* __restrict__ yl)
{
  int i = blockIdx.x*TPB + threadIdx.x;
  if (i >= 64*729*64) return;
  int c = i & 63;
  int t = i >> 6;
  int sp = t % 729;
  int b = t / 729;
  int r = sp/27, cc = sp%27;
  const short* ph = xh + (size_t)b*3025*64 + c;
  const short* pl = xl + (size_t)b*3025*64 + c;
  float m = -INFINITY;
  #pragma unroll
  for (int di=0;di<3;++di)
    #pragma unroll
    for (int dj=0;dj<3;++dj){
      size_t s = (size_t)((2*r+di)*55 + 2*cc+dj)*64;
      m = fmaxf(m, b2f(ph[s]) + b2f(pl[s]));
    }
  short h, l; bsplit(m, h, l);
  yh[i] = h; yl[i] = l;
}

// ============== conv2 MFMA v3: 32-ch chunks + A-prefetch ==============
__global__ __launch_bounds__(256, 4) void conv2m_k(
    const short* __restrict__ xh, const short* __restrict__ xl,
    const short* __restrict__ whi, const short* __restrict__ wlo,
    const float* __restrict__ bias, short* __restrict__ yh, short* __restrict__ yl)
{
  __shared__ __align__(16) short lds[2][217*40];
  const int tid = threadIdx.x;
  const int rg  = blockIdx.x;
  const int b   = blockIdx.y;
  const int wid = tid >> 6;
  const int ln  = tid & 15;
  const int lg  = (tid & 63) >> 4;
  const int lane = tid & 63;
  const int oc0 = wid*48;
  const int r0  = rg*3;

  int sb[6], nn[6];
  #pragma unroll
  for (int t=0;t<6;++t){
    int n = t*16 + ln;
    nn[t] = n;
    int ohl = n / 27, ow = n % 27;
    sb[t] = (n < 81) ? (ohl*31 + ow) : 0;
  }

  f32x4 acc[3][6];
  #pragma unroll
  for (int m=0;m<3;++m){
    const float4 bv = *reinterpret_cast<const float4*>(bias + oc0 + m*16 + lg*4);
    #pragma unroll
    for (int t=0;t<6;++t) acc[m][t] = (f32x4){bv.x, bv.y, bv.z, bv.w};
  }

  #pragma unroll 1
  for (int c0=0; c0<64; c0+=32){
    __syncthreads();
    for (int i = tid; i < 217*4; i += 256){
      int sp = i >> 2, v = i & 3;
      int pr = sp/31, pc = sp%31;
      int ih = r0 - 2 + pr, iw = pc - 2;
      s16x8 hv = {0,0,0,0,0,0,0,0}, lv = {0,0,0,0,0,0,0,0};
      if (ih >= 0 && ih < 27 && iw >= 0 && iw < 27){
        size_t o = ((size_t)b*729 + ih*27 + iw)*64 + c0 + v*8;
        hv = *reinterpret_cast<const s16x8*>(xh + o);
        lv = *reinterpret_cast<const s16x8*>(xl + o);
      }
      *reinterpret_cast<s16x8*>(&lds[0][sp*40 + v*8]) = hv;
      *reinterpret_cast<s16x8*>(&lds[1][sp*40 + v*8]) = lv;
    }
    __syncthreads();

    const size_t tstr = 50*512;
    const size_t abase = ((size_t)(wid*3)*50 + (c0 >> 5))*512 + (size_t)lane*8;
    s16x8 ah0 = *reinterpret_cast<const s16x8*>(whi + abase);
    s16x8 ah1 = *reinterpret_cast<const s16x8*>(whi + abase + tstr);
    s16x8 ah2 = *reinterpret_cast<const s16x8*>(whi + abase + 2*tstr);
    s16x8 al0 = *reinterpret_cast<const s16x8*>(wlo + abase);
    s16x8 al1 = *reinterpret_cast<const s16x8*>(wlo + abase + tstr);
    s16x8 al2 = *reinterpret_cast<const s16x8*>(wlo + abase + 2*tstr);

    #pragma unroll 1
    for (int tap=0; tap<25; ++tap){
      s16x8 nh0=ah0, nh1=ah1, nh2=ah2, nl0=al0, nl1=al1, nl2=al2;
      if (tap < 24){
        size_t ao = abase + (size_t)(tap+1)*2*512;
        nh0 = *reinterpret_cast<const s16x8*>(whi + ao);
        nh1 = *reinterpret_cast<const s16x8*>(whi + ao + tstr);
        nh2 = *reinterpret_cast<const s16x8*>(whi + ao + 2*tstr);
        nl0 = *reinterpret_cast<const s16x8*>(wlo + ao);
        nl1 = *reinterpret_cast<const s16x8*>(wlo + ao + tstr);
        nl2 = *reinterpret_cast<const s16x8*>(wlo + ao + 2*tstr);
      }
      const int toff = (tap/5)*31 + (tap%5);
      #pragma unroll
      for (int t=0;t<6;++t){
        int off = (sb[t] + toff)*40 + lg*8;
        s16x8 bh = *reinterpret_cast<const s16x8*>(&lds[0][off]);
        s16x8 bl = *reinterpret_cast<const s16x8*>(&lds[1][off]);
        acc[0][t] = __builtin_amdgcn_mfma_f32_16x16x32_bf16(al0, bh, acc[0][t], 0,0,0);
        acc[0][t] = __builtin_amdgcn_mfma_f32_16x16x32_bf16(ah0, bl, acc[0][t], 0,0,0);
        acc[0][t] = __builtin_amdgcn_mfma_f32_16x16x32_bf16(ah0, bh, acc[0][t], 0,0,0);
        acc[1][t] = __builtin_amdgcn_mfma_f32_16x16x32_bf16(al1, bh, acc[1][t], 0,0,0);
        acc[1][t] = __builtin_amdgcn_mfma_f32_16x16x32_bf16(ah1, bl, acc[1][t], 0,0,0);
        acc[1][t] = __builtin_amdgcn_mfma_f32_16x16x32_bf16(ah1, bh, acc[1][t], 0,0,0);
        acc[2][t] = __builtin_amdgcn_mfma_f32_16x16x32_bf16(al2, bh, acc[2][t], 0,0,0);
        acc[2][t] = __builtin_amdgcn_mfma_f32_16x16x32_bf16(ah2, bl, acc[2][t], 0,0,0);
        acc[2][t] = __builtin_amdgcn_mfma_f32_16x16x32_bf16(ah2, bh, acc[2][t], 0,0,0);
      }
      ah0=nh0; ah1=nh1; ah2=nh2; al0=nl0; al1=nl1; al2=nl2;
    }
  }

  #pragma unroll
  for (int m=0;m<3;++m)
    #pragma unroll
    for (int t=0;t<6;++t){
      if (nn[t] < 81){
        int gsp = r0*27 + nn[t];
        size_t base = ((size_t)b*729 + gsp)*192 + oc0 + m*16 + lg*4;
        short h[4], l[4];
        #pragma unroll
        for (int r=0;r<4;++r) bsplit(fmaxf(acc[m][t][r], 0.f), h[r], l[r]);
        s16x4 hv = {h[0],h[1],h[2],h[3]}, lv = {l[0],l[1],l[2],l[3]};
        *reinterpret_cast<s16x4*>(yh + base) = hv;
        *reinterpret_cast<s16x4*>(yl + base) = lv;
      }
    }
}

// ---- pool2: X3[729][192] split -> X4[169][192] split ----
__global__ __launch_bounds__(TPB) void pool2_k(
    const short* __restrict__ xh, const short* __restrict__ xl,
    short* __restrict__ yh, short* __restrict__ yl)
{
  int i = blockIdx.x*TPB + threadIdx.x;
  if (i >= 64*169*192) return;
  int c = i % 192;
  int t = i / 192;
  int sp = t % 169;
  int b = t / 169;
  int r = sp/13, cc = sp%13;
  const short* ph = xh + (size_t)b*729*192 + c;
  const short* pl = xl + (size_t)b*729*192 + c;
  float m = -INFINITY;
  #pragma unroll
  for (int di=0;di<3;++di)
    #pragma unroll
    for (int dj=0;dj<3;++dj){
      size_t s = (size_t)((2*r+di)*27 + 2*cc+dj)*192;
      m = fmaxf(m, b2f(ph[s]) + b2f(pl[s]));
    }
  short h, l; bsplit(m, h, l);
  yh[i] = h; yl[i] = l;
}

// ============== conv3/4/5 MFMA; in: split ch-minor [169][C]; out: [169][O] =====
template<int C,int O>
__global__ __launch_bounds__(256, 4) void conv3m_k(
    const short* __restrict__ xh, const short* __restrict__ xl,
    const short* __restrict__ whi, const short* __restrict__ wlo,
    const float* __restrict__ bias, short* __restrict__ yh, short* __restrict__ yl)
{
  __shared__ __align__(16) short lds[2][225*40];
  const int tid = threadIdx.x;
  const int b   = blockIdx.y;
  const int wid = tid >> 6;
  const int ln  = tid & 15;
  const int lg  = (tid & 63) >> 4;
  const int lane = tid & 63;
  const int tileIdx = blockIdx.x*2 + (wid & 1);
  const int oc0 = tileIdx*16;
  const int ng  = wid >> 1;
  const int tbase  = ng ? 6 : 0;
  const int ntiles = ng ? 5 : 6;
  const int S3 = 9*(C/32);

  int sb[6], nn[6];
  #pragma unroll
  for (int t=0;t<6;++t){
    int n = (tbase + t)*16 + ln;
    nn[t] = n;
    int oh = n / 13, ow = n % 13;
    sb[t] = (n < 169) ? (oh*15 + ow) : 0;
  }

  f32x4 acc[6];
  const float4 bv = *reinterpret_cast<const float4*>(bias + oc0 + lg*4);
  #pragma unroll
  for (int t=0;t<6;++t) acc[t] = (f32x4){bv.x, bv.y, bv.z, bv.w};

  #pragma unroll 1
  for (int c0=0; c0<C; c0+=32){
    __syncthreads();
    for (int i = tid; i < 225*4; i += 256){
      int sp = i >> 2, v = i & 3;
      int r = sp/15, cc = sp%15;
      s16x8 hv = {0,0,0,0,0,0,0,0}, lv = {0,0,0,0,0,0,0,0};
      if (r >= 1 && r <= 13 && cc >= 1 && cc <= 13){
        size_t o = ((size_t)b*169 + (r-1)*13 + (cc-1))*C + c0 + v*8;
        hv = *reinterpret_cast<const s16x8*>(xh + o);
        lv = *reinterpret_cast<const s16x8*>(xl + o);
      }
      *reinterpret_cast<s16x8*>(&lds[0][sp*40 + v*8]) = hv;
      *reinterpret_cast<s16x8*>(&lds[1][sp*40 + v*8]) = lv;
    }
    __syncthreads();

    const size_t tb = (size_t)tileIdx*S3 + (c0 >> 5);
    s16x8 ah = *reinterpret_cast<const s16x8*>(whi + (tb*64 + lane)*8);
    s16x8 al = *reinterpret_cast<const s16x8*>(wlo + (tb*64 + lane)*8);
    #pragma unroll 1
    for (int tap=0; tap<9; ++tap){
      s16x8 ahn = ah, aln = al;
      if (tap < 8){
        size_t ao = ((tb + (size_t)(tap+1)*(C/32))*64 + lane)*8;
        ahn = *reinterpret_cast<const s16x8*>(whi + ao);
        aln = *reinterpret_cast<const s16x8*>(wlo + ao);
      }
      const int toff = (tap/3)*15 + (tap%3);
      #pragma unroll
      for (int t=0;t<6;++t){
        if (t < ntiles){
          int off = (sb[t] + toff)*40 + lg*8;
          s16x8 bh = *reinterpret_cast<const s16x8*>(&lds[0][off]);
          s16x8 bl = *reinterpret_cast<const s16x8*>(&lds[1][off]);
          acc[t] = __builtin_amdgcn_mfma_f32_16x16x32_bf16(al, bh, acc[t], 0,0,0);
          acc[t] = __builtin_amdgcn_mfma_f32_16x16x32_bf16(ah, bl, acc[t], 0,0,0);
          acc[t] = __builtin_amdgcn_mfma_f32_16x16x32_bf16(ah, bh, acc[t], 0,0,0);
        }
      }
      ah = ahn; al = aln;
    }
  }

  #pragma unroll
  for (int t=0;t<6;++t){
    if (t < ntiles && nn[t] < 169){
      size_t base = ((size_t)b*169 + nn[t])*O + oc0 + lg*4;
      short h[4], l[4];
      #pragma unroll
      for (int r=0;r<4;++r) bsplit(fmaxf(acc[t][r], 0.f), h[r], l[r]);
      s16x4 hv = {h[0],h[1],h[2],h[3]}, lv = {l[0],l[1],l[2],l[3]};
      *reinterpret_cast<s16x4*>(yh + base) = hv;
      *reinterpret_cast<s16x4*>(yl + base) = lv;
    }
  }
}

// ---- pool3: X7[169][256] split -> feat[b][9216] f32 (d = c*36 + sp) ----
__global__ __launch_bounds__(TPB) void pool3_k(
    const short* __restrict__ xh, const short* __restrict__ xl,
    float* __restrict__ feat)
{
  int i = blockIdx.x*TPB + threadIdx.x;
  if (i >= 64*9216) return;
  int d = i % 9216;
  int b = i / 9216;
  int c = d / 36;
  int sp = d % 36;
  int r = sp/6, cc = sp%6;
  const short* ph = xh + (size_t)b*169*256 + c;
  const short* pl = xl + (size_t)b*169*256 + c;
  float m = -INFINITY;
  #pragma unroll
  for (int di=0;di<3;++di)
    #pragma unroll
    for (int dj=0;dj<3;++dj){
      size_t s = (size_t)((2*r+di)*13 + 2*cc+dj)*256;
      m = fmaxf(m, b2f(ph[s]) + b2f(pl[s]));
    }
  feat[i] = m;
}

// ---- featsplit: feat[b][9216] -> featBT B-native [288 s][4 nt][64 lane][8 j] ----
__global__ __launch_bounds__(TPB) void featsplit_k(
    const float* __restrict__ feat, short* __restrict__ fbh, short* __restrict__ fbl)
{
  int idx = blockIdx.x*TPB + threadIdx.x;
  if (idx >= 589824) return;
  int j = idx & 7;
  int lane = (idx >> 3) & 63;
  int nt = (idx >> 9) & 3;
  int s = idx >> 11;
  int b = nt*16 + (lane & 15);
  int d = s*32 + (lane >> 4)*8 + j;
  short h, l; bsplit(feat[(size_t)b*9216 + d], h, l);
  fbh[idx] = h; fbl[idx] = l;
}

// ---------------- gate ----------------
__global__ __launch_bounds__(256) void gate1_k(
    const float* __restrict__ feat, const float* __restrict__ gw1T,
    const float* __restrict__ gb1, float* __restrict__ g)
{
  const int b    = blockIdx.x;
  const int h    = blockIdx.y*4 + (threadIdx.x >> 6);
  const int lane = threadIdx.x & 63;
  const float* f = feat + (size_t)b*9216;
  const float* w = gw1T + (size_t)h*9216;
  float s = 0.f;
  #pragma unroll
  for (int it=0; it<36; ++it){
    int d = it*256 + lane*4;
    float4 fv = *reinterpret_cast<const float4*>(f + d);
    float4 wv = *reinterpret_cast<const float4*>(w + d);
    s = fmaf(fv.x, wv.x, s);
    s = fmaf(fv.y, wv.y, s);
    s = fmaf(fv.z, wv.z, s);
    s = fmaf(fv.w, wv.w, s);
  }
  #pragma unroll
  for (int off=32; off; off>>=1) s += __shfl_down(s, off, 64);
  if (lane == 0) g[(size_t)b*72 + h] = fmaxf(s + gb1[h], 0.f);
}

__global__ __launch_bounds__(128) void gate2_k(
    const float* __restrict__ g, const float* __restrict__ gw2,
    const float* __restrict__ gb2, float* __restrict__ gates)
{
  const int b = blockIdx.x;
  const int tid = threadIdx.x;
  __shared__ float gs[72];
  __shared__ float logits[8];
  if (tid < 72) gs[tid] = g[(size_t)b*72 + tid];
  __syncthreads();
  if (tid < 8) {
    float acc = gb2[tid];
    for (int j=0;j<72;++j)
      acc = fmaf(gs[j], gw2[(size_t)j*8 + tid], acc);
    logits[tid] = acc;
  }
  __syncthreads();
  if (tid == 0) {
    int i1 = 0; float v1 = logits[0];
    for (int e=1;e<8;++e) if (logits[e] > v1) { v1 = logits[e]; i1 = e; }
    int i2 = -1; float v2 = -INFINITY;
    for (int e=0;e<8;++e) { if (e==i1) continue; if (logits[e] > v2) { v2 = logits[e]; i2 = e; } }
    float z  = expf(v2 - v1);
    float w1 = 1.f / (1.f + z);
    float w2 = z   / (1.f + z);
    float* gr = gates + (size_t)b*8;
    for (int e=0;e<8;++e) gr[e] = 0.f;
    gr[i1] = w1;
    gr[i2] = w2;
  }
}

// ========== expert h1 MFMA streaming GEMM ==========
// grid (9 m2, 8 e, 16 ks); block 256 = 4 waves (wave = n-tile of 16 b).
// Per stage: 64d x 32h fp32 ew1 tile read coalesced (full 128B rows thanks to
// 32-h pairing), bsplit -> LDS [32h][88d]; 2 k-slices x 2 m x 3 MFMA per wave.
__global__ __launch_bounds__(256, 4) void eh1m_k(
    const float* __restrict__ ew1, const short* __restrict__ fbh,
    const short* __restrict__ fbl, float* __restrict__ part)
{
  __shared__ __align__(16) short wh_l[32*88];
  __shared__ __align__(16) short wl_l[32*88];
  const int m2 = blockIdx.x;
  const int e  = blockIdx.y;
  const int ks = blockIdx.z;
  const int tid = threadIdx.x;
  const int nt = tid >> 6;
  const int ln = tid & 15;
  const int lg = (tid & 63) >> 4;
  const int lane = tid & 63;

  f32x4 acc[2] = {(f32x4){0.f,0.f,0.f,0.f},(f32x4){0.f,0.f,0.f,0.f}};

  const float* wsrc = ew1 + (size_t)e*9216*288 + (size_t)m2*32;
  const int d0 = ks*576;

  #pragma unroll 1
  for (int st=0; st<9; ++st){
    __syncthreads();
    {
      int drow = tid >> 2;
      int h0 = (tid & 3)*8;
      const float* src = wsrc + (size_t)(d0 + st*64 + drow)*288 + h0;
      float4 v0 = *reinterpret_cast<const float4*>(src);
      float4 v1 = *reinterpret_cast<const float4*>(src+4);
      float vv[8] = {v0.x,v0.y,v0.z,v0.w,v1.x,v1.y,v1.z,v1.w};
      #pragma unroll
      for (int k=0;k<8;++k){
        short h, l; bsplit(vv[k], h, l);
        wh_l[(h0+k)*88 + drow] = h;
        wl_l[(h0+k)*88 + drow] = l;
      }
    }
    __syncthreads();
    int sg = (d0 + st*64) >> 5;
    #pragma unroll
    for (int sl=0; sl<2; ++sl){
      size_t bo = ((size_t)(sg+sl)*4 + nt)*512 + (size_t)lane*8;
      s16x8 bh = *reinterpret_cast<const s16x8*>(fbh + bo);
      s16x8 bl = *reinterpret_cast<const s16x8*>(fbl + bo);
      #pragma unroll
      for (int m=0;m<2;++m){
        int ao = (m*16 + ln)*88 + sl*32 + lg*8;
        s16x8 ah = *reinterpret_cast<const s16x8*>(&wh_l[ao]);
        s16x8 al = *reinterpret_cast<const s16x8*>(&wl_l[ao]);
        acc[m] = __builtin_amdgcn_mfma_f32_16x16x32_bf16(al, bh, acc[m], 0,0,0);
        acc[m] = __builtin_amdgcn_mfma_f32_16x16x32_bf16(ah, bl, acc[m], 0,0,0);
        acc[m] = __builtin_amdgcn_mfma_f32_16x16x32_bf16(ah, bh, acc[m], 0,0,0);
      }
    }
  }
  #pragma unroll
  for (int m=0;m<2;++m){
    int h = m2*32 + m*16 + lg*4;
    int b = nt*16 + ln;
    float* pp = part + ((size_t)(ks*8+e)*288 + h)*64 + b;
    #pragma unroll
    for (int r=0;r<4;++r)
      pp[(size_t)r*64] = acc[m][r];
  }
}

// reduce 16 ks partials + bias + relu -> h1[e][b][288]
__global__ __launch_bounds__(TPB) void eh1_reduce_k(
    const float* __restrict__ part, const float* __restrict__ eb1,
    float* __restrict__ h1)
{
  int idx = blockIdx.x*TPB + threadIdx.x;
  if (idx >= 8*288*64) return;
  int b = idx & 63;
  int h = (idx >> 6) % 288;
  int e = idx / (64*288);
  float a = eb1[(size_t)e*288 + h];
  #pragma unroll
  for (int s=0;s<16;++s)
    a += part[((size_t)(s*8+e)*288 + h)*64 + b];
  h1[((size_t)e*64 + b)*288 + h] = fmaxf(a, 0.f);
}

__global__ __launch_bounds__(TPB) void expert_h2_k(
    const float* __restrict__ h1, const float* __restrict__ ew2,
    const float* __restrict__ eb2, const float* __restrict__ gates,
    float* __restrict__ h2)
{
  int idx = blockIdx.x*TPB + threadIdx.x;
  if (idx >= 8*64*144) return;
  int k = idx % 144;
  int t = idx / 144;
  int b = t % 64;
  int e = t / 64;
  if (gates[(size_t)b*8 + e] == 0.f) return;
  float acc = eb2[(size_t)e*144 + k];
  const float* h = h1 + ((size_t)e*64 + b)*288;
  const float* w = ew2 + (size_t)e*288*144 + k;
  for (int d=0; d<288; ++d)
    acc = fmaf(h[d], w[(size_t)d*144], acc);
  h2[idx] = fmaxf(acc, 0.f);
}

__global__ __launch_bounds__(TPB) void expert_out_k(
    const float* __restrict__ h2, const float* __restrict__ ew3,
    const float* __restrict__ eb3, const float* __restrict__ gates,
    float* __restrict__ out)
{
  int idx = blockIdx.x*TPB + threadIdx.x;
  if (idx >= 64*1000) return;
  int o = idx % 1000;
  int b = idx / 1000;
  float acc = 0.f;
  const float* gr = gates + (size_t)b*8;
  for (int e=0;e<8;++e){
    float ge = gr[e];
    if (ge == 0.f) continue;
    float a = eb3[(size_t)e*1000 + o];
    const float* h = h2 + ((size_t)e*64 + b)*144;
    const float* w = ew3 + (size_t)e*144*1000 + o;
    for (int k=0;k<144;++k)
      a = fmaf(h[k], w[(size_t)k*1000], a);
    acc = fmaf(ge, a, acc);
  }
  out[idx] = acc;
}

static inline int nblk(long long n){ return (int)((n + TPB - 1) / TPB); }

extern "C" void kernel_launch(void* const* d_in, const int* in_sizes, int n_in,
                              void* d_out, int out_size, void* d_ws, size_t ws_size,
                              hipStream_t stream)
{
  const float* x   = (const float*)d_in[0];
  const float* c1w = (const float*)d_in[1];  const float* c1b = (const float*)d_in[2];
  const float* c2w = (const float*)d_in[3];  const float* c2b = (const float*)d_in[4];
  const float* c3w = (const float*)d_in[5];  const float* c3b = (const float*)d_in[6];
  const float* c4w = (const float*)d_in[7];  const float* c4b = (const float*)d_in[8];
  const float* c5w = (const float*)d_in[9];  const float* c5b = (const float*)d_in[10];
  const float* gw1 = (const float*)d_in[11]; const float* gb1 = (const float*)d_in[12];
  const float* gw2 = (const float*)d_in[13]; const float* gb2 = (const float*)d_in[14];
  const float* ew1 = (const float*)d_in[15]; const float* eb1 = (const float*)d_in[16];
  const float* ew2 = (const float*)d_in[17]; const float* eb2 = (const float*)d_in[18];
  const float* ew3 = (const float*)d_in[19]; const float* eb3 = (const float*)d_in[20];
  float* out = (float*)d_out;

  float* W = (float*)d_ws;
  short* X1H = (short*)W;
  short* X1L = X1H + 12390400;
  short* X3H = (short*)W;
  short* X3L = X3H + 8957952;
  short* X5H = (short*)W;
  short* X5L = X5H + 4153344;
  short* X7H = (short*)W;
  short* X7L = X7H + 2768896;
  float* feat  = W + 5000000;              // 589,824
  short* FBH   = (short*)(W + 5600000);    // 589,824 sh
  short* FBL   = (short*)(W + 5900000);    // 589,824 sh
  float* part  = W + 6300000;              // 16x8x288x64 = 2,359,296 (ends 8,659,296)
  short* WH2 = (short*)(W +  9000000);
  short* WL2 = WH2 + 307200;
  short* WH3 = (short*)(W +  9320000);
  short* WL3 = WH3 + 663552;
  short* WH4 = (short*)(W + 10000000);
  short* WL4 = WH4 + 884736;
  short* WH5 = (short*)(W + 10900000);
  short* WL5 = WH5 + 589824;
  float* GT1 = W + 11500000;
  short* X2H = (short*)(W + 12390400);
  short* X2L = X2H + 2985984;
  short* X4H = (short*)(W + 12390400);
  short* X4L = X4H + 2076672;
  short* X6H = (short*)(W + 12390400);
  short* X6L = X6H + 2768896;
  float* gates = W + 14000000;
  float* h1    = gates + 512;
  float* h2    = h1 + 147456;
  float* gbuf  = h2 + 73728;
  short* WH1 = (short*)(W + 15400000);
  short* WL1 = WH1 + 36864;
  (void)ws_size; (void)in_sizes; (void)n_in; (void)out_size;

  wsplit1_k<<<nblk(64LL*576), TPB, 0, stream>>>(c1w, WH1, WL1);
  conv1m_k<<<55*64, 256, 0, stream>>>(x, WH1, WL1, c1b, X1H, X1L);
  pool1_k<<<nblk(64LL*729*64), TPB, 0, stream>>>(X1H, X1L, X2H, X2L);
  wsplit_k<<<nblk(25LL*192*64),  TPB, 0, stream>>>(c2w, WH2, WL2,  64, 192, 25, 25*192*64);
  wsplit_k<<<nblk(9LL*384*192),  TPB, 0, stream>>>(c3w, WH3, WL3, 192, 384,  9, 9*384*192);
  wsplit_k<<<nblk(9LL*256*384),  TPB, 0, stream>>>(c4w, WH4, WL4, 384, 256,  9, 9*256*384);
  wsplit_k<<<nblk(9LL*256*256),  TPB, 0, stream>>>(c5w, WH5, WL5, 256, 256,  9, 9*256*256);
  wtrans_k<<<nblk(72LL*9216),    TPB, 0, stream>>>(gw1, GT1, 72, 9216);

  conv2m_k<<<dim3(9,64), 256, 0, stream>>>(X2H, X2L, WH2, WL2, c2b, X3H, X3L);
  pool2_k<<<nblk(64LL*169*192), TPB, 0, stream>>>(X3H, X3L, X4H, X4L);
  conv3m_k<192,384><<<dim3(12,64), 256, 0, stream>>>(X4H, X4L, WH3, WL3, c3b, X5H, X5L);
  conv3m_k<384,256><<<dim3(8,64),  256, 0, stream>>>(X5H, X5L, WH4, WL4, c4b, X6H, X6L);
  conv3m_k<256,256><<<dim3(8,64),  256, 0, stream>>>(X6H, X6L, WH5, WL5, c5b, X7H, X7L);
  pool3_k<<<nblk(64LL*9216), TPB, 0, stream>>>(X7H, X7L, feat);

  // gate
  gate1_k<<<dim3(64,18), 256, 0, stream>>>(feat, GT1, gb1, gbuf);
  gate2_k<<<64, 128, 0, stream>>>(gbuf, gw2, gb2, gates);

  // experts: MFMA streaming GEMM for h1
  featsplit_k<<<nblk(589824LL), TPB, 0, stream>>>(feat, FBH, FBL);
  eh1m_k<<<dim3(9,8,16), 256, 0, stream>>>(ew1, FBH, FBL, part);
  eh1_reduce_k<<<nblk(8LL*288*64), TPB, 0, stream>>>(part, eb1, h1);
  expert_h2_k<<<nblk(8LL*64*144), TPB, 0, stream>>>(h1, ew2, eb2, gates, h2);
  expert_out_k<<<nblk(64LL*1000), TPB, 0, stream>>>(h2, ew3, eb3, gates, out);
}

// Round 16
// 534.239 us; speedup vs baseline: 2.0388x; 1.0787x over previous
//
#include <hip/hip_runtime.h>
#include <math.h>

#define TPB 256

typedef short s16x8 __attribute__((ext_vector_type(8)));
typedef short s16x4 __attribute__((ext_vector_type(4)));
typedef float f32x4 __attribute__((ext_vector_type(4)));

__device__ inline void bsplit(float x, short& h, short& l){
  union { float f; unsigned u; } a, hf, rf;
  a.f = x;
  unsigned hu = (a.u + 0x7FFFu + ((a.u >> 16) & 1u)) >> 16;
  h = (short)hu;
  hf.u = hu << 16;
  rf.f = x - hf.f;
  l = (short)((rf.u + 0x7FFFu + ((rf.u >> 16) & 1u)) >> 16);
}
__device__ inline float b2f(short s){
  union { unsigned u; float f; } x;
  x.u = ((unsigned)(unsigned short)s) << 16;
  return x.f;
}

// ==== weight split + MFMA-native reorder ====
__global__ __launch_bounds__(TPB) void wsplit_k(
    const float* __restrict__ w, short* __restrict__ wh, short* __restrict__ wl,
    int C, int O, int ntap, int total)
{
  int idx = blockIdx.x*TPB + threadIdx.x;
  if (idx >= total) return;
  int c   = idx % C;
  int t2  = idx / C;
  int oc  = t2 % O;
  int tap = t2 / O;
  float x = w[((size_t)oc*C + c)*ntap + tap];
  short h, l; bsplit(x, h, l);
  int tile = oc >> 4, ln = oc & 15;
  int S    = ntap*(C >> 5);
  int sl   = tap*(C >> 5) + (c >> 5);
  int lg   = (c >> 3) & 3, j = c & 7;
  size_t dst = (((size_t)tile*S + sl)*64 + lg*16 + ln)*8 + j;
  wh[dst] = h; wl[dst] = l;
}

__global__ __launch_bounds__(TPB) void wsplit1_k(
    const float* __restrict__ w, short* __restrict__ wh, short* __restrict__ wl)
{
  int idx = blockIdx.x*TPB + threadIdx.x;
  if (idx >= 64*576) return;
  int k  = idx % 576;
  int oc = idx / 576;
  int g  = k >> 4, kw = k & 15;
  int c  = g / 12, kh = g % 12;
  float x = 0.f;
  if (kh < 11 && kw < 11)
    x = w[((size_t)oc*3 + c)*121 + kh*11 + kw];
  short h, l; bsplit(x, h, l);
  int m = oc >> 4, ln = oc & 15;
  int s = k >> 5, r = k & 31;
  int lg = r >> 3, j = r & 7;
  size_t dst = (((size_t)m*18 + s)*64 + lg*16 + ln)*8 + j;
  wh[dst] = h; wl[dst] = l;
}

__global__ __launch_bounds__(TPB) void wtrans_k(
    const float* __restrict__ w, float* __restrict__ wT, int K, int O)
{
  int idx = blockIdx.x*TPB + threadIdx.x;
  if (idx >= K*O) return;
  int oc = idx % O;
  int k  = idx / O;
  wT[idx] = w[(size_t)oc*K + k];
}

// ============== conv1 MFMA (im2col along kw); out: split ch-minor [3025][64] ====
#define C1W 240
#define CV1_PL 33
__global__ __launch_bounds__(256, 4) void conv1m_k(
    const float* __restrict__ in, const short* __restrict__ whi,
    const short* __restrict__ wlo, const float* __restrict__ bias,
    short* __restrict__ yh, short* __restrict__ yl)
{
  __shared__ __align__(16) short lds[2][CV1_PL*C1W + 84];
  const int tid = threadIdx.x;
  const int oh = blockIdx.x % 55;
  const int b  = blockIdx.x / 55;
  const int nt = tid >> 6;
  const int ln = tid & 15;
  const int lg = (tid & 63) >> 4;
  const int lane = tid & 63;
  const int ow = nt*16 + ln;

  const float* ip = in + (size_t)b*3*224*224;
  for (int i = tid; i < CV1_PL*59; i += 256){
    int plane = i / 59;
    int p     = i % 59;
    int c = plane / 11, kh = plane % 11;
    int ih = oh*4 - 2 + kh;
    int col0 = p*4;
    const float* rowp = (ih >= 0 && ih < 224) ? ip + (size_t)c*50176 + (size_t)ih*224 : nullptr;
    short h[4], l[4];
    #pragma unroll
    for (int j=0;j<4;++j){
      int iw = col0 + j - 2;
      float v = (rowp && iw >= 0 && iw < 224) ? rowp[iw] : 0.f;
      bsplit(v, h[j], l[j]);
    }
    s16x4 hv = {h[0],h[1],h[2],h[3]}, lv = {l[0],l[1],l[2],l[3]};
    *reinterpret_cast<s16x4*>(&lds[0][plane*C1W + col0]) = hv;
    *reinterpret_cast<s16x4*>(&lds[1][plane*C1W + col0]) = lv;
  }
  __syncthreads();

  f32x4 acc[4];
  #pragma unroll
  for (int m=0;m<4;++m){
    const float4 bv = *reinterpret_cast<const float4*>(bias + m*16 + lg*4);
    acc[m] = (f32x4){bv.x, bv.y, bv.z, bv.w};
  }

  s16x8 ah[4], al[4], ahn[4], aln[4];
  #pragma unroll
  for (int m=0;m<4;++m){
    size_t ao = (((size_t)m*18 + 0)*64 + lane)*8;
    ah[m] = *reinterpret_cast<const s16x8*>(whi + ao);
    al[m] = *reinterpret_cast<const s16x8*>(wlo + ao);
  }

  #pragma unroll 1
  for (int s=0; s<18; ++s){
    if (s < 17){
      #pragma unroll
      for (int m=0;m<4;++m){
        size_t ao = (((size_t)m*18 + s + 1)*64 + lane)*8;
        ahn[m] = *reinterpret_cast<const s16x8*>(whi + ao);
        aln[m] = *reinterpret_cast<const s16x8*>(wlo + ao);
      }
    }
    int g  = 2*s + (lg >> 1);
    int c  = g / 12, kh = g % 12;
    int plane = c*11 + (kh < 11 ? kh : 10);
    int base  = plane*C1W + ow*4 + (lg & 1)*8;
    s16x4 h0 = *reinterpret_cast<const s16x4*>(&lds[0][base]);
    s16x4 h1 = *reinterpret_cast<const s16x4*>(&lds[0][base+4]);
    s16x4 l0 = *reinterpret_cast<const s16x4*>(&lds[1][base]);
    s16x4 l1 = *reinterpret_cast<const s16x4*>(&lds[1][base+4]);
    s16x8 bh = __builtin_shufflevector(h0, h1, 0,1,2,3,4,5,6,7);
    s16x8 bl = __builtin_shufflevector(l0, l1, 0,1,2,3,4,5,6,7);
    #pragma unroll
    for (int m=0;m<4;++m){
      acc[m] = __builtin_amdgcn_mfma_f32_16x16x32_bf16(al[m], bh, acc[m], 0,0,0);
      acc[m] = __builtin_amdgcn_mfma_f32_16x16x32_bf16(ah[m], bl, acc[m], 0,0,0);
      acc[m] = __builtin_amdgcn_mfma_f32_16x16x32_bf16(ah[m], bh, acc[m], 0,0,0);
    }
    #pragma unroll
    for (int m=0;m<4;++m){ ah[m] = ahn[m]; al[m] = aln[m]; }
  }

  if (ow < 55){
    size_t base = ((size_t)b*3025 + (size_t)oh*55 + ow)*64;
    #pragma unroll
    for (int m=0;m<4;++m){
      short h[4], l[4];
      #pragma unroll
      for (int r=0;r<4;++r) bsplit(fmaxf(acc[m][r], 0.f), h[r], l[r]);
      s16x4 hv = {h[0],h[1],h[2],h[3]}, lv = {l[0],l[1],l[2],l[3]};
      *reinterpret_cast<s16x4*>(yh + base + m*16 + lg*4) = hv;
      *reinterpret_cast<s16x4*>(yl + base + m*16 + lg*4) = lv;
    }
  }
}

// ---- pool1: X1[3025][64] split -> X2[729][64] split ----
__global__ __launch_bounds__(TPB) void pool1_k(
    const short* __restrict__ xh, const short* __restrict__ xl,
    short* __restrict__ yh, short* __restrict__ yl)
{
  int i = blockIdx.x*TPB + threadIdx.x;
  if (i >= 64*729*64) return;
  int c = i & 63;
  int t = i >> 6;
  int sp = t % 729;
  int b = t / 729;
  int r = sp/27, cc = sp%27;
  const short* ph = xh + (size_t)b*3025*64 + c;
  const short* pl = xl + (size_t)b*3025*64 + c;
  float m = -INFINITY;
  #pragma unroll
  for (int di=0;di<3;++di)
    #pragma unroll
    for (int dj=0;dj<3;++dj){
      size_t s = (size_t)((2*r+di)*55 + 2*cc+dj)*64;
      m = fmaxf(m, b2f(ph[s]) + b2f(pl[s]));
    }
  short h, l; bsplit(m, h, l);
  yh[i] = h; yl[i] = l;
}

// ============== conv2 MFMA v3: 32-ch chunks + A-prefetch ==============
// (256,3): VGPR ~100 needed — (256,4) caps at 64 and spills (round-15 lesson).
__global__ __launch_bounds__(256, 3) void conv2m_k(
    const short* __restrict__ xh, const short* __restrict__ xl,
    const short* __restrict__ whi, const short* __restrict__ wlo,
    const float* __restrict__ bias, short* __restrict__ yh, short* __restrict__ yl)
{
  __shared__ __align__(16) short lds[2][217*40];
  const int tid = threadIdx.x;
  const int rg  = blockIdx.x;
  const int b   = blockIdx.y;
  const int wid = tid >> 6;
  const int ln  = tid & 15;
  const int lg  = (tid & 63) >> 4;
  const int lane = tid & 63;
  const int oc0 = wid*48;
  const int r0  = rg*3;

  int sb[6], nn[6];
  #pragma unroll
  for (int t=0;t<6;++t){
    int n = t*16 + ln;
    nn[t] = n;
    int ohl = n / 27, ow = n % 27;
    sb[t] = (n < 81) ? (ohl*31 + ow) : 0;
  }

  f32x4 acc[3][6];
  #pragma unroll
  for (int m=0;m<3;++m){
    const float4 bv = *reinterpret_cast<const float4*>(bias + oc0 + m*16 + lg*4);
    #pragma unroll
    for (int t=0;t<6;++t) acc[m][t] = (f32x4){bv.x, bv.y, bv.z, bv.w};
  }

  #pragma unroll 1
  for (int c0=0; c0<64; c0+=32){
    __syncthreads();
    for (int i = tid; i < 217*4; i += 256){
      int sp = i >> 2, v = i & 3;
      int pr = sp/31, pc = sp%31;
      int ih = r0 - 2 + pr, iw = pc - 2;
      s16x8 hv = {0,0,0,0,0,0,0,0}, lv = {0,0,0,0,0,0,0,0};
      if (ih >= 0 && ih < 27 && iw >= 0 && iw < 27){
        size_t o = ((size_t)b*729 + ih*27 + iw)*64 + c0 + v*8;
        hv = *reinterpret_cast<const s16x8*>(xh + o);
        lv = *reinterpret_cast<const s16x8*>(xl + o);
      }
      *reinterpret_cast<s16x8*>(&lds[0][sp*40 + v*8]) = hv;
      *reinterpret_cast<s16x8*>(&lds[1][sp*40 + v*8]) = lv;
    }
    __syncthreads();

    const size_t tstr = 50*512;
    const size_t abase = ((size_t)(wid*3)*50 + (c0 >> 5))*512 + (size_t)lane*8;
    s16x8 ah0 = *reinterpret_cast<const s16x8*>(whi + abase);
    s16x8 ah1 = *reinterpret_cast<const s16x8*>(whi + abase + tstr);
    s16x8 ah2 = *reinterpret_cast<const s16x8*>(whi + abase + 2*tstr);
    s16x8 al0 = *reinterpret_cast<const s16x8*>(wlo + abase);
    s16x8 al1 = *reinterpret_cast<const s16x8*>(wlo + abase + tstr);
    s16x8 al2 = *reinterpret_cast<const s16x8*>(wlo + abase + 2*tstr);

    #pragma unroll 1
    for (int tap=0; tap<25; ++tap){
      s16x8 nh0=ah0, nh1=ah1, nh2=ah2, nl0=al0, nl1=al1, nl2=al2;
      if (tap < 24){
        size_t ao = abase + (size_t)(tap+1)*2*512;
        nh0 = *reinterpret_cast<const s16x8*>(whi + ao);
        nh1 = *reinterpret_cast<const s16x8*>(whi + ao + tstr);
        nh2 = *reinterpret_cast<const s16x8*>(whi + ao + 2*tstr);
        nl0 = *reinterpret_cast<const s16x8*>(wlo + ao);
        nl1 = *reinterpret_cast<const s16x8*>(wlo + ao + tstr);
        nl2 = *reinterpret_cast<const s16x8*>(wlo + ao + 2*tstr);
      }
      const int toff = (tap/5)*31 + (tap%5);
      #pragma unroll
      for (int t=0;t<6;++t){
        int off = (sb[t] + toff)*40 + lg*8;
        s16x8 bh = *reinterpret_cast<const s16x8*>(&lds[0][off]);
        s16x8 bl = *reinterpret_cast<const s16x8*>(&lds[1][off]);
        acc[0][t] = __builtin_amdgcn_mfma_f32_16x16x32_bf16(al0, bh, acc[0][t], 0,0,0);
        acc[0][t] = __builtin_amdgcn_mfma_f32_16x16x32_bf16(ah0, bl, acc[0][t], 0,0,0);
        acc[0][t] = __builtin_amdgcn_mfma_f32_16x16x32_bf16(ah0, bh, acc[0][t], 0,0,0);
        acc[1][t] = __builtin_amdgcn_mfma_f32_16x16x32_bf16(al1, bh, acc[1][t], 0,0,0);
        acc[1][t] = __builtin_amdgcn_mfma_f32_16x16x32_bf16(ah1, bl, acc[1][t], 0,0,0);
        acc[1][t] = __builtin_amdgcn_mfma_f32_16x16x32_bf16(ah1, bh, acc[1][t], 0,0,0);
        acc[2][t] = __builtin_amdgcn_mfma_f32_16x16x32_bf16(al2, bh, acc[2][t], 0,0,0);
        acc[2][t] = __builtin_amdgcn_mfma_f32_16x16x32_bf16(ah2, bl, acc[2][t], 0,0,0);
        acc[2][t] = __builtin_amdgcn_mfma_f32_16x16x32_bf16(ah2, bh, acc[2][t], 0,0,0);
      }
      ah0=nh0; ah1=nh1; ah2=nh2; al0=nl0; al1=nl1; al2=nl2;
    }
  }

  #pragma unroll
  for (int m=0;m<3;++m)
    #pragma unroll
    for (int t=0;t<6;++t){
      if (nn[t] < 81){
        int gsp = r0*27 + nn[t];
        size_t base = ((size_t)b*729 + gsp)*192 + oc0 + m*16 + lg*4;
        short h[4], l[4];
        #pragma unroll
        for (int r=0;r<4;++r) bsplit(fmaxf(acc[m][t][r], 0.f), h[r], l[r]);
        s16x4 hv = {h[0],h[1],h[2],h[3]}, lv = {l[0],l[1],l[2],l[3]};
        *reinterpret_cast<s16x4*>(yh + base) = hv;
        *reinterpret_cast<s16x4*>(yl + base) = lv;
      }
    }
}

// ---- pool2: X3[729][192] split -> X4[169][192] split ----
__global__ __launch_bounds__(TPB) void pool2_k(
    const short* __restrict__ xh, const short* __restrict__ xl,
    short* __restrict__ yh, short* __restrict__ yl)
{
  int i = blockIdx.x*TPB + threadIdx.x;
  if (i >= 64*169*192) return;
  int c = i % 192;
  int t = i / 192;
  int sp = t % 169;
  int b = t / 169;
  int r = sp/13, cc = sp%13;
  const short* ph = xh + (size_t)b*729*192 + c;
  const short* pl = xl + (size_t)b*729*192 + c;
  float m = -INFINITY;
  #pragma unroll
  for (int di=0;di<3;++di)
    #pragma unroll
    for (int dj=0;dj<3;++dj){
      size_t s = (size_t)((2*r+di)*27 + 2*cc+dj)*192;
      m = fmaxf(m, b2f(ph[s]) + b2f(pl[s]));
    }
  short h, l; bsplit(m, h, l);
  yh[i] = h; yl[i] = l;
}

// ============== conv3/4/5 MFMA; in: split ch-minor [169][C]; out: [169][O] =====
// (256,3): VGPR 68 needed — (256,4) caps at 64 (round-15 lesson).
template<int C,int O>
__global__ __launch_bounds__(256, 3) void conv3m_k(
    const short* __restrict__ xh, const short* __restrict__ xl,
    const short* __restrict__ whi, const short* __restrict__ wlo,
    const float* __restrict__ bias, short* __restrict__ yh, short* __restrict__ yl)
{
  __shared__ __align__(16) short lds[2][225*40];
  const int tid = threadIdx.x;
  const int b   = blockIdx.y;
  const int wid = tid >> 6;
  const int ln  = tid & 15;
  const int lg  = (tid & 63) >> 4;
  const int lane = tid & 63;
  const int tileIdx = blockIdx.x*2 + (wid & 1);
  const int oc0 = tileIdx*16;
  const int ng  = wid >> 1;
  const int tbase  = ng ? 6 : 0;
  const int ntiles = ng ? 5 : 6;
  const int S3 = 9*(C/32);

  int sb[6], nn[6];
  #pragma unroll
  for (int t=0;t<6;++t){
    int n = (tbase + t)*16 + ln;
    nn[t] = n;
    int oh = n / 13, ow = n % 13;
    sb[t] = (n < 169) ? (oh*15 + ow) : 0;
  }

  f32x4 acc[6];
  const float4 bv = *reinterpret_cast<const float4*>(bias + oc0 + lg*4);
  #pragma unroll
  for (int t=0;t<6;++t) acc[t] = (f32x4){bv.x, bv.y, bv.z, bv.w};

  #pragma unroll 1
  for (int c0=0; c0<C; c0+=32){
    __syncthreads();
    for (int i = tid; i < 225*4; i += 256){
      int sp = i >> 2, v = i & 3;
      int r = sp/15, cc = sp%15;
      s16x8 hv = {0,0,0,0,0,0,0,0}, lv = {0,0,0,0,0,0,0,0};
      if (r >= 1 && r <= 13 && cc >= 1 && cc <= 13){
        size_t o = ((size_t)b*169 + (r-1)*13 + (cc-1))*C + c0 + v*8;
        hv = *reinterpret_cast<const s16x8*>(xh + o);
        lv = *reinterpret_cast<const s16x8*>(xl + o);
      }
      *reinterpret_cast<s16x8*>(&lds[0][sp*40 + v*8]) = hv;
      *reinterpret_cast<s16x8*>(&lds[1][sp*40 + v*8]) = lv;
    }
    __syncthreads();

    const size_t tb = (size_t)tileIdx*S3 + (c0 >> 5);
    s16x8 ah = *reinterpret_cast<const s16x8*>(whi + (tb*64 + lane)*8);
    s16x8 al = *reinterpret_cast<const s16x8*>(wlo + (tb*64 + lane)*8);
    #pragma unroll 1
    for (int tap=0; tap<9; ++tap){
      s16x8 ahn = ah, aln = al;
      if (tap < 8){
        size_t ao = ((tb + (size_t)(tap+1)*(C/32))*64 + lane)*8;
        ahn = *reinterpret_cast<const s16x8*>(whi + ao);
        aln = *reinterpret_cast<const s16x8*>(wlo + ao);
      }
      const int toff = (tap/3)*15 + (tap%3);
      #pragma unroll
      for (int t=0;t<6;++t){
        if (t < ntiles){
          int off = (sb[t] + toff)*40 + lg*8;
          s16x8 bh = *reinterpret_cast<const s16x8*>(&lds[0][off]);
          s16x8 bl = *reinterpret_cast<const s16x8*>(&lds[1][off]);
          acc[t] = __builtin_amdgcn_mfma_f32_16x16x32_bf16(al, bh, acc[t], 0,0,0);
          acc[t] = __builtin_amdgcn_mfma_f32_16x16x32_bf16(ah, bl, acc[t], 0,0,0);
          acc[t] = __builtin_amdgcn_mfma_f32_16x16x32_bf16(ah, bh, acc[t], 0,0,0);
        }
      }
      ah = ahn; al = aln;
    }
  }

  #pragma unroll
  for (int t=0;t<6;++t){
    if (t < ntiles && nn[t] < 169){
      size_t base = ((size_t)b*169 + nn[t])*O + oc0 + lg*4;
      short h[4], l[4];
      #pragma unroll
      for (int r=0;r<4;++r) bsplit(fmaxf(acc[t][r], 0.f), h[r], l[r]);
      s16x4 hv = {h[0],h[1],h[2],h[3]}, lv = {l[0],l[1],l[2],l[3]};
      *reinterpret_cast<s16x4*>(yh + base) = hv;
      *reinterpret_cast<s16x4*>(yl + base) = lv;
    }
  }
}

// ---- pool3: X7[169][256] split -> feat[b][9216] f32 (d = c*36 + sp) ----
__global__ __launch_bounds__(TPB) void pool3_k(
    const short* __restrict__ xh, const short* __restrict__ xl,
    float* __restrict__ feat)
{
  int i = blockIdx.x*TPB + threadIdx.x;
  if (i >= 64*9216) return;
  int d = i % 9216;
  int b = i / 9216;
  int c = d / 36;
  int sp = d % 36;
  int r = sp/6, cc = sp%6;
  const short* ph = xh + (size_t)b*169*256 + c;
  const short* pl = xl + (size_t)b*169*256 + c;
  float m = -INFINITY;
  #pragma unroll
  for (int di=0;di<3;++di)
    #pragma unroll
    for (int dj=0;dj<3;++dj){
      size_t s = (size_t)((2*r+di)*13 + 2*cc+dj)*256;
      m = fmaxf(m, b2f(ph[s]) + b2f(pl[s]));
    }
  feat[i] = m;
}

// ---- featsplit: feat[b][9216] -> featBT B-native [288 s][4 nt][64 lane][8 j] ----
__global__ __launch_bounds__(TPB) void featsplit_k(
    const float* __restrict__ feat, short* __restrict__ fbh, short* __restrict__ fbl)
{
  int idx = blockIdx.x*TPB + threadIdx.x;
  if (idx >= 589824) return;
  int j = idx & 7;
  int lane = (idx >> 3) & 63;
  int nt = (idx >> 9) & 3;
  int s = idx >> 11;
  int b = nt*16 + (lane & 15);
  int d = s*32 + (lane >> 4)*8 + j;
  short h, l; bsplit(feat[(size_t)b*9216 + d], h, l);
  fbh[idx] = h; fbl[idx] = l;
}

// ---------------- gate ----------------
__global__ __launch_bounds__(256) void gate1_k(
    const float* __restrict__ feat, const float* __restrict__ gw1T,
    const float* __restrict__ gb1, float* __restrict__ g)
{
  const int b    = blockIdx.x;
  const int h    = blockIdx.y*4 + (threadIdx.x >> 6);
  const int lane = threadIdx.x & 63;
  const float* f = feat + (size_t)b*9216;
  const float* w = gw1T + (size_t)h*9216;
  float s = 0.f;
  #pragma unroll
  for (int it=0; it<36; ++it){
    int d = it*256 + lane*4;
    float4 fv = *reinterpret_cast<const float4*>(f + d);
    float4 wv = *reinterpret_cast<const float4*>(w + d);
    s = fmaf(fv.x, wv.x, s);
    s = fmaf(fv.y, wv.y, s);
    s = fmaf(fv.z, wv.z, s);
    s = fmaf(fv.w, wv.w, s);
  }
  #pragma unroll
  for (int off=32; off; off>>=1) s += __shfl_down(s, off, 64);
  if (lane == 0) g[(size_t)b*72 + h] = fmaxf(s + gb1[h], 0.f);
}

__global__ __launch_bounds__(128) void gate2_k(
    const float* __restrict__ g, const float* __restrict__ gw2,
    const float* __restrict__ gb2, float* __restrict__ gates)
{
  const int b = blockIdx.x;
  const int tid = threadIdx.x;
  __shared__ float gs[72];
  __shared__ float logits[8];
  if (tid < 72) gs[tid] = g[(size_t)b*72 + tid];
  __syncthreads();
  if (tid < 8) {
    float acc = gb2[tid];
    for (int j=0;j<72;++j)
      acc = fmaf(gs[j], gw2[(size_t)j*8 + tid], acc);
    logits[tid] = acc;
  }
  __syncthreads();
  if (tid == 0) {
    int i1 = 0; float v1 = logits[0];
    for (int e=1;e<8;++e) if (logits[e] > v1) { v1 = logits[e]; i1 = e; }
    int i2 = -1; float v2 = -INFINITY;
    for (int e=0;e<8;++e) { if (e==i1) continue; if (logits[e] > v2) { v2 = logits[e]; i2 = e; } }
    float z  = expf(v2 - v1);
    float w1 = 1.f / (1.f + z);
    float w2 = z   / (1.f + z);
    float* gr = gates + (size_t)b*8;
    for (int e=0;e<8;++e) gr[e] = 0.f;
    gr[i1] = w1;
    gr[i2] = w2;
  }
}

// ========== expert h1 MFMA streaming GEMM ==========
__global__ __launch_bounds__(256, 4) void eh1m_k(
    const float* __restrict__ ew1, const short* __restrict__ fbh,
    const short* __restrict__ fbl, float* __restrict__ part)
{
  __shared__ __align__(16) short wh_l[32*88];
  __shared__ __align__(16) short wl_l[32*88];
  const int m2 = blockIdx.x;
  const int e  = blockIdx.y;
  const int ks = blockIdx.z;
  const int tid = threadIdx.x;
  const int nt = tid >> 6;
  const int ln = tid & 15;
  const int lg = (tid & 63) >> 4;
  const int lane = tid & 63;

  f32x4 acc[2] = {(f32x4){0.f,0.f,0.f,0.f},(f32x4){0.f,0.f,0.f,0.f}};

  const float* wsrc = ew1 + (size_t)e*9216*288 + (size_t)m2*32;
  const int d0 = ks*576;

  #pragma unroll 1
  for (int st=0; st<9; ++st){
    __syncthreads();
    {
      int drow = tid >> 2;
      int h0 = (tid & 3)*8;
      const float* src = wsrc + (size_t)(d0 + st*64 + drow)*288 + h0;
      float4 v0 = *reinterpret_cast<const float4*>(src);
      float4 v1 = *reinterpret_cast<const float4*>(src+4);
      float vv[8] = {v0.x,v0.y,v0.z,v0.w,v1.x,v1.y,v1.z,v1.w};
      #pragma unroll
      for (int k=0;k<8;++k){
        short h, l; bsplit(vv[k], h, l);
        wh_l[(h0+k)*88 + drow] = h;
        wl_l[(h0+k)*88 + drow] = l;
      }
    }
    __syncthreads();
    int sg = (d0 + st*64) >> 5;
    #pragma unroll
    for (int sl=0; sl<2; ++sl){
      size_t bo = ((size_t)(sg+sl)*4 + nt)*512 + (size_t)lane*8;
      s16x8 bh = *reinterpret_cast<const s16x8*>(fbh + bo);
      s16x8 bl = *reinterpret_cast<const s16x8*>(fbl + bo);
      #pragma unroll
      for (int m=0;m<2;++m){
        int ao = (m*16 + ln)*88 + sl*32 + lg*8;
        s16x8 ah = *reinterpret_cast<const s16x8*>(&wh_l[ao]);
        s16x8 al = *reinterpret_cast<const s16x8*>(&wl_l[ao]);
        acc[m] = __builtin_amdgcn_mfma_f32_16x16x32_bf16(al, bh, acc[m], 0,0,0);
        acc[m] = __builtin_amdgcn_mfma_f32_16x16x32_bf16(ah, bl, acc[m], 0,0,0);
        acc[m] = __builtin_amdgcn_mfma_f32_16x16x32_bf16(ah, bh, acc[m], 0,0,0);
      }
    }
  }
  #pragma unroll
  for (int m=0;m<2;++m){
    int h = m2*32 + m*16 + lg*4;
    int b = nt*16 + ln;
    float* pp = part + ((size_t)(ks*8+e)*288 + h)*64 + b;
    #pragma unroll
    for (int r=0;r<4;++r)
      pp[(size_t)r*64] = acc[m][r];
  }
}

__global__ __launch_bounds__(TPB) void eh1_reduce_k(
    const float* __restrict__ part, const float* __restrict__ eb1,
    float* __restrict__ h1)
{
  int idx = blockIdx.x*TPB + threadIdx.x;
  if (idx >= 8*288*64) return;
  int b = idx & 63;
  int h = (idx >> 6) % 288;
  int e = idx / (64*288);
  float a = eb1[(size_t)e*288 + h];
  #pragma unroll
  for (int s=0;s<16;++s)
    a += part[((size_t)(s*8+e)*288 + h)*64 + b];
  h1[((size_t)e*64 + b)*288 + h] = fmaxf(a, 0.f);
}

__global__ __launch_bounds__(TPB) void expert_h2_k(
    const float* __restrict__ h1, const float* __restrict__ ew2,
    const float* __restrict__ eb2, const float* __restrict__ gates,
    float* __restrict__ h2)
{
  int idx = blockIdx.x*TPB + threadIdx.x;
  if (idx >= 8*64*144) return;
  int k = idx % 144;
  int t = idx / 144;
  int b = t % 64;
  int e = t / 64;
  if (gates[(size_t)b*8 + e] == 0.f) return;
  float acc = eb2[(size_t)e*144 + k];
  const float* h = h1 + ((size_t)e*64 + b)*288;
  const float* w = ew2 + (size_t)e*288*144 + k;
  for (int d=0; d<288; ++d)
    acc = fmaf(h[d], w[(size_t)d*144], acc);
  h2[idx] = fmaxf(acc, 0.f);
}

__global__ __launch_bounds__(TPB) void expert_out_k(
    const float* __restrict__ h2, const float* __restrict__ ew3,
    const float* __restrict__ eb3, const float* __restrict__ gates,
    float* __restrict__ out)
{
  int idx = blockIdx.x*TPB + threadIdx.x;
  if (idx >= 64*1000) return;
  int o = idx % 1000;
  int b = idx / 1000;
  float acc = 0.f;
  const float* gr = gates + (size_t)b*8;
  for (int e=0;e<8;++e){
    float ge = gr[e];
    if (ge == 0.f) continue;
    float a = eb3[(size_t)e*1000 + o];
    const float* h = h2 + ((size_t)e*64 + b)*144;
    const float* w = ew3 + (size_t)e*144*1000 + o;
    for (int k=0;k<144;++k)
      a = fmaf(h[k], w[(size_t)k*1000], a);
    acc = fmaf(ge, a, acc);
  }
  out[idx] = acc;
}

static inline int nblk(long long n){ return (int)((n + TPB - 1) / TPB); }

extern "C" void kernel_launch(void* const* d_in, const int* in_sizes, int n_in,
                              void* d_out, int out_size, void* d_ws, size_t ws_size,
                              hipStream_t stream)
{
  const float* x   = (const float*)d_in[0];
  const float* c1w = (const float*)d_in[1];  const float* c1b = (const float*)d_in[2];
  const float* c2w = (const float*)d_in[3];  const float* c2b = (const float*)d_in[4];
  const float* c3w = (const float*)d_in[5];  const float* c3b = (const float*)d_in[6];
  const float* c4w = (const float*)d_in[7];  const float* c4b = (const float*)d_in[8];
  const float* c5w = (const float*)d_in[9];  const float* c5b = (const float*)d_in[10];
  const float* gw1 = (const float*)d_in[11]; const float* gb1 = (const float*)d_in[12];
  const float* gw2 = (const float*)d_in[13]; const float* gb2 = (const float*)d_in[14];
  const float* ew1 = (const float*)d_in[15]; const float* eb1 = (const float*)d_in[16];
  const float* ew2 = (const float*)d_in[17]; const float* eb2 = (const float*)d_in[18];
  const float* ew3 = (const float*)d_in[19]; const float* eb3 = (const float*)d_in[20];
  float* out = (float*)d_out;

  float* W = (float*)d_ws;
  short* X1H = (short*)W;
  short* X1L = X1H + 12390400;
  short* X3H = (short*)W;
  short* X3L = X3H + 8957952;
  short* X5H = (short*)W;
  short* X5L = X5H + 4153344;
  short* X7H = (short*)W;
  short* X7L = X7H + 2768896;
  float* feat  = W + 5000000;
  short* FBH   = (short*)(W + 5600000);
  short* FBL   = (short*)(W + 5900000);
  float* part  = W + 6300000;
  short* WH2 = (short*)(W +  9000000);
  short* WL2 = WH2 + 307200;
  short* WH3 = (short*)(W +  9320000);
  short* WL3 = WH3 + 663552;
  short* WH4 = (short*)(W + 10000000);
  short* WL4 = WH4 + 884736;
  short* WH5 = (short*)(W + 10900000);
  short* WL5 = WH5 + 589824;
  float* GT1 = W + 11500000;
  short* X2H = (short*)(W + 12390400);
  short* X2L = X2H + 2985984;
  short* X4H = (short*)(W + 12390400);
  short* X4L = X4H + 2076672;
  short* X6H = (short*)(W + 12390400);
  short* X6L = X6H + 2768896;
  float* gates = W + 14000000;
  float* h1    = gates + 512;
  float* h2    = h1 + 147456;
  float* gbuf  = h2 + 73728;
  short* WH1 = (short*)(W + 15400000);
  short* WL1 = WH1 + 36864;
  (void)ws_size; (void)in_sizes; (void)n_in; (void)out_size;

  wsplit1_k<<<nblk(64LL*576), TPB, 0, stream>>>(c1w, WH1, WL1);
  conv1m_k<<<55*64, 256, 0, stream>>>(x, WH1, WL1, c1b, X1H, X1L);
  pool1_k<<<nblk(64LL*729*64), TPB, 0, stream>>>(X1H, X1L, X2H, X2L);
  wsplit_k<<<nblk(25LL*192*64),  TPB, 0, stream>>>(c2w, WH2, WL2,  64, 192, 25, 25*192*64);
  wsplit_k<<<nblk(9LL*384*192),  TPB, 0, stream>>>(c3w, WH3, WL3, 192, 384,  9, 9*384*192);
  wsplit_k<<<nblk(9LL*256*384),  TPB, 0, stream>>>(c4w, WH4, WL4, 384, 256,  9, 9*256*384);
  wsplit_k<<<nblk(9LL*256*256),  TPB, 0, stream>>>(c5w, WH5, WL5, 256, 256,  9, 9*256*256);
  wtrans_k<<<nblk(72LL*9216),    TPB, 0, stream>>>(gw1, GT1, 72, 9216);

  conv2m_k<<<dim3(9,64), 256, 0, stream>>>(X2H, X2L, WH2, WL2, c2b, X3H, X3L);
  pool2_k<<<nblk(64LL*169*192), TPB, 0, stream>>>(X3H, X3L, X4H, X4L);
  conv3m_k<192,384><<<dim3(12,64), 256, 0, stream>>>(X4H, X4L, WH3, WL3, c3b, X5H, X5L);
  conv3m_k<384,256><<<dim3(8,64),  256, 0, stream>>>(X5H, X5L, WH4, WL4, c4b, X6H, X6L);
  conv3m_k<256,256><<<dim3(8,64),  256, 0, stream>>>(X6H, X6L, WH5, WL5, c5b, X7H, X7L);
  pool3_k<<<nblk(64LL*9216), TPB, 0, stream>>>(X7H, X7L, feat);

  gate1_k<<<dim3(64,18), 256, 0, stream>>>(feat, GT1, gb1, gbuf);
  gate2_k<<<64, 128, 0, stream>>>(gbuf, gw2, gb2, gates);

  featsplit_k<<<nblk(589824LL), TPB, 0, stream>>>(feat, FBH, FBL);
  eh1m_k<<<dim3(9,8,16), 256, 0, stream>>>(ew1, FBH, FBL, part);
  eh1_reduce_k<<<nblk(8LL*288*64), TPB, 0, stream>>>(part, eb1, h1);
  expert_h2_k<<<nblk(8LL*64*144), TPB, 0, stream>>>(h1, ew2, eb2, gates, h2);
  expert_out_k<<<nblk(64LL*1000), TPB, 0, stream>>>(h2, ew3, eb3, gates, out);
}

// Round 17
// 513.047 us; speedup vs baseline: 2.1230x; 1.0413x over previous
//
#include <hip/hip_runtime.h>
#include <math.h>

#define TPB 256

typedef short s16x8 __attribute__((ext_vector_type(8)));
typedef short s16x4 __attribute__((ext_vector_type(4)));
typedef float f32x4 __attribute__((ext_vector_type(4)));

__device__ inline void bsplit(float x, short& h, short& l){
  union { float f; unsigned u; } a, hf, rf;
  a.f = x;
  unsigned hu = (a.u + 0x7FFFu + ((a.u >> 16) & 1u)) >> 16;
  h = (short)hu;
  hf.u = hu << 16;
  rf.f = x - hf.f;
  l = (short)((rf.u + 0x7FFFu + ((rf.u >> 16) & 1u)) >> 16);
}
__device__ inline float b2f(short s){
  union { unsigned u; float f; } x;
  x.u = ((unsigned)(unsigned short)s) << 16;
  return x.f;
}

// ==== weight split + MFMA-native reorder ====
__global__ __launch_bounds__(TPB) void wsplit_k(
    const float* __restrict__ w, short* __restrict__ wh, short* __restrict__ wl,
    int C, int O, int ntap, int total)
{
  int idx = blockIdx.x*TPB + threadIdx.x;
  if (idx >= total) return;
  int c   = idx % C;
  int t2  = idx / C;
  int oc  = t2 % O;
  int tap = t2 / O;
  float x = w[((size_t)oc*C + c)*ntap + tap];
  short h, l; bsplit(x, h, l);
  int tile = oc >> 4, ln = oc & 15;
  int S    = ntap*(C >> 5);
  int sl   = tap*(C >> 5) + (c >> 5);
  int lg   = (c >> 3) & 3, j = c & 7;
  size_t dst = (((size_t)tile*S + sl)*64 + lg*16 + ln)*8 + j;
  wh[dst] = h; wl[dst] = l;
}

__global__ __launch_bounds__(TPB) void wsplit1_k(
    const float* __restrict__ w, short* __restrict__ wh, short* __restrict__ wl)
{
  int idx = blockIdx.x*TPB + threadIdx.x;
  if (idx >= 64*576) return;
  int k  = idx % 576;
  int oc = idx / 576;
  int g  = k >> 4, kw = k & 15;
  int c  = g / 12, kh = g % 12;
  float x = 0.f;
  if (kh < 11 && kw < 11)
    x = w[((size_t)oc*3 + c)*121 + kh*11 + kw];
  short h, l; bsplit(x, h, l);
  int m = oc >> 4, ln = oc & 15;
  int s = k >> 5, r = k & 31;
  int lg = r >> 3, j = r & 7;
  size_t dst = (((size_t)m*18 + s)*64 + lg*16 + ln)*8 + j;
  wh[dst] = h; wl[dst] = l;
}

__global__ __launch_bounds__(TPB) void wtrans_k(
    const float* __restrict__ w, float* __restrict__ wT, int K, int O)
{
  int idx = blockIdx.x*TPB + threadIdx.x;
  if (idx >= K*O) return;
  int oc = idx % O;
  int k  = idx / O;
  wT[idx] = w[(size_t)oc*K + k];
}

// ========= conv1+pool1 fused MFMA =========
// block = (pool row r 0..26, image b). Computes conv rows 2r..2r+2 (share a
// 19-row input window and the SAME A-frags), pools 3x3s2 in-LDS, writes only
// X2[729][64] split (6 MB total vs 49.6 MB X1 + pool traffic).
// LDS: input 57 planes (3c x 19 ri) x 240 cols hi/lo = 55 KB; conv buffer
// (3 rows x 64 oc x stride 57 fp32 = 43.8 KB) reuses it after MFMA.
#define C1W 240
__global__ __launch_bounds__(256, 2) void conv1p_k(
    const float* __restrict__ in, const short* __restrict__ whi,
    const short* __restrict__ wlo, const float* __restrict__ bias,
    short* __restrict__ yh, short* __restrict__ yl)
{
  __shared__ __align__(16) short lds[2][57*C1W + 84];
  const int tid = threadIdx.x;
  const int r  = blockIdx.x;            // pool row 0..26
  const int b  = blockIdx.y;
  const int nt = tid >> 6;
  const int ln = tid & 15;
  const int lg = (tid & 63) >> 4;
  const int lane = tid & 63;
  const int ow = nt*16 + ln;            // valid < 55

  // ---- phase 1: stage 19 input rows x 3 ch (bsplit, zero-guarded) ----
  const float* ip = in + (size_t)b*3*224*224;
  for (int i = tid; i < 57*59; i += 256){
    int plane = i / 59;
    int p     = i % 59;
    int c = plane / 19, ri = plane % 19;
    int ih = 8*r - 2 + ri;
    int col0 = p*4;
    const float* rowp = (ih >= 0 && ih < 224) ? ip + (size_t)c*50176 + (size_t)ih*224 : nullptr;
    short h[4], l[4];
    #pragma unroll
    for (int j=0;j<4;++j){
      int iw = col0 + j - 2;
      float v = (rowp && iw >= 0 && iw < 224) ? rowp[iw] : 0.f;
      bsplit(v, h[j], l[j]);
    }
    s16x4 hv = {h[0],h[1],h[2],h[3]}, lv = {l[0],l[1],l[2],l[3]};
    *reinterpret_cast<s16x4*>(&lds[0][plane*C1W + col0]) = hv;
    *reinterpret_cast<s16x4*>(&lds[1][plane*C1W + col0]) = lv;
  }
  __syncthreads();

  // ---- phase 2: MFMA, 3 conv rows sharing A-frags ----
  f32x4 acc[3][4];
  #pragma unroll
  for (int m=0;m<4;++m){
    const float4 bv = *reinterpret_cast<const float4*>(bias + m*16 + lg*4);
    #pragma unroll
    for (int sub=0;sub<3;++sub)
      acc[sub][m] = (f32x4){bv.x, bv.y, bv.z, bv.w};
  }

  s16x8 ah[4], al[4], ahn[4], aln[4];
  #pragma unroll
  for (int m=0;m<4;++m){
    size_t ao = (((size_t)m*18 + 0)*64 + lane)*8;
    ah[m] = *reinterpret_cast<const s16x8*>(whi + ao);
    al[m] = *reinterpret_cast<const s16x8*>(wlo + ao);
  }

  #pragma unroll 1
  for (int s=0; s<18; ++s){
    if (s < 17){
      #pragma unroll
      for (int m=0;m<4;++m){
        size_t ao = (((size_t)m*18 + s + 1)*64 + lane)*8;
        ahn[m] = *reinterpret_cast<const s16x8*>(whi + ao);
        aln[m] = *reinterpret_cast<const s16x8*>(wlo + ao);
      }
    }
    int g  = 2*s + (lg >> 1);
    int c  = g / 12, kh = g % 12;
    int khp = (kh < 11) ? kh : 10;       // kh=11: zero weights, alias row
    #pragma unroll
    for (int sub=0;sub<3;++sub){
      int plane = c*19 + 4*sub + khp;
      int base  = plane*C1W + ow*4 + (lg & 1)*8;
      s16x4 h0 = *reinterpret_cast<const s16x4*>(&lds[0][base]);
      s16x4 h1 = *reinterpret_cast<const s16x4*>(&lds[0][base+4]);
      s16x4 l0 = *reinterpret_cast<const s16x4*>(&lds[1][base]);
      s16x4 l1 = *reinterpret_cast<const s16x4*>(&lds[1][base+4]);
      s16x8 bh = __builtin_shufflevector(h0, h1, 0,1,2,3,4,5,6,7);
      s16x8 bl = __builtin_shufflevector(l0, l1, 0,1,2,3,4,5,6,7);
      #pragma unroll
      for (int m=0;m<4;++m){
        acc[sub][m] = __builtin_amdgcn_mfma_f32_16x16x32_bf16(al[m], bh, acc[sub][m], 0,0,0);
        acc[sub][m] = __builtin_amdgcn_mfma_f32_16x16x32_bf16(ah[m], bl, acc[sub][m], 0,0,0);
        acc[sub][m] = __builtin_amdgcn_mfma_f32_16x16x32_bf16(ah[m], bh, acc[sub][m], 0,0,0);
      }
    }
    #pragma unroll
    for (int m=0;m<4;++m){ ah[m] = ahn[m]; al[m] = aln[m]; }
  }

  // ---- phase 3: relu'd conv rows -> LDS fp32 buffer (reuse input LDS) ----
  __syncthreads();
  float* convbuf = (float*)&lds[0][0];   // [3][64][57] = 43,776 B
  if (ow < 55){
    #pragma unroll
    for (int sub=0;sub<3;++sub)
      #pragma unroll
      for (int m=0;m<4;++m)
        #pragma unroll
        for (int rr=0;rr<4;++rr){
          int oc = m*16 + lg*4 + rr;
          convbuf[(sub*64 + oc)*57 + ow] = fmaxf(acc[sub][m][rr], 0.f);
        }
  }
  __syncthreads();

  // ---- phase 4: 3x3s2 maxpool -> X2 split [b][r*27+pw][c] ----
  for (int i = tid; i < 27*64; i += 256){
    int pw = i >> 6, c = i & 63;
    float m = -INFINITY;
    #pragma unroll
    for (int sub=0;sub<3;++sub)
      #pragma unroll
      for (int j=0;j<3;++j)
        m = fmaxf(m, convbuf[(sub*64 + c)*57 + 2*pw + j]);
    short h, l; bsplit(m, h, l);
    size_t o = ((size_t)b*729 + r*27 + pw)*64 + c;
    yh[o] = h; yl[o] = l;
  }
}

// ============== conv2 MFMA v3: 32-ch chunks + A-prefetch ==============
__global__ __launch_bounds__(256, 3) void conv2m_k(
    const short* __restrict__ xh, const short* __restrict__ xl,
    const short* __restrict__ whi, const short* __restrict__ wlo,
    const float* __restrict__ bias, short* __restrict__ yh, short* __restrict__ yl)
{
  __shared__ __align__(16) short lds[2][217*40];
  const int tid = threadIdx.x;
  const int rg  = blockIdx.x;
  const int b   = blockIdx.y;
  const int wid = tid >> 6;
  const int ln  = tid & 15;
  const int lg  = (tid & 63) >> 4;
  const int lane = tid & 63;
  const int oc0 = wid*48;
  const int r0  = rg*3;

  int sb[6], nn[6];
  #pragma unroll
  for (int t=0;t<6;++t){
    int n = t*16 + ln;
    nn[t] = n;
    int ohl = n / 27, ow = n % 27;
    sb[t] = (n < 81) ? (ohl*31 + ow) : 0;
  }

  f32x4 acc[3][6];
  #pragma unroll
  for (int m=0;m<3;++m){
    const float4 bv = *reinterpret_cast<const float4*>(bias + oc0 + m*16 + lg*4);
    #pragma unroll
    for (int t=0;t<6;++t) acc[m][t] = (f32x4){bv.x, bv.y, bv.z, bv.w};
  }

  #pragma unroll 1
  for (int c0=0; c0<64; c0+=32){
    __syncthreads();
    for (int i = tid; i < 217*4; i += 256){
      int sp = i >> 2, v = i & 3;
      int pr = sp/31, pc = sp%31;
      int ih = r0 - 2 + pr, iw = pc - 2;
      s16x8 hv = {0,0,0,0,0,0,0,0}, lv = {0,0,0,0,0,0,0,0};
      if (ih >= 0 && ih < 27 && iw >= 0 && iw < 27){
        size_t o = ((size_t)b*729 + ih*27 + iw)*64 + c0 + v*8;
        hv = *reinterpret_cast<const s16x8*>(xh + o);
        lv = *reinterpret_cast<const s16x8*>(xl + o);
      }
      *reinterpret_cast<s16x8*>(&lds[0][sp*40 + v*8]) = hv;
      *reinterpret_cast<s16x8*>(&lds[1][sp*40 + v*8]) = lv;
    }
    __syncthreads();

    const size_t tstr = 50*512;
    const size_t abase = ((size_t)(wid*3)*50 + (c0 >> 5))*512 + (size_t)lane*8;
    s16x8 ah0 = *reinterpret_cast<const s16x8*>(whi + abase);
    s16x8 ah1 = *reinterpret_cast<const s16x8*>(whi + abase + tstr);
    s16x8 ah2 = *reinterpret_cast<const s16x8*>(whi + abase + 2*tstr);
    s16x8 al0 = *reinterpret_cast<const s16x8*>(wlo + abase);
    s16x8 al1 = *reinterpret_cast<const s16x8*>(wlo + abase + tstr);
    s16x8 al2 = *reinterpret_cast<const s16x8*>(wlo + abase + 2*tstr);

    #pragma unroll 1
    for (int tap=0; tap<25; ++tap){
      s16x8 nh0=ah0, nh1=ah1, nh2=ah2, nl0=al0, nl1=al1, nl2=al2;
      if (tap < 24){
        size_t ao = abase + (size_t)(tap+1)*2*512;
        nh0 = *reinterpret_cast<const s16x8*>(whi + ao);
        nh1 = *reinterpret_cast<const s16x8*>(whi + ao + tstr);
        nh2 = *reinterpret_cast<const s16x8*>(whi + ao + 2*tstr);
        nl0 = *reinterpret_cast<const s16x8*>(wlo + ao);
        nl1 = *reinterpret_cast<const s16x8*>(wlo + ao + tstr);
        nl2 = *reinterpret_cast<const s16x8*>(wlo + ao + 2*tstr);
      }
      const int toff = (tap/5)*31 + (tap%5);
      #pragma unroll
      for (int t=0;t<6;++t){
        int off = (sb[t] + toff)*40 + lg*8;
        s16x8 bh = *reinterpret_cast<const s16x8*>(&lds[0][off]);
        s16x8 bl = *reinterpret_cast<const s16x8*>(&lds[1][off]);
        acc[0][t] = __builtin_amdgcn_mfma_f32_16x16x32_bf16(al0, bh, acc[0][t], 0,0,0);
        acc[0][t] = __builtin_amdgcn_mfma_f32_16x16x32_bf16(ah0, bl, acc[0][t], 0,0,0);
        acc[0][t] = __builtin_amdgcn_mfma_f32_16x16x32_bf16(ah0, bh, acc[0][t], 0,0,0);
        acc[1][t] = __builtin_amdgcn_mfma_f32_16x16x32_bf16(al1, bh, acc[1][t], 0,0,0);
        acc[1][t] = __builtin_amdgcn_mfma_f32_16x16x32_bf16(ah1, bl, acc[1][t], 0,0,0);
        acc[1][t] = __builtin_amdgcn_mfma_f32_16x16x32_bf16(ah1, bh, acc[1][t], 0,0,0);
        acc[2][t] = __builtin_amdgcn_mfma_f32_16x16x32_bf16(al2, bh, acc[2][t], 0,0,0);
        acc[2][t] = __builtin_amdgcn_mfma_f32_16x16x32_bf16(ah2, bl, acc[2][t], 0,0,0);
        acc[2][t] = __builtin_amdgcn_mfma_f32_16x16x32_bf16(ah2, bh, acc[2][t], 0,0,0);
      }
      ah0=nh0; ah1=nh1; ah2=nh2; al0=nl0; al1=nl1; al2=nl2;
    }
  }

  #pragma unroll
  for (int m=0;m<3;++m)
    #pragma unroll
    for (int t=0;t<6;++t){
      if (nn[t] < 81){
        int gsp = r0*27 + nn[t];
        size_t base = ((size_t)b*729 + gsp)*192 + oc0 + m*16 + lg*4;
        short h[4], l[4];
        #pragma unroll
        for (int r=0;r<4;++r) bsplit(fmaxf(acc[m][t][r], 0.f), h[r], l[r]);
        s16x4 hv = {h[0],h[1],h[2],h[3]}, lv = {l[0],l[1],l[2],l[3]};
        *reinterpret_cast<s16x4*>(yh + base) = hv;
        *reinterpret_cast<s16x4*>(yl + base) = lv;
      }
    }
}

// ---- pool2: X3[729][192] split -> X4[169][192] split ----
__global__ __launch_bounds__(TPB) void pool2_k(
    const short* __restrict__ xh, const short* __restrict__ xl,
    short* __restrict__ yh, short* __restrict__ yl)
{
  int i = blockIdx.x*TPB + threadIdx.x;
  if (i >= 64*169*192) return;
  int c = i % 192;
  int t = i / 192;
  int sp = t % 169;
  int b = t / 169;
  int r = sp/13, cc = sp%13;
  const short* ph = xh + (size_t)b*729*192 + c;
  const short* pl = xl + (size_t)b*729*192 + c;
  float m = -INFINITY;
  #pragma unroll
  for (int di=0;di<3;++di)
    #pragma unroll
    for (int dj=0;dj<3;++dj){
      size_t s = (size_t)((2*r+di)*27 + 2*cc+dj)*192;
      m = fmaxf(m, b2f(ph[s]) + b2f(pl[s]));
    }
  short h, l; bsplit(m, h, l);
  yh[i] = h; yl[i] = l;
}

// ============== conv3/4/5 MFMA; in: split ch-minor [169][C]; out: [169][O] =====
template<int C,int O>
__global__ __launch_bounds__(256, 3) void conv3m_k(
    const short* __restrict__ xh, const short* __restrict__ xl,
    const short* __restrict__ whi, const short* __restrict__ wlo,
    const float* __restrict__ bias, short* __restrict__ yh, short* __restrict__ yl)
{
  __shared__ __align__(16) short lds[2][225*40];
  const int tid = threadIdx.x;
  const int b   = blockIdx.y;
  const int wid = tid >> 6;
  const int ln  = tid & 15;
  const int lg  = (tid & 63) >> 4;
  const int lane = tid & 63;
  const int tileIdx = blockIdx.x*2 + (wid & 1);
  const int oc0 = tileIdx*16;
  const int ng  = wid >> 1;
  const int tbase  = ng ? 6 : 0;
  const int ntiles = ng ? 5 : 6;
  const int S3 = 9*(C/32);

  int sb[6], nn[6];
  #pragma unroll
  for (int t=0;t<6;++t){
    int n = (tbase + t)*16 + ln;
    nn[t] = n;
    int oh = n / 13, ow = n % 13;
    sb[t] = (n < 169) ? (oh*15 + ow) : 0;
  }

  f32x4 acc[6];
  const float4 bv = *reinterpret_cast<const float4*>(bias + oc0 + lg*4);
  #pragma unroll
  for (int t=0;t<6;++t) acc[t] = (f32x4){bv.x, bv.y, bv.z, bv.w};

  #pragma unroll 1
  for (int c0=0; c0<C; c0+=32){
    __syncthreads();
    for (int i = tid; i < 225*4; i += 256){
      int sp = i >> 2, v = i & 3;
      int r = sp/15, cc = sp%15;
      s16x8 hv = {0,0,0,0,0,0,0,0}, lv = {0,0,0,0,0,0,0,0};
      if (r >= 1 && r <= 13 && cc >= 1 && cc <= 13){
        size_t o = ((size_t)b*169 + (r-1)*13 + (cc-1))*C + c0 + v*8;
        hv = *reinterpret_cast<const s16x8*>(xh + o);
        lv = *reinterpret_cast<const s16x8*>(xl + o);
      }
      *reinterpret_cast<s16x8*>(&lds[0][sp*40 + v*8]) = hv;
      *reinterpret_cast<s16x8*>(&lds[1][sp*40 + v*8]) = lv;
    }
    __syncthreads();

    const size_t tb = (size_t)tileIdx*S3 + (c0 >> 5);
    s16x8 ah = *reinterpret_cast<const s16x8*>(whi + (tb*64 + lane)*8);
    s16x8 al = *reinterpret_cast<const s16x8*>(wlo + (tb*64 + lane)*8);
    #pragma unroll 1
    for (int tap=0; tap<9; ++tap){
      s16x8 ahn = ah, aln = al;
      if (tap < 8){
        size_t ao = ((tb + (size_t)(tap+1)*(C/32))*64 + lane)*8;
        ahn = *reinterpret_cast<const s16x8*>(whi + ao);
        aln = *reinterpret_cast<const s16x8*>(wlo + ao);
      }
      const int toff = (tap/3)*15 + (tap%3);
      #pragma unroll
      for (int t=0;t<6;++t){
        if (t < ntiles){
          int off = (sb[t] + toff)*40 + lg*8;
          s16x8 bh = *reinterpret_cast<const s16x8*>(&lds[0][off]);
          s16x8 bl = *reinterpret_cast<const s16x8*>(&lds[1][off]);
          acc[t] = __builtin_amdgcn_mfma_f32_16x16x32_bf16(al, bh, acc[t], 0,0,0);
          acc[t] = __builtin_amdgcn_mfma_f32_16x16x32_bf16(ah, bl, acc[t], 0,0,0);
          acc[t] = __builtin_amdgcn_mfma_f32_16x16x32_bf16(ah, bh, acc[t], 0,0,0);
        }
      }
      ah = ahn; al = aln;
    }
  }

  #pragma unroll
  for (int t=0;t<6;++t){
    if (t < ntiles && nn[t] < 169){
      size_t base = ((size_t)b*169 + nn[t])*O + oc0 + lg*4;
      short h[4], l[4];
      #pragma unroll
      for (int r=0;r<4;++r) bsplit(fmaxf(acc[t][r], 0.f), h[r], l[r]);
      s16x4 hv = {h[0],h[1],h[2],h[3]}, lv = {l[0],l[1],l[2],l[3]};
      *reinterpret_cast<s16x4*>(yh + base) = hv;
      *reinterpret_cast<s16x4*>(yl + base) = lv;
    }
  }
}

// ---- pool3: X7[169][256] split -> feat[b][9216] f32 (d = c*36 + sp) ----
__global__ __launch_bounds__(TPB) void pool3_k(
    const short* __restrict__ xh, const short* __restrict__ xl,
    float* __restrict__ feat)
{
  int i = blockIdx.x*TPB + threadIdx.x;
  if (i >= 64*9216) return;
  int d = i % 9216;
  int b = i / 9216;
  int c = d / 36;
  int sp = d % 36;
  int r = sp/6, cc = sp%6;
  const short* ph = xh + (size_t)b*169*256 + c;
  const short* pl = xl + (size_t)b*169*256 + c;
  float m = -INFINITY;
  #pragma unroll
  for (int di=0;di<3;++di)
    #pragma unroll
    for (int dj=0;dj<3;++dj){
      size_t s = (size_t)((2*r+di)*13 + 2*cc+dj)*256;
      m = fmaxf(m, b2f(ph[s]) + b2f(pl[s]));
    }
  feat[i] = m;
}

// ---- featsplit: feat[b][9216] -> featBT B-native [288 s][4 nt][64 lane][8 j] ----
__global__ __launch_bounds__(TPB) void featsplit_k(
    const float* __restrict__ feat, short* __restrict__ fbh, short* __restrict__ fbl)
{
  int idx = blockIdx.x*TPB + threadIdx.x;
  if (idx >= 589824) return;
  int j = idx & 7;
  int lane = (idx >> 3) & 63;
  int nt = (idx >> 9) & 3;
  int s = idx >> 11;
  int b = nt*16 + (lane & 15);
  int d = s*32 + (lane >> 4)*8 + j;
  short h, l; bsplit(feat[(size_t)b*9216 + d], h, l);
  fbh[idx] = h; fbl[idx] = l;
}

// ---------------- gate ----------------
__global__ __launch_bounds__(256) void gate1_k(
    const float* __restrict__ feat, const float* __restrict__ gw1T,
    const float* __restrict__ gb1, float* __restrict__ g)
{
  const int b    = blockIdx.x;
  const int h    = blockIdx.y*4 + (threadIdx.x >> 6);
  const int lane = threadIdx.x & 63;
  const float* f = feat + (size_t)b*9216;
  const float* w = gw1T + (size_t)h*9216;
  float s = 0.f;
  #pragma unroll
  for (int it=0; it<36; ++it){
    int d = it*256 + lane*4;
    float4 fv = *reinterpret_cast<const float4*>(f + d);
    float4 wv = *reinterpret_cast<const float4*>(w + d);
    s = fmaf(fv.x, wv.x, s);
    s = fmaf(fv.y, wv.y, s);
    s = fmaf(fv.z, wv.z, s);
    s = fmaf(fv.w, wv.w, s);
  }
  #pragma unroll
  for (int off=32; off; off>>=1) s += __shfl_down(s, off, 64);
  if (lane == 0) g[(size_t)b*72 + h] = fmaxf(s + gb1[h], 0.f);
}

__global__ __launch_bounds__(128) void gate2_k(
    const float* __restrict__ g, const float* __restrict__ gw2,
    const float* __restrict__ gb2, float* __restrict__ gates)
{
  const int b = blockIdx.x;
  const int tid = threadIdx.x;
  __shared__ float gs[72];
  __shared__ float logits[8];
  if (tid < 72) gs[tid] = g[(size_t)b*72 + tid];
  __syncthreads();
  if (tid < 8) {
    float acc = gb2[tid];
    for (int j=0;j<72;++j)
      acc = fmaf(gs[j], gw2[(size_t)j*8 + tid], acc);
    logits[tid] = acc;
  }
  __syncthreads();
  if (tid == 0) {
    int i1 = 0; float v1 = logits[0];
    for (int e=1;e<8;++e) if (logits[e] > v1) { v1 = logits[e]; i1 = e; }
    int i2 = -1; float v2 = -INFINITY;
    for (int e=0;e<8;++e) { if (e==i1) continue; if (logits[e] > v2) { v2 = logits[e]; i2 = e; } }
    float z  = expf(v2 - v1);
    float w1 = 1.f / (1.f + z);
    float w2 = z   / (1.f + z);
    float* gr = gates + (size_t)b*8;
    for (int e=0;e<8;++e) gr[e] = 0.f;
    gr[i1] = w1;
    gr[i2] = w2;
  }
}

// ========== expert h1 MFMA streaming GEMM ==========
__global__ __launch_bounds__(256, 4) void eh1m_k(
    const float* __restrict__ ew1, const short* __restrict__ fbh,
    const short* __restrict__ fbl, float* __restrict__ part)
{
  __shared__ __align__(16) short wh_l[32*88];
  __shared__ __align__(16) short wl_l[32*88];
  const int m2 = blockIdx.x;
  const int e  = blockIdx.y;
  const int ks = blockIdx.z;
  const int tid = threadIdx.x;
  const int nt = tid >> 6;
  const int ln = tid & 15;
  const int lg = (tid & 63) >> 4;
  const int lane = tid & 63;

  f32x4 acc[2] = {(f32x4){0.f,0.f,0.f,0.f},(f32x4){0.f,0.f,0.f,0.f}};

  const float* wsrc = ew1 + (size_t)e*9216*288 + (size_t)m2*32;
  const int d0 = ks*576;

  #pragma unroll 1
  for (int st=0; st<9; ++st){
    __syncthreads();
    {
      int drow = tid >> 2;
      int h0 = (tid & 3)*8;
      const float* src = wsrc + (size_t)(d0 + st*64 + drow)*288 + h0;
      float4 v0 = *reinterpret_cast<const float4*>(src);
      float4 v1 = *reinterpret_cast<const float4*>(src+4);
      float vv[8] = {v0.x,v0.y,v0.z,v0.w,v1.x,v1.y,v1.z,v1.w};
      #pragma unroll
      for (int k=0;k<8;++k){
        short h, l; bsplit(vv[k], h, l);
        wh_l[(h0+k)*88 + drow] = h;
        wl_l[(h0+k)*88 + drow] = l;
      }
    }
    __syncthreads();
    int sg = (d0 + st*64) >> 5;
    #pragma unroll
    for (int sl=0; sl<2; ++sl){
      size_t bo = ((size_t)(sg+sl)*4 + nt)*512 + (size_t)lane*8;
      s16x8 bh = *reinterpret_cast<const s16x8*>(fbh + bo);
      s16x8 bl = *reinterpret_cast<const s16x8*>(fbl + bo);
      #pragma unroll
      for (int m=0;m<2;++m){
        int ao = (m*16 + ln)*88 + sl*32 + lg*8;
        s16x8 ah = *reinterpret_cast<const s16x8*>(&wh_l[ao]);
        s16x8 al = *reinterpret_cast<const s16x8*>(&wl_l[ao]);
        acc[m] = __builtin_amdgcn_mfma_f32_16x16x32_bf16(al, bh, acc[m], 0,0,0);
        acc[m] = __builtin_amdgcn_mfma_f32_16x16x32_bf16(ah, bl, acc[m], 0,0,0);
        acc[m] = __builtin_amdgcn_mfma_f32_16x16x32_bf16(ah, bh, acc[m], 0,0,0);
      }
    }
  }
  #pragma unroll
  for (int m=0;m<2;++m){
    int h = m2*32 + m*16 + lg*4;
    int b = nt*16 + ln;
    float* pp = part + ((size_t)(ks*8+e)*288 + h)*64 + b;
    #pragma unroll
    for (int r=0;r<4;++r)
      pp[(size_t)r*64] = acc[m][r];
  }
}

__global__ __launch_bounds__(TPB) void eh1_reduce_k(
    const float* __restrict__ part, const float* __restrict__ eb1,
    float* __restrict__ h1)
{
  int idx = blockIdx.x*TPB + threadIdx.x;
  if (idx >= 8*288*64) return;
  int b = idx & 63;
  int h = (idx >> 6) % 288;
  int e = idx / (64*288);
  float a = eb1[(size_t)e*288 + h];
  #pragma unroll
  for (int s=0;s<16;++s)
    a += part[((size_t)(s*8+e)*288 + h)*64 + b];
  h1[((size_t)e*64 + b)*288 + h] = fmaxf(a, 0.f);
}

__global__ __launch_bounds__(TPB) void expert_h2_k(
    const float* __restrict__ h1, const float* __restrict__ ew2,
    const float* __restrict__ eb2, const float* __restrict__ gates,
    float* __restrict__ h2)
{
  int idx = blockIdx.x*TPB + threadIdx.x;
  if (idx >= 8*64*144) return;
  int k = idx % 144;
  int t = idx / 144;
  int b = t % 64;
  int e = t / 64;
  if (gates[(size_t)b*8 + e] == 0.f) return;
  float acc = eb2[(size_t)e*144 + k];
  const float* h = h1 + ((size_t)e*64 + b)*288;
  const float* w = ew2 + (size_t)e*288*144 + k;
  for (int d=0; d<288; ++d)
    acc = fmaf(h[d], w[(size_t)d*144], acc);
  h2[idx] = fmaxf(acc, 0.f);
}

__global__ __launch_bounds__(TPB) void expert_out_k(
    const float* __restrict__ h2, const float* __restrict__ ew3,
    const float* __restrict__ eb3, const float* __restrict__ gates,
    float* __restrict__ out)
{
  int idx = blockIdx.x*TPB + threadIdx.x;
  if (idx >= 64*1000) return;
  int o = idx % 1000;
  int b = idx / 1000;
  float acc = 0.f;
  const float* gr = gates + (size_t)b*8;
  for (int e=0;e<8;++e){
    float ge = gr[e];
    if (ge == 0.f) continue;
    float a = eb3[(size_t)e*1000 + o];
    const float* h = h2 + ((size_t)e*64 + b)*144;
    const float* w = ew3 + (size_t)e*144*1000 + o;
    for (int k=0;k<144;++k)
      a = fmaf(h[k], w[(size_t)k*1000], a);
    acc = fmaf(ge, a, acc);
  }
  out[idx] = acc;
}

static inline int nblk(long long n){ return (int)((n + TPB - 1) / TPB); }

extern "C" void kernel_launch(void* const* d_in, const int* in_sizes, int n_in,
                              void* d_out, int out_size, void* d_ws, size_t ws_size,
                              hipStream_t stream)
{
  const float* x   = (const float*)d_in[0];
  const float* c1w = (const float*)d_in[1];  const float* c1b = (const float*)d_in[2];
  const float* c2w = (const float*)d_in[3];  const float* c2b = (const float*)d_in[4];
  const float* c3w = (const float*)d_in[5];  const float* c3b = (const float*)d_in[6];
  const float* c4w = (const float*)d_in[7];  const float* c4b = (const float*)d_in[8];
  const float* c5w = (const float*)d_in[9];  const float* c5b = (const float*)d_in[10];
  const float* gw1 = (const float*)d_in[11]; const float* gb1 = (const float*)d_in[12];
  const float* gw2 = (const float*)d_in[13]; const float* gb2 = (const float*)d_in[14];
  const float* ew1 = (const float*)d_in[15]; const float* eb1 = (const float*)d_in[16];
  const float* ew2 = (const float*)d_in[17]; const float* eb2 = (const float*)d_in[18];
  const float* ew3 = (const float*)d_in[19]; const float* eb3 = (const float*)d_in[20];
  float* out = (float*)d_out;

  float* W = (float*)d_ws;
  short* X3H = (short*)W;
  short* X3L = X3H + 8957952;
  short* X5H = (short*)W;
  short* X5L = X5H + 4153344;
  short* X7H = (short*)W;
  short* X7L = X7H + 2768896;
  float* feat  = W + 5000000;
  short* FBH   = (short*)(W + 5600000);
  short* FBL   = (short*)(W + 5900000);
  float* part  = W + 6300000;
  short* WH2 = (short*)(W +  9000000);
  short* WL2 = WH2 + 307200;
  short* WH3 = (short*)(W +  9320000);
  short* WL3 = WH3 + 663552;
  short* WH4 = (short*)(W + 10000000);
  short* WL4 = WH4 + 884736;
  short* WH5 = (short*)(W + 10900000);
  short* WL5 = WH5 + 589824;
  float* GT1 = W + 11500000;
  short* X2H = (short*)(W + 12390400);
  short* X2L = X2H + 2985984;
  short* X4H = (short*)(W + 12390400);
  short* X4L = X4H + 2076672;
  short* X6H = (short*)(W + 12390400);
  short* X6L = X6H + 2768896;
  float* gates = W + 14000000;
  float* h1    = gates + 512;
  float* h2    = h1 + 147456;
  float* gbuf  = h2 + 73728;
  short* WH1 = (short*)(W + 15400000);
  short* WL1 = WH1 + 36864;
  (void)ws_size; (void)in_sizes; (void)n_in; (void)out_size;

  // conv1+pool1 fused -> X2 split directly (no X1)
  wsplit1_k<<<nblk(64LL*576), TPB, 0, stream>>>(c1w, WH1, WL1);
  conv1p_k<<<dim3(27,64), 256, 0, stream>>>(x, WH1, WL1, c1b, X2H, X2L);
  // weight prep (runs fine alongside/after conv1p; regions disjoint)
  wsplit_k<<<nblk(25LL*192*64),  TPB, 0, stream>>>(c2w, WH2, WL2,  64, 192, 25, 25*192*64);
  wsplit_k<<<nblk(9LL*384*192),  TPB, 0, stream>>>(c3w, WH3, WL3, 192, 384,  9, 9*384*192);
  wsplit_k<<<nblk(9LL*256*384),  TPB, 0, stream>>>(c4w, WH4, WL4, 384, 256,  9, 9*256*384);
  wsplit_k<<<nblk(9LL*256*256),  TPB, 0, stream>>>(c5w, WH5, WL5, 256, 256,  9, 9*256*256);
  wtrans_k<<<nblk(72LL*9216),    TPB, 0, stream>>>(gw1, GT1, 72, 9216);

  conv2m_k<<<dim3(9,64), 256, 0, stream>>>(X2H, X2L, WH2, WL2, c2b, X3H, X3L);
  pool2_k<<<nblk(64LL*169*192), TPB, 0, stream>>>(X3H, X3L, X4H, X4L);
  conv3m_k<192,384><<<dim3(12,64), 256, 0, stream>>>(X4H, X4L, WH3, WL3, c3b, X5H, X5L);
  conv3m_k<384,256><<<dim3(8,64),  256, 0, stream>>>(X5H, X5L, WH4, WL4, c4b, X6H, X6L);
  conv3m_k<256,256><<<dim3(8,64),  256, 0, stream>>>(X6H, X6L, WH5, WL5, c5b, X7H, X7L);
  pool3_k<<<nblk(64LL*9216), TPB, 0, stream>>>(X7H, X7L, feat);

  gate1_k<<<dim3(64,18), 256, 0, stream>>>(feat, GT1, gb1, gbuf);
  gate2_k<<<64, 128, 0, stream>>>(gbuf, gw2, gb2, gates);

  featsplit_k<<<nblk(589824LL), TPB, 0, stream>>>(feat, FBH, FBL);
  eh1m_k<<<dim3(9,8,16), 256, 0, stream>>>(ew1, FBH, FBL, part);
  eh1_reduce_k<<<nblk(8LL*288*64), TPB, 0, stream>>>(part, eb1, h1);
  expert_h2_k<<<nblk(8LL*64*144), TPB, 0, stream>>>(h1, ew2, eb2, gates, h2);
  expert_out_k<<<nblk(64LL*1000), TPB, 0, stream>>>(h2, ew3, eb3, gates, out);
}

// Round 19
// 500.038 us; speedup vs baseline: 2.1783x; 1.0260x over previous
//
#include <hip/hip_runtime.h>
#include <math.h>

#define TPB 256

typedef short s16x8 __attribute__((ext_vector_type(8)));
typedef short s16x4 __attribute__((ext_vector_type(4)));
typedef float f32x4 __attribute__((ext_vector_type(4)));

__device__ inline void bsplit(float x, short& h, short& l){
  union { float f; unsigned u; } a, hf, rf;
  a.f = x;
  unsigned hu = (a.u + 0x7FFFu + ((a.u >> 16) & 1u)) >> 16;
  h = (short)hu;
  hf.u = hu << 16;
  rf.f = x - hf.f;
  l = (short)((rf.u + 0x7FFFu + ((rf.u >> 16) & 1u)) >> 16);
}
__device__ inline float b2f(short s){
  union { unsigned u; float f; } x;
  x.u = ((unsigned)(unsigned short)s) << 16;
  return x.f;
}

// ==== weight split + MFMA-native reorder ====
__global__ __launch_bounds__(TPB) void wsplit_k(
    const float* __restrict__ w, short* __restrict__ wh, short* __restrict__ wl,
    int C, int O, int ntap, int total)
{
  int idx = blockIdx.x*TPB + threadIdx.x;
  if (idx >= total) return;
  int c   = idx % C;
  int t2  = idx / C;
  int oc  = t2 % O;
  int tap = t2 / O;
  float x = w[((size_t)oc*C + c)*ntap + tap];
  short h, l; bsplit(x, h, l);
  int tile = oc >> 4, ln = oc & 15;
  int S    = ntap*(C >> 5);
  int sl   = tap*(C >> 5) + (c >> 5);
  int lg   = (c >> 3) & 3, j = c & 7;
  size_t dst = (((size_t)tile*S + sl)*64 + lg*16 + ln)*8 + j;
  wh[dst] = h; wl[dst] = l;
}

__global__ __launch_bounds__(TPB) void wsplit1_k(
    const float* __restrict__ w, short* __restrict__ wh, short* __restrict__ wl)
{
  int idx = blockIdx.x*TPB + threadIdx.x;
  if (idx >= 64*576) return;
  int k  = idx % 576;
  int oc = idx / 576;
  int g  = k >> 4, kw = k & 15;
  int c  = g / 12, kh = g % 12;
  float x = 0.f;
  if (kh < 11 && kw < 11)
    x = w[((size_t)oc*3 + c)*121 + kh*11 + kw];
  short h, l; bsplit(x, h, l);
  int m = oc >> 4, ln = oc & 15;
  int s = k >> 5, r = k & 31;
  int lg = r >> 3, j = r & 7;
  size_t dst = (((size_t)m*18 + s)*64 + lg*16 + ln)*8 + j;
  wh[dst] = h; wl[dst] = l;
}

__global__ __launch_bounds__(TPB) void wtrans_k(
    const float* __restrict__ w, float* __restrict__ wT, int K, int O)
{
  int idx = blockIdx.x*TPB + threadIdx.x;
  if (idx >= K*O) return;
  int oc = idx % O;
  int k  = idx / O;
  wT[idx] = w[(size_t)oc*K + k];
}

// ========= conv1+pool1 fused MFMA v2: ow-split halves for occupancy =========
// grid (27 r, 64 b, 2 half). LDS: 57 planes x 128 cols hi/lo = 29.9 KB.
// FULL 128-col staging (round-18 bug: cols 124..127 were uninitialized ->
// bf16 NaN garbage -> 0*NaN=NaN -> fmaxf(NaN,0)=0 silently zeroed outputs).
#define CW1 128
__global__ __launch_bounds__(256, 4) void conv1p_k(
    const float* __restrict__ in, const short* __restrict__ whi,
    const short* __restrict__ wlo, const float* __restrict__ bias,
    short* __restrict__ yh, short* __restrict__ yl)
{
  __shared__ __align__(16) short lds[2][57*CW1 + 176];
  const int tid = threadIdx.x;
  const int r  = blockIdx.x;            // pool row 0..26
  const int b  = blockIdx.y;
  const int hf = blockIdx.z;            // ow half
  const int wid = tid >> 6;
  const int ntl = wid & 1;
  const int och = wid >> 1;
  const int ln = tid & 15;
  const int lg = (tid & 63) >> 4;
  const int lane = tid & 63;
  const int lw = ntl*16 + ln;           // local ow
  const int iwbase = hf*112 - 2;        // ow0*4 - 2, ow0 = hf*28

  // ---- phase 1: stage 57 planes x FULL 128 cols (bsplit, zero-guarded) ----
  const float* ip = in + (size_t)b*3*224*224;
  for (int i = tid; i < 57*32; i += 256){
    int plane = i >> 5;
    int p     = i & 31;
    int c = plane / 19, ri = plane % 19;
    int ih = 8*r - 2 + ri;
    int col0 = p*4;
    const float* rowp = (ih >= 0 && ih < 224) ? ip + (size_t)c*50176 + (size_t)ih*224 : nullptr;
    short h[4], l[4];
    #pragma unroll
    for (int j=0;j<4;++j){
      int iw = iwbase + col0 + j;
      float v = (rowp && iw >= 0 && iw < 224) ? rowp[iw] : 0.f;
      bsplit(v, h[j], l[j]);
    }
    s16x4 hv = {h[0],h[1],h[2],h[3]}, lv = {l[0],l[1],l[2],l[3]};
    *reinterpret_cast<s16x4*>(&lds[0][plane*CW1 + col0]) = hv;
    *reinterpret_cast<s16x4*>(&lds[1][plane*CW1 + col0]) = lv;
  }
  __syncthreads();

  // ---- phase 2: MFMA, 3 conv rows sharing A-frags; 2 oc-tiles per wave ----
  f32x4 acc[3][2];
  #pragma unroll
  for (int m=0;m<2;++m){
    const float4 bv = *reinterpret_cast<const float4*>(bias + och*32 + m*16 + lg*4);
    #pragma unroll
    for (int sub=0;sub<3;++sub)
      acc[sub][m] = (f32x4){bv.x, bv.y, bv.z, bv.w};
  }

  s16x8 ah[2], al[2], ahn[2], aln[2];
  #pragma unroll
  for (int m=0;m<2;++m){
    size_t ao = (((size_t)(och*2+m)*18 + 0)*64 + lane)*8;
    ah[m] = *reinterpret_cast<const s16x8*>(whi + ao);
    al[m] = *reinterpret_cast<const s16x8*>(wlo + ao);
  }

  #pragma unroll 1
  for (int s=0; s<18; ++s){
    if (s < 17){
      #pragma unroll
      for (int m=0;m<2;++m){
        size_t ao = (((size_t)(och*2+m)*18 + s + 1)*64 + lane)*8;
        ahn[m] = *reinterpret_cast<const s16x8*>(whi + ao);
        aln[m] = *reinterpret_cast<const s16x8*>(wlo + ao);
      }
    }
    int g  = 2*s + (lg >> 1);
    int c  = g / 12, kh = g % 12;
    int khp = (kh < 11) ? kh : 10;       // kh=11: zero weights, alias row
    #pragma unroll
    for (int sub=0;sub<3;++sub){
      int plane = c*19 + 4*sub + khp;
      int base  = plane*CW1 + lw*4 + (lg & 1)*8;
      s16x4 h0 = *reinterpret_cast<const s16x4*>(&lds[0][base]);
      s16x4 h1 = *reinterpret_cast<const s16x4*>(&lds[0][base+4]);
      s16x4 l0 = *reinterpret_cast<const s16x4*>(&lds[1][base]);
      s16x4 l1 = *reinterpret_cast<const s16x4*>(&lds[1][base+4]);
      s16x8 bh = __builtin_shufflevector(h0, h1, 0,1,2,3,4,5,6,7);
      s16x8 bl = __builtin_shufflevector(l0, l1, 0,1,2,3,4,5,6,7);
      #pragma unroll
      for (int m=0;m<2;++m){
        acc[sub][m] = __builtin_amdgcn_mfma_f32_16x16x32_bf16(al[m], bh, acc[sub][m], 0,0,0);
        acc[sub][m] = __builtin_amdgcn_mfma_f32_16x16x32_bf16(ah[m], bl, acc[sub][m], 0,0,0);
        acc[sub][m] = __builtin_amdgcn_mfma_f32_16x16x32_bf16(ah[m], bh, acc[sub][m], 0,0,0);
      }
    }
    #pragma unroll
    for (int m=0;m<2;++m){ ah[m] = ahn[m]; al[m] = aln[m]; }
  }

  // ---- phase 3: relu'd conv rows -> LDS buffer [sub][lw][65*oc] (reuse) ----
  __syncthreads();
  float* convbuf = (float*)&lds[0][0];
  #pragma unroll
  for (int sub=0;sub<3;++sub)
    #pragma unroll
    for (int m=0;m<2;++m)
      #pragma unroll
      for (int rr=0;rr<4;++rr){
        int oc = och*32 + m*16 + lg*4 + rr;
        convbuf[(sub*36 + lw)*65 + oc] = fmaxf(acc[sub][m][rr], 0.f);
      }
  __syncthreads();

  // ---- phase 4: 3x3s2 maxpool -> X2 split ----
  const int npw = hf ? 13 : 14;
  for (int i = tid; i < npw*64; i += 256){
    int pwl = i >> 6, c = i & 63;
    float m = -INFINITY;
    #pragma unroll
    for (int sub=0;sub<3;++sub)
      #pragma unroll
      for (int j=0;j<3;++j)
        m = fmaxf(m, convbuf[(sub*36 + 2*pwl + j)*65 + c]);
    short h, l; bsplit(m, h, l);
    int pw = hf*14 + pwl;
    size_t o = ((size_t)b*729 + r*27 + pw)*64 + c;
    yh[o] = h; yl[o] = l;
  }
}

// ============== conv2 MFMA v3: 32-ch chunks + A-prefetch ==============
__global__ __launch_bounds__(256, 3) void conv2m_k(
    const short* __restrict__ xh, const short* __restrict__ xl,
    const short* __restrict__ whi, const short* __restrict__ wlo,
    const float* __restrict__ bias, short* __restrict__ yh, short* __restrict__ yl)
{
  __shared__ __align__(16) short lds[2][217*40];
  const int tid = threadIdx.x;
  const int rg  = blockIdx.x;
  const int b   = blockIdx.y;
  const int wid = tid >> 6;
  const int ln  = tid & 15;
  const int lg  = (tid & 63) >> 4;
  const int lane = tid & 63;
  const int oc0 = wid*48;
  const int r0  = rg*3;

  int sb[6], nn[6];
  #pragma unroll
  for (int t=0;t<6;++t){
    int n = t*16 + ln;
    nn[t] = n;
    int ohl = n / 27, ow = n % 27;
    sb[t] = (n < 81) ? (ohl*31 + ow) : 0;
  }

  f32x4 acc[3][6];
  #pragma unroll
  for (int m=0;m<3;++m){
    const float4 bv = *reinterpret_cast<const float4*>(bias + oc0 + m*16 + lg*4);
    #pragma unroll
    for (int t=0;t<6;++t) acc[m][t] = (f32x4){bv.x, bv.y, bv.z, bv.w};
  }

  #pragma unroll 1
  for (int c0=0; c0<64; c0+=32){
    __syncthreads();
    for (int i = tid; i < 217*4; i += 256){
      int sp = i >> 2, v = i & 3;
      int pr = sp/31, pc = sp%31;
      int ih = r0 - 2 + pr, iw = pc - 2;
      s16x8 hv = {0,0,0,0,0,0,0,0}, lv = {0,0,0,0,0,0,0,0};
      if (ih >= 0 && ih < 27 && iw >= 0 && iw < 27){
        size_t o = ((size_t)b*729 + ih*27 + iw)*64 + c0 + v*8;
        hv = *reinterpret_cast<const s16x8*>(xh + o);
        lv = *reinterpret_cast<const s16x8*>(xl + o);
      }
      *reinterpret_cast<s16x8*>(&lds[0][sp*40 + v*8]) = hv;
      *reinterpret_cast<s16x8*>(&lds[1][sp*40 + v*8]) = lv;
    }
    __syncthreads();

    const size_t tstr = 50*512;
    const size_t abase = ((size_t)(wid*3)*50 + (c0 >> 5))*512 + (size_t)lane*8;
    s16x8 ah0 = *reinterpret_cast<const s16x8*>(whi + abase);
    s16x8 ah1 = *reinterpret_cast<const s16x8*>(whi + abase + tstr);
    s16x8 ah2 = *reinterpret_cast<const s16x8*>(whi + abase + 2*tstr);
    s16x8 al0 = *reinterpret_cast<const s16x8*>(wlo + abase);
    s16x8 al1 = *reinterpret_cast<const s16x8*>(wlo + abase + tstr);
    s16x8 al2 = *reinterpret_cast<const s16x8*>(wlo + abase + 2*tstr);

    #pragma unroll 1
    for (int tap=0; tap<25; ++tap){
      s16x8 nh0=ah0, nh1=ah1, nh2=ah2, nl0=al0, nl1=al1, nl2=al2;
      if (tap < 24){
        size_t ao = abase + (size_t)(tap+1)*2*512;
        nh0 = *reinterpret_cast<const s16x8*>(whi + ao);
        nh1 = *reinterpret_cast<const s16x8*>(whi + ao + tstr);
        nh2 = *reinterpret_cast<const s16x8*>(whi + ao + 2*tstr);
        nl0 = *reinterpret_cast<const s16x8*>(wlo + ao);
        nl1 = *reinterpret_cast<const s16x8*>(wlo + ao + tstr);
        nl2 = *reinterpret_cast<const s16x8*>(wlo + ao + 2*tstr);
      }
      const int toff = (tap/5)*31 + (tap%5);
      #pragma unroll
      for (int t=0;t<6;++t){
        int off = (sb[t] + toff)*40 + lg*8;
        s16x8 bh = *reinterpret_cast<const s16x8*>(&lds[0][off]);
        s16x8 bl = *reinterpret_cast<const s16x8*>(&lds[1][off]);
        acc[0][t] = __builtin_amdgcn_mfma_f32_16x16x32_bf16(al0, bh, acc[0][t], 0,0,0);
        acc[0][t] = __builtin_amdgcn_mfma_f32_16x16x32_bf16(ah0, bl, acc[0][t], 0,0,0);
        acc[0][t] = __builtin_amdgcn_mfma_f32_16x16x32_bf16(ah0, bh, acc[0][t], 0,0,0);
        acc[1][t] = __builtin_amdgcn_mfma_f32_16x16x32_bf16(al1, bh, acc[1][t], 0,0,0);
        acc[1][t] = __builtin_amdgcn_mfma_f32_16x16x32_bf16(ah1, bl, acc[1][t], 0,0,0);
        acc[1][t] = __builtin_amdgcn_mfma_f32_16x16x32_bf16(ah1, bh, acc[1][t], 0,0,0);
        acc[2][t] = __builtin_amdgcn_mfma_f32_16x16x32_bf16(al2, bh, acc[2][t], 0,0,0);
        acc[2][t] = __builtin_amdgcn_mfma_f32_16x16x32_bf16(ah2, bl, acc[2][t], 0,0,0);
        acc[2][t] = __builtin_amdgcn_mfma_f32_16x16x32_bf16(ah2, bh, acc[2][t], 0,0,0);
      }
      ah0=nh0; ah1=nh1; ah2=nh2; al0=nl0; al1=nl1; al2=nl2;
    }
  }

  #pragma unroll
  for (int m=0;m<3;++m)
    #pragma unroll
    for (int t=0;t<6;++t){
      if (nn[t] < 81){
        int gsp = r0*27 + nn[t];
        size_t base = ((size_t)b*729 + gsp)*192 + oc0 + m*16 + lg*4;
        short h[4], l[4];
        #pragma unroll
        for (int r=0;r<4;++r) bsplit(fmaxf(acc[m][t][r], 0.f), h[r], l[r]);
        s16x4 hv = {h[0],h[1],h[2],h[3]}, lv = {l[0],l[1],l[2],l[3]};
        *reinterpret_cast<s16x4*>(yh + base) = hv;
        *reinterpret_cast<s16x4*>(yl + base) = lv;
      }
    }
}

// ---- pool2: X3[729][192] split -> X4[169][192] split ----
__global__ __launch_bounds__(TPB) void pool2_k(
    const short* __restrict__ xh, const short* __restrict__ xl,
    short* __restrict__ yh, short* __restrict__ yl)
{
  int i = blockIdx.x*TPB + threadIdx.x;
  if (i >= 64*169*192) return;
  int c = i % 192;
  int t = i / 192;
  int sp = t % 169;
  int b = t / 169;
  int r = sp/13, cc = sp%13;
  const short* ph = xh + (size_t)b*729*192 + c;
  const short* pl = xl + (size_t)b*729*192 + c;
  float m = -INFINITY;
  #pragma unroll
  for (int di=0;di<3;++di)
    #pragma unroll
    for (int dj=0;dj<3;++dj){
      size_t s = (size_t)((2*r+di)*27 + 2*cc+dj)*192;
      m = fmaxf(m, b2f(ph[s]) + b2f(pl[s]));
    }
  short h, l; bsplit(m, h, l);
  yh[i] = h; yl[i] = l;
}

// ============== conv3/4/5 MFMA; in: split ch-minor [169][C]; out: [169][O] =====
template<int C,int O>
__global__ __launch_bounds__(256, 3) void conv3m_k(
    const short* __restrict__ xh, const short* __restrict__ xl,
    const short* __restrict__ whi, const short* __restrict__ wlo,
    const float* __restrict__ bias, short* __restrict__ yh, short* __restrict__ yl)
{
  __shared__ __align__(16) short lds[2][225*40];
  const int tid = threadIdx.x;
  const int b   = blockIdx.y;
  const int wid = tid >> 6;
  const int ln  = tid & 15;
  const int lg  = (tid & 63) >> 4;
  const int lane = tid & 63;
  const int tileIdx = blockIdx.x*2 + (wid & 1);
  const int oc0 = tileIdx*16;
  const int ng  = wid >> 1;
  const int tbase  = ng ? 6 : 0;
  const int ntiles = ng ? 5 : 6;
  const int S3 = 9*(C/32);

  int sb[6], nn[6];
  #pragma unroll
  for (int t=0;t<6;++t){
    int n = (tbase + t)*16 + ln;
    nn[t] = n;
    int oh = n / 13, ow = n % 13;
    sb[t] = (n < 169) ? (oh*15 + ow) : 0;
  }

  f32x4 acc[6];
  const float4 bv = *reinterpret_cast<const float4*>(bias + oc0 + lg*4);
  #pragma unroll
  for (int t=0;t<6;++t) acc[t] = (f32x4){bv.x, bv.y, bv.z, bv.w};

  #pragma unroll 1
  for (int c0=0; c0<C; c0+=32){
    __syncthreads();
    for (int i = tid; i < 225*4; i += 256){
      int sp = i >> 2, v = i & 3;
      int r = sp/15, cc = sp%15;
      s16x8 hv = {0,0,0,0,0,0,0,0}, lv = {0,0,0,0,0,0,0,0};
      if (r >= 1 && r <= 13 && cc >= 1 && cc <= 13){
        size_t o = ((size_t)b*169 + (r-1)*13 + (cc-1))*C + c0 + v*8;
        hv = *reinterpret_cast<const s16x8*>(xh + o);
        lv = *reinterpret_cast<const s16x8*>(xl + o);
      }
      *reinterpret_cast<s16x8*>(&lds[0][sp*40 + v*8]) = hv;
      *reinterpret_cast<s16x8*>(&lds[1][sp*40 + v*8]) = lv;
    }
    __syncthreads();

    const size_t tb = (size_t)tileIdx*S3 + (c0 >> 5);
    s16x8 ah = *reinterpret_cast<const s16x8*>(whi + (tb*64 + lane)*8);
    s16x8 al = *reinterpret_cast<const s16x8*>(wlo + (tb*64 + lane)*8);
    #pragma unroll 1
    for (int tap=0; tap<9; ++tap){
      s16x8 ahn = ah, aln = al;
      if (tap < 8){
        size_t ao = ((tb + (size_t)(tap+1)*(C/32))*64 + lane)*8;
        ahn = *reinterpret_cast<const s16x8*>(whi + ao);
        aln = *reinterpret_cast<const s16x8*>(wlo + ao);
      }
      const int toff = (tap/3)*15 + (tap%3);
      #pragma unroll
      for (int t=0;t<6;++t){
        if (t < ntiles){
          int off = (sb[t] + toff)*40 + lg*8;
          s16x8 bh = *reinterpret_cast<const s16x8*>(&lds[0][off]);
          s16x8 bl = *reinterpret_cast<const s16x8*>(&lds[1][off]);
          acc[t] = __builtin_amdgcn_mfma_f32_16x16x32_bf16(al, bh, acc[t], 0,0,0);
          acc[t] = __builtin_amdgcn_mfma_f32_16x16x32_bf16(ah, bl, acc[t], 0,0,0);
          acc[t] = __builtin_amdgcn_mfma_f32_16x16x32_bf16(ah, bh, acc[t], 0,0,0);
        }
      }
      ah = ahn; al = aln;
    }
  }

  #pragma unroll
  for (int t=0;t<6;++t){
    if (t < ntiles && nn[t] < 169){
      size_t base = ((size_t)b*169 + nn[t])*O + oc0 + lg*4;
      short h[4], l[4];
      #pragma unroll
      for (int r=0;r<4;++r) bsplit(fmaxf(acc[t][r], 0.f), h[r], l[r]);
      s16x4 hv = {h[0],h[1],h[2],h[3]}, lv = {l[0],l[1],l[2],l[3]};
      *reinterpret_cast<s16x4*>(yh + base) = hv;
      *reinterpret_cast<s16x4*>(yl + base) = lv;
    }
  }
}

// ---- pool3: X7[169][256] split -> feat[b][9216] f32 (d = c*36 + sp) ----
__global__ __launch_bounds__(TPB) void pool3_k(
    const short* __restrict__ xh, const short* __restrict__ xl,
    float* __restrict__ feat)
{
  int i = blockIdx.x*TPB + threadIdx.x;
  if (i >= 64*9216) return;
  int d = i % 9216;
  int b = i / 9216;
  int c = d / 36;
  int sp = d % 36;
  int r = sp/6, cc = sp%6;
  const short* ph = xh + (size_t)b*169*256 + c;
  const short* pl = xl + (size_t)b*169*256 + c;
  float m = -INFINITY;
  #pragma unroll
  for (int di=0;di<3;++di)
    #pragma unroll
    for (int dj=0;dj<3;++dj){
      size_t s = (size_t)((2*r+di)*13 + 2*cc+dj)*256;
      m = fmaxf(m, b2f(ph[s]) + b2f(pl[s]));
    }
  feat[i] = m;
}

// ---- featsplit: feat[b][9216] -> featBT B-native [288 s][4 nt][64 lane][8 j] ----
__global__ __launch_bounds__(TPB) void featsplit_k(
    const float* __restrict__ feat, short* __restrict__ fbh, short* __restrict__ fbl)
{
  int idx = blockIdx.x*TPB + threadIdx.x;
  if (idx >= 589824) return;
  int j = idx & 7;
  int lane = (idx >> 3) & 63;
  int nt = (idx >> 9) & 3;
  int s = idx >> 11;
  int b = nt*16 + (lane & 15);
  int d = s*32 + (lane >> 4)*8 + j;
  short h, l; bsplit(feat[(size_t)b*9216 + d], h, l);
  fbh[idx] = h; fbl[idx] = l;
}

// ---------------- gate ----------------
__global__ __launch_bounds__(256) void gate1_k(
    const float* __restrict__ feat, const float* __restrict__ gw1T,
    const float* __restrict__ gb1, float* __restrict__ g)
{
  const int b    = blockIdx.x;
  const int h    = blockIdx.y*4 + (threadIdx.x >> 6);
  const int lane = threadIdx.x & 63;
  const float* f = feat + (size_t)b*9216;
  const float* w = gw1T + (size_t)h*9216;
  float s = 0.f;
  #pragma unroll
  for (int it=0; it<36; ++it){
    int d = it*256 + lane*4;
    float4 fv = *reinterpret_cast<const float4*>(f + d);
    float4 wv = *reinterpret_cast<const float4*>(w + d);
    s = fmaf(fv.x, wv.x, s);
    s = fmaf(fv.y, wv.y, s);
    s = fmaf(fv.z, wv.z, s);
    s = fmaf(fv.w, wv.w, s);
  }
  #pragma unroll
  for (int off=32; off; off>>=1) s += __shfl_down(s, off, 64);
  if (lane == 0) g[(size_t)b*72 + h] = fmaxf(s + gb1[h], 0.f);
}

__global__ __launch_bounds__(128) void gate2_k(
    const float* __restrict__ g, const float* __restrict__ gw2,
    const float* __restrict__ gb2, float* __restrict__ gates)
{
  const int b = blockIdx.x;
  const int tid = threadIdx.x;
  __shared__ float gs[72];
  __shared__ float logits[8];
  if (tid < 72) gs[tid] = g[(size_t)b*72 + tid];
  __syncthreads();
  if (tid < 8) {
    float acc = gb2[tid];
    for (int j=0;j<72;++j)
      acc = fmaf(gs[j], gw2[(size_t)j*8 + tid], acc);
    logits[tid] = acc;
  }
  __syncthreads();
  if (tid == 0) {
    int i1 = 0; float v1 = logits[0];
    for (int e=1;e<8;++e) if (logits[e] > v1) { v1 = logits[e]; i1 = e; }
    int i2 = -1; float v2 = -INFINITY;
    for (int e=0;e<8;++e) { if (e==i1) continue; if (logits[e] > v2) { v2 = logits[e]; i2 = e; } }
    float z  = expf(v2 - v1);
    float w1 = 1.f / (1.f + z);
    float w2 = z   / (1.f + z);
    float* gr = gates + (size_t)b*8;
    for (int e=0;e<8;++e) gr[e] = 0.f;
    gr[i1] = w1;
    gr[i2] = w2;
  }
}

// ========== expert h1 MFMA streaming GEMM ==========
__global__ __launch_bounds__(256, 4) void eh1m_k(
    const float* __restrict__ ew1, const short* __restrict__ fbh,
    const short* __restrict__ fbl, float* __restrict__ part)
{
  __shared__ __align__(16) short wh_l[32*88];
  __shared__ __align__(16) short wl_l[32*88];
  const int m2 = blockIdx.x;
  const int e  = blockIdx.y;
  const int ks = blockIdx.z;
  const int tid = threadIdx.x;
  const int nt = tid >> 6;
  const int ln = tid & 15;
  const int lg = (tid & 63) >> 4;
  const int lane = tid & 63;

  f32x4 acc[2] = {(f32x4){0.f,0.f,0.f,0.f},(f32x4){0.f,0.f,0.f,0.f}};

  const float* wsrc = ew1 + (size_t)e*9216*288 + (size_t)m2*32;
  const int d0 = ks*576;

  #pragma unroll 1
  for (int st=0; st<9; ++st){
    __syncthreads();
    {
      int drow = tid >> 2;
      int h0 = (tid & 3)*8;
      const float* src = wsrc + (size_t)(d0 + st*64 + drow)*288 + h0;
      float4 v0 = *reinterpret_cast<const float4*>(src);
      float4 v1 = *reinterpret_cast<const float4*>(src+4);
      float vv[8] = {v0.x,v0.y,v0.z,v0.w,v1.x,v1.y,v1.z,v1.w};
      #pragma unroll
      for (int k=0;k<8;++k){
        short h, l; bsplit(vv[k], h, l);
        wh_l[(h0+k)*88 + drow] = h;
        wl_l[(h0+k)*88 + drow] = l;
      }
    }
    __syncthreads();
    int sg = (d0 + st*64) >> 5;
    #pragma unroll
    for (int sl=0; sl<2; ++sl){
      size_t bo = ((size_t)(sg+sl)*4 + nt)*512 + (size_t)lane*8;
      s16x8 bh = *reinterpret_cast<const s16x8*>(fbh + bo);
      s16x8 bl = *reinterpret_cast<const s16x8*>(fbl + bo);
      #pragma unroll
      for (int m=0;m<2;++m){
        int ao = (m*16 + ln)*88 + sl*32 + lg*8;
        s16x8 ah = *reinterpret_cast<const s16x8*>(&wh_l[ao]);
        s16x8 al = *reinterpret_cast<const s16x8*>(&wl_l[ao]);
        acc[m] = __builtin_amdgcn_mfma_f32_16x16x32_bf16(al, bh, acc[m], 0,0,0);
        acc[m] = __builtin_amdgcn_mfma_f32_16x16x32_bf16(ah, bl, acc[m], 0,0,0);
        acc[m] = __builtin_amdgcn_mfma_f32_16x16x32_bf16(ah, bh, acc[m], 0,0,0);
      }
    }
  }
  #pragma unroll
  for (int m=0;m<2;++m){
    int h = m2*32 + m*16 + lg*4;
    int b = nt*16 + ln;
    float* pp = part + ((size_t)(ks*8+e)*288 + h)*64 + b;
    #pragma unroll
    for (int r=0;r<4;++r)
      pp[(size_t)r*64] = acc[m][r];
  }
}

__global__ __launch_bounds__(TPB) void eh1_reduce_k(
    const float* __restrict__ part, const float* __restrict__ eb1,
    float* __restrict__ h1)
{
  int idx = blockIdx.x*TPB + threadIdx.x;
  if (idx >= 8*288*64) return;
  int b = idx & 63;
  int h = (idx >> 6) % 288;
  int e = idx / (64*288);
  float a = eb1[(size_t)e*288 + h];
  #pragma unroll
  for (int s=0;s<16;++s)
    a += part[((size_t)(s*8+e)*288 + h)*64 + b];
  h1[((size_t)e*64 + b)*288 + h] = fmaxf(a, 0.f);
}

__global__ __launch_bounds__(TPB) void expert_h2_k(
    const float* __restrict__ h1, const float* __restrict__ ew2,
    const float* __restrict__ eb2, const float* __restrict__ gates,
    float* __restrict__ h2)
{
  int idx = blockIdx.x*TPB + threadIdx.x;
  if (idx >= 8*64*144) return;
  int k = idx % 144;
  int t = idx / 144;
  int b = t % 64;
  int e = t / 64;
  if (gates[(size_t)b*8 + e] == 0.f) return;
  float acc = eb2[(size_t)e*144 + k];
  const float* h = h1 + ((size_t)e*64 + b)*288;
  const float* w = ew2 + (size_t)e*288*144 + k;
  for (int d=0; d<288; ++d)
    acc = fmaf(h[d], w[(size_t)d*144], acc);
  h2[idx] = fmaxf(acc, 0.f);
}

__global__ __launch_bounds__(TPB) void expert_out_k(
    const float* __restrict__ h2, const float* __restrict__ ew3,
    const float* __restrict__ eb3, const float* __restrict__ gates,
    float* __restrict__ out)
{
  int idx = blockIdx.x*TPB + threadIdx.x;
  if (idx >= 64*1000) return;
  int o = idx % 1000;
  int b = idx / 1000;
  float acc = 0.f;
  const float* gr = gates + (size_t)b*8;
  for (int e=0;e<8;++e){
    float ge = gr[e];
    if (ge == 0.f) continue;
    float a = eb3[(size_t)e*1000 + o];
    const float* h = h2 + ((size_t)e*64 + b)*144;
    const float* w = ew3 + (size_t)e*144*1000 + o;
    for (int k=0;k<144;++k)
      a = fmaf(h[k], w[(size_t)k*1000], a);
    acc = fmaf(ge, a, acc);
  }
  out[idx] = acc;
}

static inline int nblk(long long n){ return (int)((n + TPB - 1) / TPB); }

extern "C" void kernel_launch(void* const* d_in, const int* in_sizes, int n_in,
                              void* d_out, int out_size, void* d_ws, size_t ws_size,
                              hipStream_t stream)
{
  const float* x   = (const float*)d_in[0];
  const float* c1w = (const float*)d_in[1];  const float* c1b = (const float*)d_in[2];
  const float* c2w = (const float*)d_in[3];  const float* c2b = (const float*)d_in[4];
  const float* c3w = (const float*)d_in[5];  const float* c3b = (const float*)d_in[6];
  const float* c4w = (const float*)d_in[7];  const float* c4b = (const float*)d_in[8];
  const float* c5w = (const float*)d_in[9];  const float* c5b = (const float*)d_in[10];
  const float* gw1 = (const float*)d_in[11]; const float* gb1 = (const float*)d_in[12];
  const float* gw2 = (const float*)d_in[13]; const float* gb2 = (const float*)d_in[14];
  const float* ew1 = (const float*)d_in[15]; const float* eb1 = (const float*)d_in[16];
  const float* ew2 = (const float*)d_in[17]; const float* eb2 = (const float*)d_in[18];
  const float* ew3 = (const float*)d_in[19]; const float* eb3 = (const float*)d_in[20];
  float* out = (float*)d_out;

  float* W = (float*)d_ws;
  short* X3H = (short*)W;
  short* X3L = X3H + 8957952;
  short* X5H = (short*)W;
  short* X5L = X5H + 4153344;
  short* X7H = (short*)W;
  short* X7L = X7H + 2768896;
  float* feat  = W + 5000000;
  short* FBH   = (short*)(W + 5600000);
  short* FBL   = (short*)(W + 5900000);
  float* part  = W + 6300000;
  short* WH2 = (short*)(W +  9000000);
  short* WL2 = WH2 + 307200;
  short* WH3 = (short*)(W +  9320000);
  short* WL3 = WH3 + 663552;
  short* WH4 = (short*)(W + 10000000);
  short* WL4 = WH4 + 884736;
  short* WH5 = (short*)(W + 10900000);
  short* WL5 = WH5 + 589824;
  float* GT1 = W + 11500000;
  short* X2H = (short*)(W + 12390400);
  short* X2L = X2H + 2985984;
  short* X4H = (short*)(W + 12390400);
  short* X4L = X4H + 2076672;
  short* X6H = (short*)(W + 12390400);
  short* X6L = X6H + 2768896;
  float* gates = W + 14000000;
  float* h1    = gates + 512;
  float* h2    = h1 + 147456;
  float* gbuf  = h2 + 73728;
  short* WH1 = (short*)(W + 15400000);
  short* WL1 = WH1 + 36864;
  (void)ws_size; (void)in_sizes; (void)n_in; (void)out_size;

  // conv1+pool1 fused v2 (ow-split, full-width staging) -> X2 split
  wsplit1_k<<<nblk(64LL*576), TPB, 0, stream>>>(c1w, WH1, WL1);
  conv1p_k<<<dim3(27,64,2), 256, 0, stream>>>(x, WH1, WL1, c1b, X2H, X2L);
  // weight prep
  wsplit_k<<<nblk(25LL*192*64),  TPB, 0, stream>>>(c2w, WH2, WL2,  64, 192, 25, 25*192*64);
  wsplit_k<<<nblk(9LL*384*192),  TPB, 0, stream>>>(c3w, WH3, WL3, 192, 384,  9, 9*384*192);
  wsplit_k<<<nblk(9LL*256*384),  TPB, 0, stream>>>(c4w, WH4, WL4, 384, 256,  9, 9*256*384);
  wsplit_k<<<nblk(9LL*256*256),  TPB, 0, stream>>>(c5w, WH5, WL5, 256, 256,  9, 9*256*256);
  wtrans_k<<<nblk(72LL*9216),    TPB, 0, stream>>>(gw1, GT1, 72, 9216);

  conv2m_k<<<dim3(9,64), 256, 0, stream>>>(X2H, X2L, WH2, WL2, c2b, X3H, X3L);
  pool2_k<<<nblk(64LL*169*192), TPB, 0, stream>>>(X3H, X3L, X4H, X4L);
  conv3m_k<192,384><<<dim3(12,64), 256, 0, stream>>>(X4H, X4L, WH3, WL3, c3b, X5H, X5L);
  conv3m_k<384,256><<<dim3(8,64),  256, 0, stream>>>(X5H, X5L, WH4, WL4, c4b, X6H, X6L);
  conv3m_k<256,256><<<dim3(8,64),  256, 0, stream>>>(X6H, X6L, WH5, WL5, c5b, X7H, X7L);
  pool3_k<<<nblk(64LL*9216), TPB, 0, stream>>>(X7H, X7L, feat);

  gate1_k<<<dim3(64,18), 256, 0, stream>>>(feat, GT1, gb1, gbuf);
  gate2_k<<<64, 128, 0, stream>>>(gbuf, gw2, gb2, gates);

  featsplit_k<<<nblk(589824LL), TPB, 0, stream>>>(feat, FBH, FBL);
  eh1m_k<<<dim3(9,8,16), 256, 0, stream>>>(ew1, FBH, FBL, part);
  eh1_reduce_k<<<nblk(8LL*288*64), TPB, 0, stream>>>(part, eb1, h1);
  expert_h2_k<<<nblk(8LL*64*144), TPB, 0, stream>>>(h1, ew2, eb2, gates, h2);
  expert_out_k<<<nblk(64LL*1000), TPB, 0, stream>>>(h2, ew3, eb3, gates, out);
}